// Round 1
// baseline (6761.993 us; speedup 1.0000x reference)
//
#include <hip/hip_runtime.h>
#include <math.h>

// ---- problem constants ----
constexpr int Hc = 24, Wc = 24, Nc = 576, BINSc = 82, Gc = 2;
constexpr int Tc = Nc + 1 + Gc;          // 579
constexpr int Dc = 256, NHc = 8, HDc = 32, DEPTHc = 6, MLPc = 512;
constexpr int Bc = 16, CINc = 10;
constexpr int BT = Bc * Tc;              // 9264
constexpr float SCALE = 0.17677669529663687f;  // 1/sqrt(32)

__device__ __forceinline__ float gelu_f(float x) {
    return 0.5f * x * (1.0f + erff(x * 0.70710678118654752f));
}

__device__ __forceinline__ float block_sum256(float v, float* s4) {
    #pragma unroll
    for (int off = 32; off > 0; off >>= 1) v += __shfl_down(v, off, 64);
    __syncthreads();                    // protect s4 from previous use
    if ((threadIdx.x & 63) == 0) s4[threadIdx.x >> 6] = v;
    __syncthreads();
    return s4[0] + s4[1] + s4[2] + s4[3];
}

// ---- embed: x[b,t,:] = cls | global | tokens@input_w + input_b + pos ----
__global__ __launch_bounds__(256) void embed_kernel(
        const float* __restrict__ obs, const float* __restrict__ iw,
        const float* __restrict__ ib, const float* __restrict__ cls,
        const float* __restrict__ glob, const float* __restrict__ rowe,
        const float* __restrict__ cole, float* __restrict__ x) {
    int t = blockIdx.x, b = blockIdx.y, d = threadIdx.x;
    float v;
    if (t == 0) {
        v = cls[d];
    } else if (t <= Gc) {
        v = glob[(t - 1) * Dc + d];
    } else {
        int n = t - 1 - Gc;
        float acc = ib[d];
        #pragma unroll
        for (int c = 0; c < CINc; ++c)
            acc = fmaf(obs[(b * CINc + c) * Nc + n], iw[c * Dc + d], acc);
        v = acc + rowe[(n / Wc) * Dc + d] + cole[(n % Wc) * Dc + d];
    }
    x[((size_t)b * Tc + t) * Dc + d] = v;
}

// ---- layernorm (row = one token), out = (x-m)*rsqrt(v+eps)*g + b ----
__global__ __launch_bounds__(256) void ln_kernel(
        const float* __restrict__ x, const float* __restrict__ g,
        const float* __restrict__ b, float* __restrict__ out) {
    __shared__ float s4[4];
    size_t row = blockIdx.x;
    float v = x[row * Dc + threadIdx.x];
    float m = block_sum256(v, s4) * (1.0f / 256.0f);
    float d = v - m;
    float var = block_sum256(d * d, s4) * (1.0f / 256.0f);
    out[row * Dc + threadIdx.x] = d * rsqrtf(var + 1e-5f) * g[threadIdx.x] + b[threadIdx.x];
}

// ---- LN + gather policy tokens (tokens 1..576) into contiguous rows ----
__global__ __launch_bounds__(256) void lnsel_kernel(
        const float* __restrict__ xn, const float* __restrict__ g,
        const float* __restrict__ b, float* __restrict__ out) {
    __shared__ float s4[4];
    int n = blockIdx.x, bb = blockIdx.y;
    const float* xr = xn + ((size_t)bb * Tc + 1 + n) * Dc;
    float v = xr[threadIdx.x];
    float m = block_sum256(v, s4) * (1.0f / 256.0f);
    float d = v - m;
    float var = block_sum256(d * d, s4) * (1.0f / 256.0f);
    out[((size_t)bb * Nc + n) * Dc + threadIdx.x] =
        d * rsqrtf(var + 1e-5f) * g[threadIdx.x] + b[threadIdx.x];
}

// ---- tiled fp32 GEMM: C = act(A@W + bias) (+ res). 64x64 tile, 4x4/thread ----
#define BMt 64
#define BNt 64
#define BKt 16
template <int ACT, bool RES>
__global__ __launch_bounds__(256) void gemm_kernel(
        const float* __restrict__ A, const float* __restrict__ W,
        const float* __restrict__ bias, const float* __restrict__ res,
        float* __restrict__ C, int M, int N, int K) {
    __shared__ float As[BKt][BMt + 4];
    __shared__ float Ws[BKt][BNt + 4];
    const int tid = threadIdx.x;
    const int tx = tid & 15, ty = tid >> 4;
    const int m0 = blockIdx.y * BMt, n0 = blockIdx.x * BNt;
    const int arow = tid >> 2, acol = (tid & 3) * 4;   // A: 64 rows x 16 k
    const int wrow = tid >> 4, wcol = (tid & 15) * 4;  // W: 16 k x 64 cols
    float acc[4][4] = {};
    for (int k0 = 0; k0 < K; k0 += BKt) {
        float4 av = make_float4(0.f, 0.f, 0.f, 0.f);
        if (m0 + arow < M)
            av = *reinterpret_cast<const float4*>(A + (size_t)(m0 + arow) * K + k0 + acol);
        As[acol + 0][arow] = av.x; As[acol + 1][arow] = av.y;
        As[acol + 2][arow] = av.z; As[acol + 3][arow] = av.w;
        *reinterpret_cast<float4*>(&Ws[wrow][wcol]) =
            *reinterpret_cast<const float4*>(W + (size_t)(k0 + wrow) * N + n0 + wcol);
        __syncthreads();
        #pragma unroll
        for (int kk = 0; kk < BKt; ++kk) {
            const float4 a = *reinterpret_cast<const float4*>(&As[kk][ty * 4]);
            const float4 w = *reinterpret_cast<const float4*>(&Ws[kk][tx * 4]);
            const float av4[4] = {a.x, a.y, a.z, a.w};
            const float wv4[4] = {w.x, w.y, w.z, w.w};
            #pragma unroll
            for (int i = 0; i < 4; ++i)
                #pragma unroll
                for (int j = 0; j < 4; ++j)
                    acc[i][j] = fmaf(av4[i], wv4[j], acc[i][j]);
        }
        __syncthreads();
    }
    #pragma unroll
    for (int i = 0; i < 4; ++i) {
        int row = m0 + ty * 4 + i;
        if (row < M) {
            float vals[4];
            #pragma unroll
            for (int j = 0; j < 4; ++j) {
                float v = acc[i][j] + bias[n0 + tx * 4 + j];
                if (ACT == 1) v = gelu_f(v);
                vals[j] = v;
            }
            if (RES) {
                const float4 rv = *reinterpret_cast<const float4*>(
                    res + (size_t)row * N + n0 + tx * 4);
                vals[0] += rv.x; vals[1] += rv.y; vals[2] += rv.z; vals[3] += rv.w;
            }
            *reinterpret_cast<float4*>(C + (size_t)row * N + n0 + tx * 4) =
                make_float4(vals[0], vals[1], vals[2], vals[3]);
        }
    }
}

// ---- attention: one wave per q-row; scores row in LDS; K/V L2-resident ----
__global__ __launch_bounds__(256) void attn_kernel(
        const float* __restrict__ qkv, const float* __restrict__ relb,
        const int* __restrict__ relidx, float* __restrict__ o) {
    __shared__ float sc[4][Tc];
    __shared__ float qs[4][HDc];
    __shared__ float bias_s[BINSc];
    const int bh = blockIdx.x;
    const int b = bh / NHc, h = bh % NHc;
    const int wave = threadIdx.x >> 6, lane = threadIdx.x & 63;
    const int q = blockIdx.y * 4 + wave;
    const bool active = q < Tc;
    if (threadIdx.x < BINSc) bias_s[threadIdx.x] = relb[h * BINSc + threadIdx.x];
    if (active && lane < HDc)
        qs[wave][lane] = qkv[(((size_t)b * Tc + q) * 3 + 0) * Dc + h * HDc + lane];
    __syncthreads();

    float mx = -1e30f;
    if (active) {
        for (int k = lane; k < Tc; k += 64) {
            const float* kp = qkv + (((size_t)b * Tc + k) * 3 + 1) * Dc + h * HDc;
            float a = 0.f;
            #pragma unroll
            for (int d4 = 0; d4 < HDc; d4 += 4) {
                const float4 kv = *reinterpret_cast<const float4*>(kp + d4);
                a = fmaf(qs[wave][d4 + 0], kv.x, a);
                a = fmaf(qs[wave][d4 + 1], kv.y, a);
                a = fmaf(qs[wave][d4 + 2], kv.z, a);
                a = fmaf(qs[wave][d4 + 3], kv.w, a);
            }
            float s = a * SCALE + bias_s[relidx[q * Tc + k]];
            sc[wave][k] = s;
            mx = fmaxf(mx, s);
        }
    }
    #pragma unroll
    for (int off = 32; off > 0; off >>= 1) mx = fmaxf(mx, __shfl_xor(mx, off, 64));
    float sum = 0.f;
    if (active) {
        for (int k = lane; k < Tc; k += 64) {
            float e = expf(sc[wave][k] - mx);
            sc[wave][k] = e;
            sum += e;
        }
    }
    #pragma unroll
    for (int off = 32; off > 0; off >>= 1) sum += __shfl_xor(sum, off, 64);
    if (active) {
        const float inv = 1.0f / sum;
        const int d = lane & 31, half = lane >> 5;
        float a = 0.f;
        #pragma unroll 4
        for (int k = half; k < Tc; k += 2)
            a = fmaf(sc[wave][k],
                     qkv[(((size_t)b * Tc + k) * 3 + 2) * Dc + h * HDc + d], a);
        a += __shfl_xor(a, 32, 64);
        if (half == 0)
            o[((size_t)b * Tc + q) * Dc + h * HDc + d] = a * inv;
    }
}

// ---- logits: out[b, n] = dot(PH_row, w2) + b2 ----
__global__ __launch_bounds__(256) void logits_kernel(
        const float* __restrict__ ph, const float* __restrict__ w2,
        const float* __restrict__ b2, float* __restrict__ out) {
    __shared__ float s4[4];
    size_t r = blockIdx.x;
    int bb = (int)(r / Nc), n = (int)(r % Nc);
    float v = ph[r * Dc + threadIdx.x] * w2[threadIdx.x];
    float s = block_sum256(v, s4);
    if (threadIdx.x == 0) out[bb * (Nc + 1) + n] = s + b2[0];
}

// ---- value head (16 blocks): LN + D->D gelu + D->1 ----
__global__ __launch_bounds__(256) void value_kernel(
        const float* __restrict__ xn, const float* __restrict__ g,
        const float* __restrict__ b, const float* __restrict__ w1,
        const float* __restrict__ b1, const float* __restrict__ w2,
        const float* __restrict__ b2, float* __restrict__ out) {
    __shared__ float s4[4];
    __shared__ float ts[Dc];
    const int bb = blockIdx.x, tid = threadIdx.x;
    float v = xn[(size_t)bb * Tc * Dc + tid];
    float m = block_sum256(v, s4) * (1.0f / 256.0f);
    float d = v - m;
    float var = block_sum256(d * d, s4) * (1.0f / 256.0f);
    ts[tid] = d * rsqrtf(var + 1e-5f) * g[tid] + b[tid];
    __syncthreads();
    float acc = b1[tid];
    #pragma unroll 8
    for (int i = 0; i < Dc; ++i) acc = fmaf(ts[i], w1[i * Dc + tid], acc);
    float hv = gelu_f(acc) * w2[tid];
    float s = block_sum256(hv, s4);
    if (tid == 0) out[bb * (Nc + 1) + Nc] = s + b2[0];
}

extern "C" void kernel_launch(void* const* d_in, const int* in_sizes, int n_in,
                              void* d_out, int out_size, void* d_ws, size_t ws_size,
                              hipStream_t stream) {
    const float* obs      = (const float*)d_in[0];
    const float* input_w  = (const float*)d_in[1];
    const float* input_b  = (const float*)d_in[2];
    const float* cls_tok  = (const float*)d_in[3];
    const float* glob_tok = (const float*)d_in[4];
    const float* row_emb  = (const float*)d_in[5];
    const float* col_emb  = (const float*)d_in[6];
    const float* ln1_g    = (const float*)d_in[7];
    const float* ln1_b    = (const float*)d_in[8];
    const float* qkv_w    = (const float*)d_in[9];
    const float* qkv_b    = (const float*)d_in[10];
    const float* proj_w   = (const float*)d_in[11];
    const float* proj_b   = (const float*)d_in[12];
    const float* rel_bias = (const float*)d_in[13];
    const float* ln2_g    = (const float*)d_in[14];
    const float* ln2_b    = (const float*)d_in[15];
    const float* fc1_w    = (const float*)d_in[16];
    const float* fc1_b    = (const float*)d_in[17];
    const float* fc2_w    = (const float*)d_in[18];
    const float* fc2_b    = (const float*)d_in[19];
    const float* norm_g   = (const float*)d_in[20];
    const float* norm_b   = (const float*)d_in[21];
    const float* pol_ln_g = (const float*)d_in[22];
    const float* pol_ln_b = (const float*)d_in[23];
    const float* pol_w1   = (const float*)d_in[24];
    const float* pol_b1   = (const float*)d_in[25];
    const float* pol_w2   = (const float*)d_in[26];
    const float* pol_b2   = (const float*)d_in[27];
    const float* val_ln_g = (const float*)d_in[28];
    const float* val_ln_b = (const float*)d_in[29];
    const float* val_w1   = (const float*)d_in[30];
    const float* val_b1   = (const float*)d_in[31];
    const float* val_w2   = (const float*)d_in[32];
    const float* val_b2   = (const float*)d_in[33];
    const int*   rel_idx  = (const int*)d_in[34];
    float* out = (float*)d_out;

    float* ws = (float*)d_ws;
    const size_t SZ_XD = (size_t)BT * Dc;       // 2,371,584 floats
    float* X    = ws;                            // persistent residual stream
    float* Hb   = ws + SZ_XD;                    // LN out / attn out
    float* QKV  = ws + 2 * SZ_XD;                // 3*SZ_XD floats (also MLP hidden / head scratch)
    float* MLPH = QKV;
    float* PT   = QKV;                           // policy tokens (9216x256)
    float* PH   = QKV + (size_t)Bc * Nc * Dc;    // policy hidden (9216x256)

    embed_kernel<<<dim3(Tc, Bc), 256, 0, stream>>>(
        obs, input_w, input_b, cls_tok, glob_tok, row_emb, col_emb, X);

    for (int l = 0; l < DEPTHc; ++l) {
        ln_kernel<<<BT, 256, 0, stream>>>(X, ln1_g + l * Dc, ln1_b + l * Dc, Hb);
        gemm_kernel<0, false><<<dim3(12, 145), 256, 0, stream>>>(
            Hb, qkv_w + (size_t)l * Dc * 3 * Dc, qkv_b + l * 3 * Dc, nullptr, QKV,
            BT, 3 * Dc, Dc);
        attn_kernel<<<dim3(Bc * NHc, (Tc + 3) / 4), 256, 0, stream>>>(
            QKV, rel_bias + l * NHc * BINSc, rel_idx, Hb);
        gemm_kernel<0, true><<<dim3(4, 145), 256, 0, stream>>>(
            Hb, proj_w + (size_t)l * Dc * Dc, proj_b + l * Dc, X, X, BT, Dc, Dc);
        ln_kernel<<<BT, 256, 0, stream>>>(X, ln2_g + l * Dc, ln2_b + l * Dc, Hb);
        gemm_kernel<1, false><<<dim3(8, 145), 256, 0, stream>>>(
            Hb, fc1_w + (size_t)l * Dc * MLPc, fc1_b + l * MLPc, nullptr, MLPH,
            BT, MLPc, Dc);
        gemm_kernel<0, true><<<dim3(4, 145), 256, 0, stream>>>(
            MLPH, fc2_w + (size_t)l * MLPc * Dc, fc2_b + l * Dc, X, X, BT, Dc, MLPc);
    }

    ln_kernel<<<BT, 256, 0, stream>>>(X, norm_g, norm_b, Hb);
    lnsel_kernel<<<dim3(Nc, Bc), 256, 0, stream>>>(Hb, pol_ln_g, pol_ln_b, PT);
    gemm_kernel<1, false><<<dim3(4, 144), 256, 0, stream>>>(
        PT, pol_w1, pol_b1, nullptr, PH, Bc * Nc, Dc, Dc);
    logits_kernel<<<Bc * Nc, 256, 0, stream>>>(PH, pol_w2, pol_b2, out);
    value_kernel<<<Bc, 256, 0, stream>>>(
        Hb, val_ln_g, val_ln_b, val_w1, val_b1, val_w2, val_b2, out);
}

// Round 2
// 2401.282 us; speedup vs baseline: 2.8160x; 2.8160x over previous
//
#include <hip/hip_runtime.h>
#include <math.h>

// ---- problem constants ----
constexpr int Hc = 24, Wc = 24, Nc = 576, BINSc = 82, Gc = 2;
constexpr int Tc = Nc + 1 + Gc;          // 579
constexpr int Dc = 256, NHc = 8, HDc = 32, DEPTHc = 6, MLPc = 512;
constexpr int Bc = 16, CINc = 10;
constexpr int BT = Bc * Tc;              // 9264
constexpr float SCALE = 0.17677669529663687f;  // 1/sqrt(32)

__device__ __forceinline__ float gelu_f(float x) {
    return 0.5f * x * (1.0f + erff(x * 0.70710678118654752f));
}

__device__ __forceinline__ float block_sum256(float v, float* s4) {
    #pragma unroll
    for (int off = 32; off > 0; off >>= 1) v += __shfl_down(v, off, 64);
    __syncthreads();                    // protect s4 from previous use
    if ((threadIdx.x & 63) == 0) s4[threadIdx.x >> 6] = v;
    __syncthreads();
    return s4[0] + s4[1] + s4[2] + s4[3];
}

// ---- embed: x[b,t,:] = cls | global | tokens@input_w + input_b + pos ----
__global__ __launch_bounds__(256) void embed_kernel(
        const float* __restrict__ obs, const float* __restrict__ iw,
        const float* __restrict__ ib, const float* __restrict__ cls,
        const float* __restrict__ glob, const float* __restrict__ rowe,
        const float* __restrict__ cole, float* __restrict__ x) {
    int t = blockIdx.x, b = blockIdx.y, d = threadIdx.x;
    float v;
    if (t == 0) {
        v = cls[d];
    } else if (t <= Gc) {
        v = glob[(t - 1) * Dc + d];
    } else {
        int n = t - 1 - Gc;
        float acc = ib[d];
        #pragma unroll
        for (int c = 0; c < CINc; ++c)
            acc = fmaf(obs[(b * CINc + c) * Nc + n], iw[c * Dc + d], acc);
        v = acc + rowe[(n / Wc) * Dc + d] + cole[(n % Wc) * Dc + d];
    }
    x[((size_t)b * Tc + t) * Dc + d] = v;
}

// ---- layernorm (row = one token), out = (x-m)*rsqrt(v+eps)*g + b ----
__global__ __launch_bounds__(256) void ln_kernel(
        const float* __restrict__ x, const float* __restrict__ g,
        const float* __restrict__ b, float* __restrict__ out) {
    __shared__ float s4[4];
    size_t row = blockIdx.x;
    float v = x[row * Dc + threadIdx.x];
    float m = block_sum256(v, s4) * (1.0f / 256.0f);
    float d = v - m;
    float var = block_sum256(d * d, s4) * (1.0f / 256.0f);
    out[row * Dc + threadIdx.x] = d * rsqrtf(var + 1e-5f) * g[threadIdx.x] + b[threadIdx.x];
}

// ---- LN + gather policy tokens (tokens 1..576) into contiguous rows ----
__global__ __launch_bounds__(256) void lnsel_kernel(
        const float* __restrict__ xn, const float* __restrict__ g,
        const float* __restrict__ b, float* __restrict__ out) {
    __shared__ float s4[4];
    int n = blockIdx.x, bb = blockIdx.y;
    const float* xr = xn + ((size_t)bb * Tc + 1 + n) * Dc;
    float v = xr[threadIdx.x];
    float m = block_sum256(v, s4) * (1.0f / 256.0f);
    float d = v - m;
    float var = block_sum256(d * d, s4) * (1.0f / 256.0f);
    out[((size_t)bb * Nc + n) * Dc + threadIdx.x] =
        d * rsqrtf(var + 1e-5f) * g[threadIdx.x] + b[threadIdx.x];
}

// ---- tiled fp32 GEMM: C = act(A@W + bias) (+ res). 64x64 tile, 4x4/thread ----
#define BMt 64
#define BNt 64
#define BKt 16
template <int ACT, bool RES>
__global__ __launch_bounds__(256) void gemm_kernel(
        const float* __restrict__ A, const float* __restrict__ W,
        const float* __restrict__ bias, const float* __restrict__ res,
        float* __restrict__ C, int M, int N, int K) {
    __shared__ float As[BKt][BMt + 4];
    __shared__ float Ws[BKt][BNt + 4];
    const int tid = threadIdx.x;
    const int tx = tid & 15, ty = tid >> 4;
    const int m0 = blockIdx.y * BMt, n0 = blockIdx.x * BNt;
    const int arow = tid >> 2, acol = (tid & 3) * 4;   // A: 64 rows x 16 k
    const int wrow = tid >> 4, wcol = (tid & 15) * 4;  // W: 16 k x 64 cols
    float acc[4][4] = {};
    for (int k0 = 0; k0 < K; k0 += BKt) {
        float4 av = make_float4(0.f, 0.f, 0.f, 0.f);
        if (m0 + arow < M)
            av = *reinterpret_cast<const float4*>(A + (size_t)(m0 + arow) * K + k0 + acol);
        As[acol + 0][arow] = av.x; As[acol + 1][arow] = av.y;
        As[acol + 2][arow] = av.z; As[acol + 3][arow] = av.w;
        *reinterpret_cast<float4*>(&Ws[wrow][wcol]) =
            *reinterpret_cast<const float4*>(W + (size_t)(k0 + wrow) * N + n0 + wcol);
        __syncthreads();
        #pragma unroll
        for (int kk = 0; kk < BKt; ++kk) {
            const float4 a = *reinterpret_cast<const float4*>(&As[kk][ty * 4]);
            const float4 w = *reinterpret_cast<const float4*>(&Ws[kk][tx * 4]);
            const float av4[4] = {a.x, a.y, a.z, a.w};
            const float wv4[4] = {w.x, w.y, w.z, w.w};
            #pragma unroll
            for (int i = 0; i < 4; ++i)
                #pragma unroll
                for (int j = 0; j < 4; ++j)
                    acc[i][j] = fmaf(av4[i], wv4[j], acc[i][j]);
        }
        __syncthreads();
    }
    #pragma unroll
    for (int i = 0; i < 4; ++i) {
        int row = m0 + ty * 4 + i;
        if (row < M) {
            float vals[4];
            #pragma unroll
            for (int j = 0; j < 4; ++j) {
                float v = acc[i][j] + bias[n0 + tx * 4 + j];
                if (ACT == 1) v = gelu_f(v);
                vals[j] = v;
            }
            if (RES) {
                const float4 rv = *reinterpret_cast<const float4*>(
                    res + (size_t)row * N + n0 + tx * 4);
                vals[0] += rv.x; vals[1] += rv.y; vals[2] += rv.z; vals[3] += rv.w;
            }
            *reinterpret_cast<float4*>(C + (size_t)row * N + n0 + tx * 4) =
                make_float4(vals[0], vals[1], vals[2], vals[3]);
        }
    }
}

// ---- flash-style attention: block = (b,h,q-tile of 64); 16x16 threads ----
// K/V/Q staged TRANSPOSED in LDS ([d][token], pad->68 floats: conflict-free),
// 4x4 register score tile, online softmax (width-16 shfl row reduce),
// P staged in LDS, PV as register-tiled pass. ~43.8KB LDS -> 3 blocks/CU.
#define QT 64
#define KT 64
__global__ __launch_bounds__(256) void attn_kernel(
        const float* __restrict__ qkv, const float* __restrict__ relb,
        const int* __restrict__ relidx, float* __restrict__ o) {
    __shared__ float Qs[HDc][QT + 4];
    __shared__ float Ks[HDc][KT + 4];
    __shared__ float Vs[HDc][KT + 4];
    __shared__ float Ps[QT][KT + 4];
    __shared__ float bias_s[BINSc];
    const int tid = threadIdx.x;
    const int b = blockIdx.x / NHc, h = blockIdx.x % NHc;
    const int q0 = blockIdx.y * QT;
    const int tx = tid & 15, ty = tid >> 4;
    if (tid < BINSc) bias_s[tid] = relb[h * BINSc + tid];
    const int lr = tid >> 3, ld4 = (tid & 7) * 4;
    // stage Q transposed: Qs[d][r] (rows clamped; fake rows discarded at store)
    #pragma unroll
    for (int pass = 0; pass < 2; ++pass) {
        const int r = pass * 32 + lr;
        const int gq = min(q0 + r, Tc - 1);
        const float4 v = *reinterpret_cast<const float4*>(
            qkv + ((size_t)(b * Tc + gq) * 3 + 0) * Dc + h * HDc + ld4);
        Qs[ld4 + 0][r] = v.x; Qs[ld4 + 1][r] = v.y;
        Qs[ld4 + 2][r] = v.z; Qs[ld4 + 3][r] = v.w;
    }
    float m_run[4], l_run[4], Oa[4][2];
    #pragma unroll
    for (int i = 0; i < 4; ++i) {
        m_run[i] = -1e30f; l_run[i] = 0.f; Oa[i][0] = 0.f; Oa[i][1] = 0.f;
    }
    const int nt = (Tc + KT - 1) / KT;  // 10
    for (int t = 0; t < nt; ++t) {
        const int k0 = t * KT;
        __syncthreads();  // prev PV done (and Q/bias staged on t=0)
        #pragma unroll
        for (int pass = 0; pass < 2; ++pass) {
            const int r = pass * 32 + lr;
            const int gk = min(k0 + r, Tc - 1);
            const float* src =
                qkv + ((size_t)(b * Tc + gk) * 3 + 1) * Dc + h * HDc + ld4;
            const float4 kv = *reinterpret_cast<const float4*>(src);
            Ks[ld4 + 0][r] = kv.x; Ks[ld4 + 1][r] = kv.y;
            Ks[ld4 + 2][r] = kv.z; Ks[ld4 + 3][r] = kv.w;
            const float4 vv = *reinterpret_cast<const float4*>(src + Dc);
            Vs[ld4 + 0][r] = vv.x; Vs[ld4 + 1][r] = vv.y;
            Vs[ld4 + 2][r] = vv.z; Vs[ld4 + 3][r] = vv.w;
        }
        __syncthreads();  // K/V ready
        // scores: 4x4 register tile, dot over d
        float s[4][4] = {};
        #pragma unroll 8
        for (int d = 0; d < HDc; ++d) {
            const float4 qv = *reinterpret_cast<const float4*>(&Qs[d][ty * 4]);
            const float4 kv = *reinterpret_cast<const float4*>(&Ks[d][tx * 4]);
            const float qa[4] = {qv.x, qv.y, qv.z, qv.w};
            const float ka[4] = {kv.x, kv.y, kv.z, kv.w};
            #pragma unroll
            for (int i = 0; i < 4; ++i)
                #pragma unroll
                for (int j = 0; j < 4; ++j)
                    s[i][j] = fmaf(qa[i], ka[j], s[i][j]);
        }
        // scale + rel-pos bias + k-mask
        #pragma unroll
        for (int i = 0; i < 4; ++i) {
            const int gq = q0 + ty * 4 + i;
            const int rbase = (gq < Tc ? gq : 0) * Tc;
            #pragma unroll
            for (int j = 0; j < 4; ++j) {
                const int kk = k0 + tx * 4 + j;
                s[i][j] = (kk < Tc)
                    ? fmaf(s[i][j], SCALE, bias_s[relidx[rbase + kk]])
                    : -1e30f;
            }
        }
        // online softmax per q-row (16 tx threads share a row)
        #pragma unroll
        for (int i = 0; i < 4; ++i) {
            float tm = fmaxf(fmaxf(s[i][0], s[i][1]), fmaxf(s[i][2], s[i][3]));
            #pragma unroll
            for (int mk = 1; mk < 16; mk <<= 1)
                tm = fmaxf(tm, __shfl_xor(tm, mk, 16));
            const float mn = fmaxf(m_run[i], tm);
            const float rescale = __expf(m_run[i] - mn);
            m_run[i] = mn;
            float ls = 0.f;
            #pragma unroll
            for (int j = 0; j < 4; ++j) {
                s[i][j] = __expf(s[i][j] - mn);
                ls += s[i][j];
            }
            #pragma unroll
            for (int mk = 1; mk < 16; mk <<= 1)
                ls += __shfl_xor(ls, mk, 16);
            l_run[i] = l_run[i] * rescale + ls;
            Oa[i][0] *= rescale; Oa[i][1] *= rescale;
            *reinterpret_cast<float4*>(&Ps[ty * 4 + i][tx * 4]) =
                make_float4(s[i][0], s[i][1], s[i][2], s[i][3]);
        }
        __syncthreads();  // P ready
        // PV: O[i][c] += sum_j P[row_i][j] * V_t[d_c][j]
        #pragma unroll 4
        for (int j4 = 0; j4 < KT; j4 += 4) {
            float4 pv[4];
            #pragma unroll
            for (int i = 0; i < 4; ++i)
                pv[i] = *reinterpret_cast<const float4*>(&Ps[ty * 4 + i][j4]);
            const float4 v0 = *reinterpret_cast<const float4*>(&Vs[tx][j4]);
            const float4 v1 = *reinterpret_cast<const float4*>(&Vs[tx + 16][j4]);
            const float va0[4] = {v0.x, v0.y, v0.z, v0.w};
            const float va1[4] = {v1.x, v1.y, v1.z, v1.w};
            #pragma unroll
            for (int i = 0; i < 4; ++i) {
                const float pa[4] = {pv[i].x, pv[i].y, pv[i].z, pv[i].w};
                #pragma unroll
                for (int jj = 0; jj < 4; ++jj) {
                    Oa[i][0] = fmaf(pa[jj], va0[jj], Oa[i][0]);
                    Oa[i][1] = fmaf(pa[jj], va1[jj], Oa[i][1]);
                }
            }
        }
    }
    // store: thread owns rows ty*4+i, d-cols {tx, tx+16}
    #pragma unroll
    for (int i = 0; i < 4; ++i) {
        const int gq = q0 + ty * 4 + i;
        if (gq < Tc) {
            const float inv = 1.0f / l_run[i];
            float* op = o + ((size_t)b * Tc + gq) * Dc + h * HDc;
            op[tx] = Oa[i][0] * inv;
            op[tx + 16] = Oa[i][1] * inv;
        }
    }
}

// ---- logits: out[b, n] = dot(PH_row, w2) + b2 ----
__global__ __launch_bounds__(256) void logits_kernel(
        const float* __restrict__ ph, const float* __restrict__ w2,
        const float* __restrict__ b2, float* __restrict__ out) {
    __shared__ float s4[4];
    size_t r = blockIdx.x;
    int bb = (int)(r / Nc), n = (int)(r % Nc);
    float v = ph[r * Dc + threadIdx.x] * w2[threadIdx.x];
    float s = block_sum256(v, s4);
    if (threadIdx.x == 0) out[bb * (Nc + 1) + n] = s + b2[0];
}

// ---- value head (16 blocks): LN + D->D gelu + D->1 ----
__global__ __launch_bounds__(256) void value_kernel(
        const float* __restrict__ xn, const float* __restrict__ g,
        const float* __restrict__ b, const float* __restrict__ w1,
        const float* __restrict__ b1, const float* __restrict__ w2,
        const float* __restrict__ b2, float* __restrict__ out) {
    __shared__ float s4[4];
    __shared__ float ts[Dc];
    const int bb = blockIdx.x, tid = threadIdx.x;
    float v = xn[(size_t)bb * Tc * Dc + tid];
    float m = block_sum256(v, s4) * (1.0f / 256.0f);
    float d = v - m;
    float var = block_sum256(d * d, s4) * (1.0f / 256.0f);
    ts[tid] = d * rsqrtf(var + 1e-5f) * g[tid] + b[tid];
    __syncthreads();
    float acc = b1[tid];
    #pragma unroll 8
    for (int i = 0; i < Dc; ++i) acc = fmaf(ts[i], w1[i * Dc + tid], acc);
    float hv = gelu_f(acc) * w2[tid];
    float s = block_sum256(hv, s4);
    if (tid == 0) out[bb * (Nc + 1) + Nc] = s + b2[0];
}

extern "C" void kernel_launch(void* const* d_in, const int* in_sizes, int n_in,
                              void* d_out, int out_size, void* d_ws, size_t ws_size,
                              hipStream_t stream) {
    const float* obs      = (const float*)d_in[0];
    const float* input_w  = (const float*)d_in[1];
    const float* input_b  = (const float*)d_in[2];
    const float* cls_tok  = (const float*)d_in[3];
    const float* glob_tok = (const float*)d_in[4];
    const float* row_emb  = (const float*)d_in[5];
    const float* col_emb  = (const float*)d_in[6];
    const float* ln1_g    = (const float*)d_in[7];
    const float* ln1_b    = (const float*)d_in[8];
    const float* qkv_w    = (const float*)d_in[9];
    const float* qkv_b    = (const float*)d_in[10];
    const float* proj_w   = (const float*)d_in[11];
    const float* proj_b   = (const float*)d_in[12];
    const float* rel_bias = (const float*)d_in[13];
    const float* ln2_g    = (const float*)d_in[14];
    const float* ln2_b    = (const float*)d_in[15];
    const float* fc1_w    = (const float*)d_in[16];
    const float* fc1_b    = (const float*)d_in[17];
    const float* fc2_w    = (const float*)d_in[18];
    const float* fc2_b    = (const float*)d_in[19];
    const float* norm_g   = (const float*)d_in[20];
    const float* norm_b   = (const float*)d_in[21];
    const float* pol_ln_g = (const float*)d_in[22];
    const float* pol_ln_b = (const float*)d_in[23];
    const float* pol_w1   = (const float*)d_in[24];
    const float* pol_b1   = (const float*)d_in[25];
    const float* pol_w2   = (const float*)d_in[26];
    const float* pol_b2   = (const float*)d_in[27];
    const float* val_ln_g = (const float*)d_in[28];
    const float* val_ln_b = (const float*)d_in[29];
    const float* val_w1   = (const float*)d_in[30];
    const float* val_b1   = (const float*)d_in[31];
    const float* val_w2   = (const float*)d_in[32];
    const float* val_b2   = (const float*)d_in[33];
    const int*   rel_idx  = (const int*)d_in[34];
    float* out = (float*)d_out;

    float* ws = (float*)d_ws;
    const size_t SZ_XD = (size_t)BT * Dc;       // 2,371,584 floats
    float* X    = ws;                            // persistent residual stream
    float* Hb   = ws + SZ_XD;                    // LN out / attn out
    float* QKV  = ws + 2 * SZ_XD;                // 3*SZ_XD floats (also MLP hidden / head scratch)
    float* MLPH = QKV;
    float* PT   = QKV;                           // policy tokens (9216x256)
    float* PH   = QKV + (size_t)Bc * Nc * Dc;    // policy hidden (9216x256)

    embed_kernel<<<dim3(Tc, Bc), 256, 0, stream>>>(
        obs, input_w, input_b, cls_tok, glob_tok, row_emb, col_emb, X);

    for (int l = 0; l < DEPTHc; ++l) {
        ln_kernel<<<BT, 256, 0, stream>>>(X, ln1_g + l * Dc, ln1_b + l * Dc, Hb);
        gemm_kernel<0, false><<<dim3(12, 145), 256, 0, stream>>>(
            Hb, qkv_w + (size_t)l * Dc * 3 * Dc, qkv_b + l * 3 * Dc, nullptr, QKV,
            BT, 3 * Dc, Dc);
        attn_kernel<<<dim3(Bc * NHc, (Tc + QT - 1) / QT), 256, 0, stream>>>(
            QKV, rel_bias + l * NHc * BINSc, rel_idx, Hb);
        gemm_kernel<0, true><<<dim3(4, 145), 256, 0, stream>>>(
            Hb, proj_w + (size_t)l * Dc * Dc, proj_b + l * Dc, X, X, BT, Dc, Dc);
        ln_kernel<<<BT, 256, 0, stream>>>(X, ln2_g + l * Dc, ln2_b + l * Dc, Hb);
        gemm_kernel<1, false><<<dim3(8, 145), 256, 0, stream>>>(
            Hb, fc1_w + (size_t)l * Dc * MLPc, fc1_b + l * MLPc, nullptr, MLPH,
            BT, MLPc, Dc);
        gemm_kernel<0, true><<<dim3(4, 145), 256, 0, stream>>>(
            MLPH, fc2_w + (size_t)l * MLPc * Dc, fc2_b + l * Dc, X, X, BT, Dc, MLPc);
    }

    ln_kernel<<<BT, 256, 0, stream>>>(X, norm_g, norm_b, Hb);
    lnsel_kernel<<<dim3(Nc, Bc), 256, 0, stream>>>(Hb, pol_ln_g, pol_ln_b, PT);
    gemm_kernel<1, false><<<dim3(4, 144), 256, 0, stream>>>(
        PT, pol_w1, pol_b1, nullptr, PH, Bc * Nc, Dc, Dc);
    logits_kernel<<<Bc * Nc, 256, 0, stream>>>(PH, pol_w2, pol_b2, out);
    value_kernel<<<Bc, 256, 0, stream>>>(
        Hb, val_ln_g, val_ln_b, val_w1, val_b1, val_w2, val_b2, out);
}

// Round 3
// 1854.225 us; speedup vs baseline: 3.6468x; 1.2950x over previous
//
#include <hip/hip_runtime.h>
#include <math.h>

// ---- problem constants ----
constexpr int Hc = 24, Wc = 24, Nc = 576, BINSc = 82, Gc = 2;
constexpr int Tc = Nc + 1 + Gc;          // 579
constexpr int Dc = 256, NHc = 8, HDc = 32, DEPTHc = 6, MLPc = 512;
constexpr int Bc = 16, CINc = 10;
constexpr int BT = Bc * Tc;              // 9264
constexpr float SCALE = 0.17677669529663687f;  // 1/sqrt(32)

typedef _Float16 f16;
typedef _Float16 f16x8 __attribute__((ext_vector_type(8)));
typedef float f32x4 __attribute__((ext_vector_type(4)));

__device__ __forceinline__ float gelu_f(float x) {
    return 0.5f * x * (1.0f + erff(x * 0.70710678118654752f));
}

__device__ __forceinline__ float block_sum256(float v, float* s4) {
    #pragma unroll
    for (int off = 32; off > 0; off >>= 1) v += __shfl_down(v, off, 64);
    __syncthreads();
    if ((threadIdx.x & 63) == 0) s4[threadIdx.x >> 6] = v;
    __syncthreads();
    return s4[0] + s4[1] + s4[2] + s4[3];
}

// ---- embed ----
__global__ __launch_bounds__(256) void embed_kernel(
        const float* __restrict__ obs, const float* __restrict__ iw,
        const float* __restrict__ ib, const float* __restrict__ cls,
        const float* __restrict__ glob, const float* __restrict__ rowe,
        const float* __restrict__ cole, float* __restrict__ x) {
    int t = blockIdx.x, b = blockIdx.y, d = threadIdx.x;
    float v;
    if (t == 0) {
        v = cls[d];
    } else if (t <= Gc) {
        v = glob[(t - 1) * Dc + d];
    } else {
        int n = t - 1 - Gc;
        float acc = ib[d];
        #pragma unroll
        for (int c = 0; c < CINc; ++c)
            acc = fmaf(obs[(b * CINc + c) * Nc + n], iw[c * Dc + d], acc);
        v = acc + rowe[(n / Wc) * Dc + d] + cole[(n % Wc) * Dc + d];
    }
    x[((size_t)b * Tc + t) * Dc + d] = v;
}

// ---- layernorm ----
__global__ __launch_bounds__(256) void ln_kernel(
        const float* __restrict__ x, const float* __restrict__ g,
        const float* __restrict__ b, float* __restrict__ out) {
    __shared__ float s4[4];
    size_t row = blockIdx.x;
    float v = x[row * Dc + threadIdx.x];
    float m = block_sum256(v, s4) * (1.0f / 256.0f);
    float d = v - m;
    float var = block_sum256(d * d, s4) * (1.0f / 256.0f);
    out[row * Dc + threadIdx.x] = d * rsqrtf(var + 1e-5f) * g[threadIdx.x] + b[threadIdx.x];
}

// ---- LN + gather policy tokens ----
__global__ __launch_bounds__(256) void lnsel_kernel(
        const float* __restrict__ xn, const float* __restrict__ g,
        const float* __restrict__ b, float* __restrict__ out) {
    __shared__ float s4[4];
    int n = blockIdx.x, bb = blockIdx.y;
    const float* xr = xn + ((size_t)bb * Tc + 1 + n) * Dc;
    float v = xr[threadIdx.x];
    float m = block_sum256(v, s4) * (1.0f / 256.0f);
    float d = v - m;
    float var = block_sum256(d * d, s4) * (1.0f / 256.0f);
    out[((size_t)bb * Nc + n) * Dc + threadIdx.x] =
        d * rsqrtf(var + 1e-5f) * g[threadIdx.x] + b[threadIdx.x];
}

// ---- weight split+transpose: W[K][N] fp32 -> WT_h[N][K], WT_l[N][K] fp16 ----
// region layout (f16 elems), h then l per matrix:
//   qkvT:  base 0        layer stride 393216 (N=768,K=256)
//   projT: base 2359296  layer stride 131072 (256,256)
//   fc1T:  base 3145728  layer stride 262144 (N=512,K=256)
//   fc2T:  base 4718592  layer stride 262144 (N=256,K=512)
//   polT:  base 6291456                      (256,256)
// total 6,422,528 f16
__global__ __launch_bounds__(256) void split_w_kernel(
        const float* __restrict__ qkv_w, const float* __restrict__ proj_w,
        const float* __restrict__ fc1_w, const float* __restrict__ fc2_w,
        const float* __restrict__ pol_w1, f16* __restrict__ out) {
    int r = blockIdx.x * 256 + threadIdx.x;
    float v; f16* dst; int NK;
    if (r < 1179648) {               // qkv
        int layer = r / 196608, e = r % 196608;
        int n = e >> 8, k = e & 255;
        v = qkv_w[(size_t)layer * 196608 + k * 768 + n];
        dst = out + (size_t)layer * 393216 + n * 256 + k; NK = 196608;
    } else if (r < 1572864) {        // proj
        int rr = r - 1179648; int layer = rr / 65536, e = rr % 65536;
        int n = e >> 8, k = e & 255;
        v = proj_w[(size_t)layer * 65536 + k * 256 + n];
        dst = out + 2359296 + (size_t)layer * 131072 + n * 256 + k; NK = 65536;
    } else if (r < 2359296) {        // fc1 (K=256,N=512)
        int rr = r - 1572864; int layer = rr / 131072, e = rr % 131072;
        int n = e >> 8, k = e & 255;
        v = fc1_w[(size_t)layer * 131072 + k * 512 + n];
        dst = out + 3145728 + (size_t)layer * 262144 + n * 256 + k; NK = 131072;
    } else if (r < 3145728) {        // fc2 (K=512,N=256)
        int rr = r - 2359296; int layer = rr / 131072, e = rr % 131072;
        int n = e >> 9, k = e & 511;
        v = fc2_w[(size_t)layer * 131072 + k * 256 + n];
        dst = out + 4718592 + (size_t)layer * 262144 + n * 512 + k; NK = 131072;
    } else if (r < 3211264) {        // pol_w1
        int rr = r - 3145728; int n = rr >> 8, k = rr & 255;
        v = pol_w1[k * 256 + n];
        dst = out + 6291456 + n * 256 + k; NK = 65536;
    } else return;
    f16 h = (f16)v;
    dst[0] = h;
    dst[NK] = (f16)(v - (float)h);
}

// ---- fp16x3 MFMA GEMM: C = act(A@W + bias) (+res), fp32 in/out ----
// A fp32 [M][K]; WT pre-split fp16: h at WT[0], l at WT[N*K] (both [N][K]).
// BM=128, BN=64, BK=32; 4 waves, each 64x32 via 4x2 frags of 16x16x32.
// acc += Ah*Wh + Ah*Wl + Al*Wh (error ~2^-22 rel).
// LDS granule XOR-swizzle: stage writes <=2-way, frag reads 2-way (free).
__device__ __forceinline__ int swz(int r, int g) {
    return r * 40 + ((g ^ ((r >> 3) & 3)) << 3);   // f16 index; rows 16B-aligned
}
template <int ACT, bool RES>
__global__ __launch_bounds__(256) void mgemm_kernel(
        const float* __restrict__ A, const f16* __restrict__ WT,
        const float* __restrict__ bias, const float* __restrict__ res,
        float* __restrict__ C, int M, int N, int K) {
    constexpr int BM = 128, BN = 64, BK = 32;
    __shared__ f16 Ah[BM * 40], Al[BM * 40];   // 10 KiB each
    __shared__ f16 Bh[BN * 40], Bl[BN * 40];   // 5 KiB each
    const int tid = threadIdx.x;
    const int m0 = blockIdx.y * BM, n0 = blockIdx.x * BN;
    const int w = tid >> 6, l = tid & 63;
    const int wm = (w >> 1) * 64, wn = (w & 1) * 32;
    const int lg = l >> 4, lr = l & 15;
    f32x4 acc[4][2] = {};
    // staging assignments
    const int sa_row = tid >> 1, sa_kc = (tid & 1) * 16;       // A: 128 rows x 2 halves
    const int sb_part = tid >> 7;                               // 0=h, 1=l
    const int sb_n = (tid & 127) >> 1, sb_kc = (tid & 1) * 16;  // B: 64 rows x 2 halves

    for (int k0 = 0; k0 < K; k0 += BK) {
        // ---- stage A (fp32 -> fp16 h/l) ----
        {
            int gr = m0 + sa_row; if (gr >= M) gr = M - 1;
            const float4* src = reinterpret_cast<const float4*>(
                A + (size_t)gr * K + k0 + sa_kc);
            f16x8 hv0, hv1, lv0, lv1;
            #pragma unroll
            for (int c = 0; c < 4; ++c) {
                float4 v = src[c];
                f16 h0 = (f16)v.x, h1 = (f16)v.y, h2 = (f16)v.z, h3 = (f16)v.w;
                f16 l0 = (f16)(v.x - (float)h0), l1 = (f16)(v.y - (float)h1);
                f16 l2 = (f16)(v.z - (float)h2), l3 = (f16)(v.w - (float)h3);
                if (c < 2) {
                    hv0[c * 4 + 0] = h0; hv0[c * 4 + 1] = h1;
                    hv0[c * 4 + 2] = h2; hv0[c * 4 + 3] = h3;
                    lv0[c * 4 + 0] = l0; lv0[c * 4 + 1] = l1;
                    lv0[c * 4 + 2] = l2; lv0[c * 4 + 3] = l3;
                } else {
                    hv1[(c - 2) * 4 + 0] = h0; hv1[(c - 2) * 4 + 1] = h1;
                    hv1[(c - 2) * 4 + 2] = h2; hv1[(c - 2) * 4 + 3] = h3;
                    lv1[(c - 2) * 4 + 0] = l0; lv1[(c - 2) * 4 + 1] = l1;
                    lv1[(c - 2) * 4 + 2] = l2; lv1[(c - 2) * 4 + 3] = l3;
                }
            }
            const int g0 = sa_kc >> 3;
            *reinterpret_cast<f16x8*>(&Ah[swz(sa_row, g0)])     = hv0;
            *reinterpret_cast<f16x8*>(&Ah[swz(sa_row, g0 + 1)]) = hv1;
            *reinterpret_cast<f16x8*>(&Al[swz(sa_row, g0)])     = lv0;
            *reinterpret_cast<f16x8*>(&Al[swz(sa_row, g0 + 1)]) = lv1;
        }
        // ---- stage B (pre-split fp16, copy) ----
        {
            const f16x8* src = reinterpret_cast<const f16x8*>(
                WT + (size_t)sb_part * N * K + (size_t)(n0 + sb_n) * K + k0 + sb_kc);
            f16* dbase = sb_part ? Bl : Bh;
            const int g0 = sb_kc >> 3;
            *reinterpret_cast<f16x8*>(&dbase[swz(sb_n, g0)])     = src[0];
            *reinterpret_cast<f16x8*>(&dbase[swz(sb_n, g0 + 1)]) = src[1];
        }
        __syncthreads();
        // ---- fragments + MFMA ----
        f16x8 afh[4], afl[4], bfh[2], bfl[2];
        #pragma unroll
        for (int mi = 0; mi < 4; ++mi) {
            int row = wm + mi * 16 + lr;
            afh[mi] = *reinterpret_cast<const f16x8*>(&Ah[swz(row, lg)]);
            afl[mi] = *reinterpret_cast<const f16x8*>(&Al[swz(row, lg)]);
        }
        #pragma unroll
        for (int ni = 0; ni < 2; ++ni) {
            int col = wn + ni * 16 + lr;
            bfh[ni] = *reinterpret_cast<const f16x8*>(&Bh[swz(col, lg)]);
            bfl[ni] = *reinterpret_cast<const f16x8*>(&Bl[swz(col, lg)]);
        }
        #pragma unroll
        for (int mi = 0; mi < 4; ++mi)
            #pragma unroll
            for (int ni = 0; ni < 2; ++ni) {
                acc[mi][ni] = __builtin_amdgcn_mfma_f32_16x16x32_f16(
                    afh[mi], bfh[ni], acc[mi][ni], 0, 0, 0);
                acc[mi][ni] = __builtin_amdgcn_mfma_f32_16x16x32_f16(
                    afh[mi], bfl[ni], acc[mi][ni], 0, 0, 0);
                acc[mi][ni] = __builtin_amdgcn_mfma_f32_16x16x32_f16(
                    afl[mi], bfh[ni], acc[mi][ni], 0, 0, 0);
            }
        __syncthreads();
    }
    // ---- epilogue: C row = m0+wm+mi*16+lg*4+r, col = n0+wn+ni*16+lr ----
    float bv[2];
    #pragma unroll
    for (int ni = 0; ni < 2; ++ni) bv[ni] = bias[n0 + wn + ni * 16 + lr];
    #pragma unroll
    for (int mi = 0; mi < 4; ++mi) {
        #pragma unroll
        for (int r = 0; r < 4; ++r) {
            int grow = m0 + wm + mi * 16 + lg * 4 + r;
            if (grow < M) {
                #pragma unroll
                for (int ni = 0; ni < 2; ++ni) {
                    int gcol = n0 + wn + ni * 16 + lr;
                    float v = acc[mi][ni][r] + bv[ni];
                    if (ACT == 1) v = gelu_f(v);
                    if (RES) v += res[(size_t)grow * N + gcol];
                    C[(size_t)grow * N + gcol] = v;
                }
            }
        }
    }
}

// ---- flash-style attention (unchanged from round 2) ----
#define QT 64
#define KT 64
__global__ __launch_bounds__(256) void attn_kernel(
        const float* __restrict__ qkv, const float* __restrict__ relb,
        const int* __restrict__ relidx, float* __restrict__ o) {
    __shared__ float Qs[HDc][QT + 4];
    __shared__ float Ks[HDc][KT + 4];
    __shared__ float Vs[HDc][KT + 4];
    __shared__ float Ps[QT][KT + 4];
    __shared__ float bias_s[BINSc];
    const int tid = threadIdx.x;
    const int b = blockIdx.x / NHc, h = blockIdx.x % NHc;
    const int q0 = blockIdx.y * QT;
    const int tx = tid & 15, ty = tid >> 4;
    if (tid < BINSc) bias_s[tid] = relb[h * BINSc + tid];
    const int lr = tid >> 3, ld4 = (tid & 7) * 4;
    #pragma unroll
    for (int pass = 0; pass < 2; ++pass) {
        const int r = pass * 32 + lr;
        const int gq = min(q0 + r, Tc - 1);
        const float4 v = *reinterpret_cast<const float4*>(
            qkv + ((size_t)(b * Tc + gq) * 3 + 0) * Dc + h * HDc + ld4);
        Qs[ld4 + 0][r] = v.x; Qs[ld4 + 1][r] = v.y;
        Qs[ld4 + 2][r] = v.z; Qs[ld4 + 3][r] = v.w;
    }
    float m_run[4], l_run[4], Oa[4][2];
    #pragma unroll
    for (int i = 0; i < 4; ++i) {
        m_run[i] = -1e30f; l_run[i] = 0.f; Oa[i][0] = 0.f; Oa[i][1] = 0.f;
    }
    const int nt = (Tc + KT - 1) / KT;  // 10
    for (int t = 0; t < nt; ++t) {
        const int k0 = t * KT;
        __syncthreads();
        #pragma unroll
        for (int pass = 0; pass < 2; ++pass) {
            const int r = pass * 32 + lr;
            const int gk = min(k0 + r, Tc - 1);
            const float* src =
                qkv + ((size_t)(b * Tc + gk) * 3 + 1) * Dc + h * HDc + ld4;
            const float4 kv = *reinterpret_cast<const float4*>(src);
            Ks[ld4 + 0][r] = kv.x; Ks[ld4 + 1][r] = kv.y;
            Ks[ld4 + 2][r] = kv.z; Ks[ld4 + 3][r] = kv.w;
            const float4 vv = *reinterpret_cast<const float4*>(src + Dc);
            Vs[ld4 + 0][r] = vv.x; Vs[ld4 + 1][r] = vv.y;
            Vs[ld4 + 2][r] = vv.z; Vs[ld4 + 3][r] = vv.w;
        }
        __syncthreads();
        float s[4][4] = {};
        #pragma unroll 8
        for (int d = 0; d < HDc; ++d) {
            const float4 qv = *reinterpret_cast<const float4*>(&Qs[d][ty * 4]);
            const float4 kv = *reinterpret_cast<const float4*>(&Ks[d][tx * 4]);
            const float qa[4] = {qv.x, qv.y, qv.z, qv.w};
            const float ka[4] = {kv.x, kv.y, kv.z, kv.w};
            #pragma unroll
            for (int i = 0; i < 4; ++i)
                #pragma unroll
                for (int j = 0; j < 4; ++j)
                    s[i][j] = fmaf(qa[i], ka[j], s[i][j]);
        }
        #pragma unroll
        for (int i = 0; i < 4; ++i) {
            const int gq = q0 + ty * 4 + i;
            const int rbase = (gq < Tc ? gq : 0) * Tc;
            #pragma unroll
            for (int j = 0; j < 4; ++j) {
                const int kk = k0 + tx * 4 + j;
                s[i][j] = (kk < Tc)
                    ? fmaf(s[i][j], SCALE, bias_s[relidx[rbase + kk]])
                    : -1e30f;
            }
        }
        #pragma unroll
        for (int i = 0; i < 4; ++i) {
            float tm = fmaxf(fmaxf(s[i][0], s[i][1]), fmaxf(s[i][2], s[i][3]));
            #pragma unroll
            for (int mk = 1; mk < 16; mk <<= 1)
                tm = fmaxf(tm, __shfl_xor(tm, mk, 16));
            const float mn = fmaxf(m_run[i], tm);
            const float rescale = __expf(m_run[i] - mn);
            m_run[i] = mn;
            float ls = 0.f;
            #pragma unroll
            for (int j = 0; j < 4; ++j) {
                s[i][j] = __expf(s[i][j] - mn);
                ls += s[i][j];
            }
            #pragma unroll
            for (int mk = 1; mk < 16; mk <<= 1)
                ls += __shfl_xor(ls, mk, 16);
            l_run[i] = l_run[i] * rescale + ls;
            Oa[i][0] *= rescale; Oa[i][1] *= rescale;
            *reinterpret_cast<float4*>(&Ps[ty * 4 + i][tx * 4]) =
                make_float4(s[i][0], s[i][1], s[i][2], s[i][3]);
        }
        __syncthreads();
        #pragma unroll 4
        for (int j4 = 0; j4 < KT; j4 += 4) {
            float4 pv[4];
            #pragma unroll
            for (int i = 0; i < 4; ++i)
                pv[i] = *reinterpret_cast<const float4*>(&Ps[ty * 4 + i][j4]);
            const float4 v0 = *reinterpret_cast<const float4*>(&Vs[tx][j4]);
            const float4 v1 = *reinterpret_cast<const float4*>(&Vs[tx + 16][j4]);
            const float va0[4] = {v0.x, v0.y, v0.z, v0.w};
            const float va1[4] = {v1.x, v1.y, v1.z, v1.w};
            #pragma unroll
            for (int i = 0; i < 4; ++i) {
                const float pa[4] = {pv[i].x, pv[i].y, pv[i].z, pv[i].w};
                #pragma unroll
                for (int jj = 0; jj < 4; ++jj) {
                    Oa[i][0] = fmaf(pa[jj], va0[jj], Oa[i][0]);
                    Oa[i][1] = fmaf(pa[jj], va1[jj], Oa[i][1]);
                }
            }
        }
    }
    #pragma unroll
    for (int i = 0; i < 4; ++i) {
        const int gq = q0 + ty * 4 + i;
        if (gq < Tc) {
            const float inv = 1.0f / l_run[i];
            float* op = o + ((size_t)b * Tc + gq) * Dc + h * HDc;
            op[tx] = Oa[i][0] * inv;
            op[tx + 16] = Oa[i][1] * inv;
        }
    }
}

// ---- logits ----
__global__ __launch_bounds__(256) void logits_kernel(
        const float* __restrict__ ph, const float* __restrict__ w2,
        const float* __restrict__ b2, float* __restrict__ out) {
    __shared__ float s4[4];
    size_t r = blockIdx.x;
    int bb = (int)(r / Nc), n = (int)(r % Nc);
    float v = ph[r * Dc + threadIdx.x] * w2[threadIdx.x];
    float s = block_sum256(v, s4);
    if (threadIdx.x == 0) out[bb * (Nc + 1) + n] = s + b2[0];
}

// ---- value head ----
__global__ __launch_bounds__(256) void value_kernel(
        const float* __restrict__ xn, const float* __restrict__ g,
        const float* __restrict__ b, const float* __restrict__ w1,
        const float* __restrict__ b1, const float* __restrict__ w2,
        const float* __restrict__ b2, float* __restrict__ out) {
    __shared__ float s4[4];
    __shared__ float ts[Dc];
    const int bb = blockIdx.x, tid = threadIdx.x;
    float v = xn[(size_t)bb * Tc * Dc + tid];
    float m = block_sum256(v, s4) * (1.0f / 256.0f);
    float d = v - m;
    float var = block_sum256(d * d, s4) * (1.0f / 256.0f);
    ts[tid] = d * rsqrtf(var + 1e-5f) * g[tid] + b[tid];
    __syncthreads();
    float acc = b1[tid];
    #pragma unroll 8
    for (int i = 0; i < Dc; ++i) acc = fmaf(ts[i], w1[i * Dc + tid], acc);
    float hv = gelu_f(acc) * w2[tid];
    float s = block_sum256(hv, s4);
    if (tid == 0) out[bb * (Nc + 1) + Nc] = s + b2[0];
}

extern "C" void kernel_launch(void* const* d_in, const int* in_sizes, int n_in,
                              void* d_out, int out_size, void* d_ws, size_t ws_size,
                              hipStream_t stream) {
    const float* obs      = (const float*)d_in[0];
    const float* input_w  = (const float*)d_in[1];
    const float* input_b  = (const float*)d_in[2];
    const float* cls_tok  = (const float*)d_in[3];
    const float* glob_tok = (const float*)d_in[4];
    const float* row_emb  = (const float*)d_in[5];
    const float* col_emb  = (const float*)d_in[6];
    const float* ln1_g    = (const float*)d_in[7];
    const float* ln1_b    = (const float*)d_in[8];
    const float* qkv_w    = (const float*)d_in[9];
    const float* qkv_b    = (const float*)d_in[10];
    const float* proj_w   = (const float*)d_in[11];
    const float* proj_b   = (const float*)d_in[12];
    const float* rel_bias = (const float*)d_in[13];
    const float* ln2_g    = (const float*)d_in[14];
    const float* ln2_b    = (const float*)d_in[15];
    const float* fc1_w    = (const float*)d_in[16];
    const float* fc1_b    = (const float*)d_in[17];
    const float* fc2_w    = (const float*)d_in[18];
    const float* fc2_b    = (const float*)d_in[19];
    const float* norm_g   = (const float*)d_in[20];
    const float* norm_b   = (const float*)d_in[21];
    const float* pol_ln_g = (const float*)d_in[22];
    const float* pol_ln_b = (const float*)d_in[23];
    const float* pol_w1   = (const float*)d_in[24];
    const float* pol_b1   = (const float*)d_in[25];
    const float* pol_w2   = (const float*)d_in[26];
    const float* pol_b2   = (const float*)d_in[27];
    const float* val_ln_g = (const float*)d_in[28];
    const float* val_ln_b = (const float*)d_in[29];
    const float* val_w1   = (const float*)d_in[30];
    const float* val_b1   = (const float*)d_in[31];
    const float* val_w2   = (const float*)d_in[32];
    const float* val_b2   = (const float*)d_in[33];
    const int*   rel_idx  = (const int*)d_in[34];
    float* out = (float*)d_out;

    float* ws = (float*)d_ws;
    const size_t SZ_XD = (size_t)BT * Dc;        // 2,371,584 floats
    float* X    = ws;
    float* Hb   = ws + SZ_XD;
    float* QKV  = ws + 2 * SZ_XD;                // 3*SZ_XD floats
    float* MLPH = QKV;
    float* PT   = QKV;
    float* PH   = QKV + (size_t)Bc * Nc * Dc;
    f16* wsplit = (f16*)(ws + 5 * SZ_XD);        // 6,422,528 f16 = 12.85 MB

    // per-matrix pre-split weight pointers (h base; l at +N*K)
    auto qkvT = [&](int l) { return wsplit + (size_t)l * 393216; };
    auto projT = [&](int l) { return wsplit + 2359296 + (size_t)l * 131072; };
    auto fc1T = [&](int l) { return wsplit + 3145728 + (size_t)l * 262144; };
    auto fc2T = [&](int l) { return wsplit + 4718592 + (size_t)l * 262144; };
    f16* polT = wsplit + 6291456;

    split_w_kernel<<<12544, 256, 0, stream>>>(
        qkv_w, proj_w, fc1_w, fc2_w, pol_w1, wsplit);

    embed_kernel<<<dim3(Tc, Bc), 256, 0, stream>>>(
        obs, input_w, input_b, cls_tok, glob_tok, row_emb, col_emb, X);

    for (int l = 0; l < DEPTHc; ++l) {
        ln_kernel<<<BT, 256, 0, stream>>>(X, ln1_g + l * Dc, ln1_b + l * Dc, Hb);
        mgemm_kernel<0, false><<<dim3(12, 73), 256, 0, stream>>>(
            Hb, qkvT(l), qkv_b + l * 3 * Dc, nullptr, QKV, BT, 3 * Dc, Dc);
        attn_kernel<<<dim3(Bc * NHc, (Tc + QT - 1) / QT), 256, 0, stream>>>(
            QKV, rel_bias + l * NHc * BINSc, rel_idx, Hb);
        mgemm_kernel<0, true><<<dim3(4, 73), 256, 0, stream>>>(
            Hb, projT(l), proj_b + l * Dc, X, X, BT, Dc, Dc);
        ln_kernel<<<BT, 256, 0, stream>>>(X, ln2_g + l * Dc, ln2_b + l * Dc, Hb);
        mgemm_kernel<1, false><<<dim3(8, 73), 256, 0, stream>>>(
            Hb, fc1T(l), fc1_b + l * MLPc, nullptr, MLPH, BT, MLPc, Dc);
        mgemm_kernel<0, true><<<dim3(4, 73), 256, 0, stream>>>(
            MLPH, fc2T(l), fc2_b + l * Dc, X, X, BT, Dc, MLPc);
    }

    ln_kernel<<<BT, 256, 0, stream>>>(X, norm_g, norm_b, Hb);
    lnsel_kernel<<<dim3(Nc, Bc), 256, 0, stream>>>(Hb, pol_ln_g, pol_ln_b, PT);
    mgemm_kernel<1, false><<<dim3(4, 72), 256, 0, stream>>>(
        PT, polT, pol_b1, nullptr, PH, Bc * Nc, Dc, Dc);
    logits_kernel<<<Bc * Nc, 256, 0, stream>>>(PH, pol_w2, pol_b2, out);
    value_kernel<<<Bc, 256, 0, stream>>>(
        Hb, val_ln_g, val_ln_b, val_w1, val_b1, val_w2, val_b2, out);
}

// Round 4
// 1633.037 us; speedup vs baseline: 4.1407x; 1.1354x over previous
//
#include <hip/hip_runtime.h>
#include <math.h>

// ---- problem constants ----
constexpr int Hc = 24, Wc = 24, Nc = 576, BINSc = 82, Gc = 2;
constexpr int Tc = Nc + 1 + Gc;          // 579
constexpr int Dc = 256, NHc = 8, HDc = 32, DEPTHc = 6, MLPc = 512;
constexpr int Bc = 16, CINc = 10;
constexpr int BT = Bc * Tc;              // 9264
constexpr float SCALE = 0.17677669529663687f;  // 1/sqrt(32)

typedef _Float16 f16;
typedef _Float16 f16x8 __attribute__((ext_vector_type(8)));
typedef float f32x4 __attribute__((ext_vector_type(4)));

__device__ __forceinline__ float gelu_f(float x) {
    return 0.5f * x * (1.0f + erff(x * 0.70710678118654752f));
}

__device__ __forceinline__ float block_sum256(float v, float* s4) {
    #pragma unroll
    for (int off = 32; off > 0; off >>= 1) v += __shfl_down(v, off, 64);
    __syncthreads();
    if ((threadIdx.x & 63) == 0) s4[threadIdx.x >> 6] = v;
    __syncthreads();
    return s4[0] + s4[1] + s4[2] + s4[3];
}

// ---- embed ----
__global__ __launch_bounds__(256) void embed_kernel(
        const float* __restrict__ obs, const float* __restrict__ iw,
        const float* __restrict__ ib, const float* __restrict__ cls,
        const float* __restrict__ glob, const float* __restrict__ rowe,
        const float* __restrict__ cole, float* __restrict__ x) {
    int t = blockIdx.x, b = blockIdx.y, d = threadIdx.x;
    float v;
    if (t == 0) {
        v = cls[d];
    } else if (t <= Gc) {
        v = glob[(t - 1) * Dc + d];
    } else {
        int n = t - 1 - Gc;
        float acc = ib[d];
        #pragma unroll
        for (int c = 0; c < CINc; ++c)
            acc = fmaf(obs[(b * CINc + c) * Nc + n], iw[c * Dc + d], acc);
        v = acc + rowe[(n / Wc) * Dc + d] + cole[(n % Wc) * Dc + d];
    }
    x[((size_t)b * Tc + t) * Dc + d] = v;
}

// ---- layernorm: one wave per row, float4 + shfl-only (no barriers) ----
__global__ __launch_bounds__(256) void ln4_kernel(
        const float* __restrict__ x, const float* __restrict__ g,
        const float* __restrict__ b, float* __restrict__ out, int nrows) {
    const int w = threadIdx.x >> 6, l = threadIdx.x & 63;
    const int row = blockIdx.x * 4 + w;
    if (row >= nrows) return;
    const float4 v = *reinterpret_cast<const float4*>(x + (size_t)row * Dc + l * 4);
    float s = v.x + v.y + v.z + v.w;
    #pragma unroll
    for (int mk = 1; mk < 64; mk <<= 1) s += __shfl_xor(s, mk, 64);
    const float m = s * (1.0f / 256.0f);
    const float4 d = make_float4(v.x - m, v.y - m, v.z - m, v.w - m);
    float vs = d.x * d.x + d.y * d.y + d.z * d.z + d.w * d.w;
    #pragma unroll
    for (int mk = 1; mk < 64; mk <<= 1) vs += __shfl_xor(vs, mk, 64);
    const float rs = rsqrtf(vs * (1.0f / 256.0f) + 1e-5f);
    const float4 gg = *reinterpret_cast<const float4*>(g + l * 4);
    const float4 bb = *reinterpret_cast<const float4*>(b + l * 4);
    *reinterpret_cast<float4*>(out + (size_t)row * Dc + l * 4) =
        make_float4(d.x * rs * gg.x + bb.x, d.y * rs * gg.y + bb.y,
                    d.z * rs * gg.z + bb.z, d.w * rs * gg.w + bb.w);
}

// ---- LN + gather policy tokens (wave per row) ----
__global__ __launch_bounds__(256) void lnsel4_kernel(
        const float* __restrict__ xn, const float* __restrict__ g,
        const float* __restrict__ b, float* __restrict__ out) {
    const int w = threadIdx.x >> 6, l = threadIdx.x & 63;
    const int rr = blockIdx.x * 4 + w;          // rr in [0, B*N)
    const int bb = rr / Nc, n = rr % Nc;
    const float* xr = xn + ((size_t)bb * Tc + 1 + n) * Dc;
    const float4 v = *reinterpret_cast<const float4*>(xr + l * 4);
    float s = v.x + v.y + v.z + v.w;
    #pragma unroll
    for (int mk = 1; mk < 64; mk <<= 1) s += __shfl_xor(s, mk, 64);
    const float m = s * (1.0f / 256.0f);
    const float4 d = make_float4(v.x - m, v.y - m, v.z - m, v.w - m);
    float vs = d.x * d.x + d.y * d.y + d.z * d.z + d.w * d.w;
    #pragma unroll
    for (int mk = 1; mk < 64; mk <<= 1) vs += __shfl_xor(vs, mk, 64);
    const float rs = rsqrtf(vs * (1.0f / 256.0f) + 1e-5f);
    const float4 gg = *reinterpret_cast<const float4*>(g + l * 4);
    const float4 bb4 = *reinterpret_cast<const float4*>(b + l * 4);
    *reinterpret_cast<float4*>(out + ((size_t)bb * Nc + n) * Dc + l * 4) =
        make_float4(d.x * rs * gg.x + bb4.x, d.y * rs * gg.y + bb4.y,
                    d.z * rs * gg.z + bb4.z, d.w * rs * gg.w + bb4.w);
}

// ---- weight split+transpose: W[K][N] fp32 -> WT_h[N][K], WT_l[N][K] fp16 ----
__global__ __launch_bounds__(256) void split_w_kernel(
        const float* __restrict__ qkv_w, const float* __restrict__ proj_w,
        const float* __restrict__ fc1_w, const float* __restrict__ fc2_w,
        const float* __restrict__ pol_w1, f16* __restrict__ out) {
    int r = blockIdx.x * 256 + threadIdx.x;
    float v; f16* dst; int NK;
    if (r < 1179648) {               // qkv
        int layer = r / 196608, e = r % 196608;
        int n = e >> 8, k = e & 255;
        v = qkv_w[(size_t)layer * 196608 + k * 768 + n];
        dst = out + (size_t)layer * 393216 + n * 256 + k; NK = 196608;
    } else if (r < 1572864) {        // proj
        int rr = r - 1179648; int layer = rr / 65536, e = rr % 65536;
        int n = e >> 8, k = e & 255;
        v = proj_w[(size_t)layer * 65536 + k * 256 + n];
        dst = out + 2359296 + (size_t)layer * 131072 + n * 256 + k; NK = 65536;
    } else if (r < 2359296) {        // fc1 (K=256,N=512)
        int rr = r - 1572864; int layer = rr / 131072, e = rr % 131072;
        int n = e >> 8, k = e & 255;
        v = fc1_w[(size_t)layer * 131072 + k * 512 + n];
        dst = out + 3145728 + (size_t)layer * 262144 + n * 256 + k; NK = 131072;
    } else if (r < 3145728) {        // fc2 (K=512,N=256)
        int rr = r - 2359296; int layer = rr / 131072, e = rr % 131072;
        int n = e >> 9, k = e & 511;
        v = fc2_w[(size_t)layer * 131072 + k * 256 + n];
        dst = out + 4718592 + (size_t)layer * 262144 + n * 512 + k; NK = 131072;
    } else if (r < 3211264) {        // pol_w1
        int rr = r - 3145728; int n = rr >> 8, k = rr & 255;
        v = pol_w1[k * 256 + n];
        dst = out + 6291456 + n * 256 + k; NK = 65536;
    } else return;
    f16 h = (f16)v;
    dst[0] = h;
    dst[NK] = (f16)(v - (float)h);
}

// ---- fp16x3 MFMA GEMM (unchanged from round 3) ----
__device__ __forceinline__ int swz(int r, int g) {
    return r * 40 + ((g ^ ((r >> 3) & 3)) << 3);
}
template <int ACT, bool RES>
__global__ __launch_bounds__(256) void mgemm_kernel(
        const float* __restrict__ A, const f16* __restrict__ WT,
        const float* __restrict__ bias, const float* __restrict__ res,
        float* __restrict__ C, int M, int N, int K) {
    constexpr int BM = 128, BN = 64, BK = 32;
    __shared__ f16 Ah[BM * 40], Al[BM * 40];
    __shared__ f16 Bh[BN * 40], Bl[BN * 40];
    const int tid = threadIdx.x;
    const int m0 = blockIdx.y * BM, n0 = blockIdx.x * BN;
    const int w = tid >> 6, l = tid & 63;
    const int wm = (w >> 1) * 64, wn = (w & 1) * 32;
    const int lg = l >> 4, lr = l & 15;
    f32x4 acc[4][2] = {};
    const int sa_row = tid >> 1, sa_kc = (tid & 1) * 16;
    const int sb_part = tid >> 7;
    const int sb_n = (tid & 127) >> 1, sb_kc = (tid & 1) * 16;

    for (int k0 = 0; k0 < K; k0 += BK) {
        {
            int gr = m0 + sa_row; if (gr >= M) gr = M - 1;
            const float4* src = reinterpret_cast<const float4*>(
                A + (size_t)gr * K + k0 + sa_kc);
            f16x8 hv0, hv1, lv0, lv1;
            #pragma unroll
            for (int c = 0; c < 4; ++c) {
                float4 v = src[c];
                f16 h0 = (f16)v.x, h1 = (f16)v.y, h2 = (f16)v.z, h3 = (f16)v.w;
                f16 l0 = (f16)(v.x - (float)h0), l1 = (f16)(v.y - (float)h1);
                f16 l2 = (f16)(v.z - (float)h2), l3 = (f16)(v.w - (float)h3);
                if (c < 2) {
                    hv0[c * 4 + 0] = h0; hv0[c * 4 + 1] = h1;
                    hv0[c * 4 + 2] = h2; hv0[c * 4 + 3] = h3;
                    lv0[c * 4 + 0] = l0; lv0[c * 4 + 1] = l1;
                    lv0[c * 4 + 2] = l2; lv0[c * 4 + 3] = l3;
                } else {
                    hv1[(c - 2) * 4 + 0] = h0; hv1[(c - 2) * 4 + 1] = h1;
                    hv1[(c - 2) * 4 + 2] = h2; hv1[(c - 2) * 4 + 3] = h3;
                    lv1[(c - 2) * 4 + 0] = l0; lv1[(c - 2) * 4 + 1] = l1;
                    lv1[(c - 2) * 4 + 2] = l2; lv1[(c - 2) * 4 + 3] = l3;
                }
            }
            const int g0 = sa_kc >> 3;
            *reinterpret_cast<f16x8*>(&Ah[swz(sa_row, g0)])     = hv0;
            *reinterpret_cast<f16x8*>(&Ah[swz(sa_row, g0 + 1)]) = hv1;
            *reinterpret_cast<f16x8*>(&Al[swz(sa_row, g0)])     = lv0;
            *reinterpret_cast<f16x8*>(&Al[swz(sa_row, g0 + 1)]) = lv1;
        }
        {
            const f16x8* src = reinterpret_cast<const f16x8*>(
                WT + (size_t)sb_part * N * K + (size_t)(n0 + sb_n) * K + k0 + sb_kc);
            f16* dbase = sb_part ? Bl : Bh;
            const int g0 = sb_kc >> 3;
            *reinterpret_cast<f16x8*>(&dbase[swz(sb_n, g0)])     = src[0];
            *reinterpret_cast<f16x8*>(&dbase[swz(sb_n, g0 + 1)]) = src[1];
        }
        __syncthreads();
        f16x8 afh[4], afl[4], bfh[2], bfl[2];
        #pragma unroll
        for (int mi = 0; mi < 4; ++mi) {
            int row = wm + mi * 16 + lr;
            afh[mi] = *reinterpret_cast<const f16x8*>(&Ah[swz(row, lg)]);
            afl[mi] = *reinterpret_cast<const f16x8*>(&Al[swz(row, lg)]);
        }
        #pragma unroll
        for (int ni = 0; ni < 2; ++ni) {
            int col = wn + ni * 16 + lr;
            bfh[ni] = *reinterpret_cast<const f16x8*>(&Bh[swz(col, lg)]);
            bfl[ni] = *reinterpret_cast<const f16x8*>(&Bl[swz(col, lg)]);
        }
        #pragma unroll
        for (int mi = 0; mi < 4; ++mi)
            #pragma unroll
            for (int ni = 0; ni < 2; ++ni) {
                acc[mi][ni] = __builtin_amdgcn_mfma_f32_16x16x32_f16(
                    afh[mi], bfh[ni], acc[mi][ni], 0, 0, 0);
                acc[mi][ni] = __builtin_amdgcn_mfma_f32_16x16x32_f16(
                    afh[mi], bfl[ni], acc[mi][ni], 0, 0, 0);
                acc[mi][ni] = __builtin_amdgcn_mfma_f32_16x16x32_f16(
                    afl[mi], bfh[ni], acc[mi][ni], 0, 0, 0);
            }
        __syncthreads();
    }
    float bv[2];
    #pragma unroll
    for (int ni = 0; ni < 2; ++ni) bv[ni] = bias[n0 + wn + ni * 16 + lr];
    #pragma unroll
    for (int mi = 0; mi < 4; ++mi) {
        #pragma unroll
        for (int r = 0; r < 4; ++r) {
            int grow = m0 + wm + mi * 16 + lg * 4 + r;
            if (grow < M) {
                #pragma unroll
                for (int ni = 0; ni < 2; ++ni) {
                    int gcol = n0 + wn + ni * 16 + lr;
                    float v = acc[mi][ni][r] + bv[ni];
                    if (ACT == 1) v = gelu_f(v);
                    if (RES) v += res[(size_t)grow * N + gcol];
                    C[(size_t)grow * N + gcol] = v;
                }
            }
        }
    }
}

// ---- MFMA flash attention ----
// Block = (b*NH, q-tile of 64). 4 waves x 16 q-rows. HD=32 = one MFMA K-depth.
// Q in registers (A-frag, split h/l). K in LDS (B-frag layout, split).
// V^T in LDS (B-frag for PV, split). Scores/PV: fp16x3 split MFMA.
// Online softmax directly on C-layout regs (row=(lane>>4)*4+r, col=lane&15).
__global__ __launch_bounds__(256) void mattn_kernel(
        const float* __restrict__ qkv, const float* __restrict__ relb,
        const int* __restrict__ relidx, float* __restrict__ o) {
    __shared__ f16 Kh[64][40], Kl[64][40];        // 10240 B
    __shared__ f16 VTh[32][72], VTl[32][72];      // 9216 B
    __shared__ float Ps[4][16][68];               // 17408 B (wave-private rows)
    __shared__ float bias_s[BINSc];
    const int tid = threadIdx.x;
    const int b = blockIdx.x / NHc, h = blockIdx.x % NHc;
    const int q0 = blockIdx.y * 64;
    const int w = tid >> 6, l = tid & 63;
    const int lr = l & 15, lg = l >> 4;
    if (tid < BINSc) bias_s[tid] = relb[h * BINSc + tid];

    // Q A-fragment: row = q0 + w*16 + lr, k = lg*8 + e  (HD=32 exactly)
    int qrow = q0 + w * 16 + lr; if (qrow >= Tc) qrow = Tc - 1;
    f16x8 Qh, Ql;
    {
        const float* qsrc = qkv + ((size_t)(b * Tc + qrow) * 3 + 0) * Dc + h * HDc + lg * 8;
        const float4 q01 = *reinterpret_cast<const float4*>(qsrc);
        const float4 q23 = *reinterpret_cast<const float4*>(qsrc + 4);
        const float qa[8] = {q01.x, q01.y, q01.z, q01.w, q23.x, q23.y, q23.z, q23.w};
        #pragma unroll
        for (int e = 0; e < 8; ++e) {
            f16 hh = (f16)qa[e];
            Qh[e] = hh; Ql[e] = (f16)(qa[e] - (float)hh);
        }
    }
    // my q-rows for softmax state: q = q0 + w*16 + lg*4 + r
    const int myq = q0 + w * 16 + lg * 4;

    // staging roles
    const int skrow = tid >> 2, skc = (tid & 3) * 8;        // K: 64 rows x 4 chunks
    const int svkey = (tid & 31) * 2, svd = (tid >> 5) * 4; // V: 32 key-pairs x 8 d-chunks

    float m_run[4], l_run[4];
    f32x4 Oacc[2] = {};
    #pragma unroll
    for (int r = 0; r < 4; ++r) { m_run[r] = -1e30f; l_run[r] = 0.f; }

    for (int t = 0; t < 10; ++t) {
        const int k0 = t * 64;
        __syncthreads();  // previous iteration's K/VT reads complete
        // ---- stage K (split h/l, B-frag row-major [key][k]) ----
        {
            int gk = k0 + skrow; if (gk >= Tc) gk = Tc - 1;
            const float* src = qkv + ((size_t)(b * Tc + gk) * 3 + 1) * Dc + h * HDc + skc;
            const float4 a = *reinterpret_cast<const float4*>(src);
            const float4 c = *reinterpret_cast<const float4*>(src + 4);
            const float va[8] = {a.x, a.y, a.z, a.w, c.x, c.y, c.z, c.w};
            f16x8 hv, lv;
            #pragma unroll
            for (int e = 0; e < 8; ++e) {
                f16 hh = (f16)va[e];
                hv[e] = hh; lv[e] = (f16)(va[e] - (float)hh);
            }
            *reinterpret_cast<f16x8*>(&Kh[skrow][skc]) = hv;
            *reinterpret_cast<f16x8*>(&Kl[skrow][skc]) = lv;
        }
        // ---- stage V transposed (VT[d][key]), packed u32 writes ----
        {
            int gk0 = k0 + svkey, gk1 = gk0 + 1;
            if (gk0 >= Tc) gk0 = Tc - 1;
            if (gk1 >= Tc) gk1 = Tc - 1;
            const float* s0 = qkv + ((size_t)(b * Tc + gk0) * 3 + 2) * Dc + h * HDc + svd;
            const float* s1 = qkv + ((size_t)(b * Tc + gk1) * 3 + 2) * Dc + h * HDc + svd;
            const float4 a = *reinterpret_cast<const float4*>(s0);
            const float4 c = *reinterpret_cast<const float4*>(s1);
            const float va0[4] = {a.x, a.y, a.z, a.w};
            const float va1[4] = {c.x, c.y, c.z, c.w};
            #pragma unroll
            for (int i = 0; i < 4; ++i) {
                f16 h0 = (f16)va0[i], h1 = (f16)va1[i];
                f16 l0 = (f16)(va0[i] - (float)h0), l1 = (f16)(va1[i] - (float)h1);
                unsigned hp = (unsigned)__builtin_bit_cast(unsigned short, h0) |
                              ((unsigned)__builtin_bit_cast(unsigned short, h1) << 16);
                unsigned lp = (unsigned)__builtin_bit_cast(unsigned short, l0) |
                              ((unsigned)__builtin_bit_cast(unsigned short, l1) << 16);
                *reinterpret_cast<unsigned*>(&VTh[svd + i][svkey]) = hp;
                *reinterpret_cast<unsigned*>(&VTl[svd + i][svkey]) = lp;
            }
        }
        __syncthreads();  // K/VT ready
        // ---- scores: 4 tiles of 16 keys, 3 MFMA each ----
        f32x4 sc[4];
        #pragma unroll
        for (int j = 0; j < 4; ++j) {
            const f16x8 kh = *reinterpret_cast<const f16x8*>(&Kh[j * 16 + lr][lg * 8]);
            const f16x8 kl = *reinterpret_cast<const f16x8*>(&Kl[j * 16 + lr][lg * 8]);
            f32x4 s = {};
            s = __builtin_amdgcn_mfma_f32_16x16x32_f16(Qh, kh, s, 0, 0, 0);
            s = __builtin_amdgcn_mfma_f32_16x16x32_f16(Qh, kl, s, 0, 0, 0);
            s = __builtin_amdgcn_mfma_f32_16x16x32_f16(Ql, kh, s, 0, 0, 0);
            sc[j] = s;
        }
        // ---- scale + rel-bias + tail mask ----
        #pragma unroll
        for (int j = 0; j < 4; ++j) {
            const int kk = k0 + j * 16 + lr;
            const int kksafe = kk < Tc ? kk : Tc - 1;
            #pragma unroll
            for (int r = 0; r < 4; ++r) {
                const int qq = myq + r < Tc ? myq + r : Tc - 1;
                float v = fmaf(sc[j][r], SCALE, bias_s[relidx[qq * Tc + kksafe]]);
                sc[j][r] = (kk < Tc) ? v : -1e30f;
            }
        }
        // ---- online softmax (per row r; 16 lanes of same lg share a row) ----
        #pragma unroll
        for (int r = 0; r < 4; ++r) {
            float tm = fmaxf(fmaxf(sc[0][r], sc[1][r]), fmaxf(sc[2][r], sc[3][r]));
            #pragma unroll
            for (int mk = 1; mk < 16; mk <<= 1) tm = fmaxf(tm, __shfl_xor(tm, mk, 64));
            const float mn = fmaxf(m_run[r], tm);
            const float resc = __expf(m_run[r] - mn);
            m_run[r] = mn;
            float ls = 0.f;
            #pragma unroll
            for (int j = 0; j < 4; ++j) {
                sc[j][r] = __expf(sc[j][r] - mn);
                ls += sc[j][r];
            }
            #pragma unroll
            for (int mk = 1; mk < 16; mk <<= 1) ls += __shfl_xor(ls, mk, 64);
            l_run[r] = l_run[r] * resc + ls;
            Oacc[0][r] *= resc; Oacc[1][r] *= resc;
            // write P row (wave-private LDS region)
            #pragma unroll
            for (int j = 0; j < 4; ++j)
                Ps[w][lg * 4 + r][j * 16 + lr] = sc[j][r];
        }
        // ---- PV: P A-frag (from LDS, re-split), VT B-frag; 12 MFMA ----
        #pragma unroll
        for (int kc = 0; kc < 2; ++kc) {
            const float* pr = &Ps[w][lr][kc * 32 + lg * 8];
            const float4 p0 = *reinterpret_cast<const float4*>(pr);
            const float4 p1 = *reinterpret_cast<const float4*>(pr + 4);
            const float pa[8] = {p0.x, p0.y, p0.z, p0.w, p1.x, p1.y, p1.z, p1.w};
            f16x8 Ph, Pl;
            #pragma unroll
            for (int e = 0; e < 8; ++e) {
                f16 hh = (f16)pa[e];
                Ph[e] = hh; Pl[e] = (f16)(pa[e] - (float)hh);
            }
            #pragma unroll
            for (int dt = 0; dt < 2; ++dt) {
                const f16x8 vh = *reinterpret_cast<const f16x8*>(&VTh[dt * 16 + lr][kc * 32 + lg * 8]);
                const f16x8 vl = *reinterpret_cast<const f16x8*>(&VTl[dt * 16 + lr][kc * 32 + lg * 8]);
                Oacc[dt] = __builtin_amdgcn_mfma_f32_16x16x32_f16(Ph, vh, Oacc[dt], 0, 0, 0);
                Oacc[dt] = __builtin_amdgcn_mfma_f32_16x16x32_f16(Ph, vl, Oacc[dt], 0, 0, 0);
                Oacc[dt] = __builtin_amdgcn_mfma_f32_16x16x32_f16(Pl, vh, Oacc[dt], 0, 0, 0);
            }
        }
    }
    // ---- store: row = myq + r, col = dt*16 + lr ----
    #pragma unroll
    for (int r = 0; r < 4; ++r) {
        const int qq = myq + r;
        if (qq < Tc) {
            const float inv = 1.0f / l_run[r];
            float* op = o + ((size_t)b * Tc + qq) * Dc + h * HDc;
            op[lr]      = Oacc[0][r] * inv;
            op[16 + lr] = Oacc[1][r] * inv;
        }
    }
}

// ---- logits ----
__global__ __launch_bounds__(256) void logits_kernel(
        const float* __restrict__ ph, const float* __restrict__ w2,
        const float* __restrict__ b2, float* __restrict__ out) {
    __shared__ float s4[4];
    size_t r = blockIdx.x;
    int bb = (int)(r / Nc), n = (int)(r % Nc);
    float v = ph[r * Dc + threadIdx.x] * w2[threadIdx.x];
    float s = block_sum256(v, s4);
    if (threadIdx.x == 0) out[bb * (Nc + 1) + n] = s + b2[0];
}

// ---- value head ----
__global__ __launch_bounds__(256) void value_kernel(
        const float* __restrict__ xn, const float* __restrict__ g,
        const float* __restrict__ b, const float* __restrict__ w1,
        const float* __restrict__ b1, const float* __restrict__ w2,
        const float* __restrict__ b2, float* __restrict__ out) {
    __shared__ float s4[4];
    __shared__ float ts[Dc];
    const int bb = blockIdx.x, tid = threadIdx.x;
    float v = xn[(size_t)bb * Tc * Dc + tid];
    float m = block_sum256(v, s4) * (1.0f / 256.0f);
    float d = v - m;
    float var = block_sum256(d * d, s4) * (1.0f / 256.0f);
    ts[tid] = d * rsqrtf(var + 1e-5f) * g[tid] + b[tid];
    __syncthreads();
    float acc = b1[tid];
    #pragma unroll 8
    for (int i = 0; i < Dc; ++i) acc = fmaf(ts[i], w1[i * Dc + tid], acc);
    float hv = gelu_f(acc) * w2[tid];
    float s = block_sum256(hv, s4);
    if (tid == 0) out[bb * (Nc + 1) + Nc] = s + b2[0];
}

extern "C" void kernel_launch(void* const* d_in, const int* in_sizes, int n_in,
                              void* d_out, int out_size, void* d_ws, size_t ws_size,
                              hipStream_t stream) {
    const float* obs      = (const float*)d_in[0];
    const float* input_w  = (const float*)d_in[1];
    const float* input_b  = (const float*)d_in[2];
    const float* cls_tok  = (const float*)d_in[3];
    const float* glob_tok = (const float*)d_in[4];
    const float* row_emb  = (const float*)d_in[5];
    const float* col_emb  = (const float*)d_in[6];
    const float* ln1_g    = (const float*)d_in[7];
    const float* ln1_b    = (const float*)d_in[8];
    const float* qkv_w    = (const float*)d_in[9];
    const float* qkv_b    = (const float*)d_in[10];
    const float* proj_w   = (const float*)d_in[11];
    const float* proj_b   = (const float*)d_in[12];
    const float* rel_bias = (const float*)d_in[13];
    const float* ln2_g    = (const float*)d_in[14];
    const float* ln2_b    = (const float*)d_in[15];
    const float* fc1_w    = (const float*)d_in[16];
    const float* fc1_b    = (const float*)d_in[17];
    const float* fc2_w    = (const float*)d_in[18];
    const float* fc2_b    = (const float*)d_in[19];
    const float* norm_g   = (const float*)d_in[20];
    const float* norm_b   = (const float*)d_in[21];
    const float* pol_ln_g = (const float*)d_in[22];
    const float* pol_ln_b = (const float*)d_in[23];
    const float* pol_w1   = (const float*)d_in[24];
    const float* pol_b1   = (const float*)d_in[25];
    const float* pol_w2   = (const float*)d_in[26];
    const float* pol_b2   = (const float*)d_in[27];
    const float* val_ln_g = (const float*)d_in[28];
    const float* val_ln_b = (const float*)d_in[29];
    const float* val_w1   = (const float*)d_in[30];
    const float* val_b1   = (const float*)d_in[31];
    const float* val_w2   = (const float*)d_in[32];
    const float* val_b2   = (const float*)d_in[33];
    const int*   rel_idx  = (const int*)d_in[34];
    float* out = (float*)d_out;

    float* ws = (float*)d_ws;
    const size_t SZ_XD = (size_t)BT * Dc;        // 2,371,584 floats
    float* X    = ws;
    float* Hb   = ws + SZ_XD;
    float* QKV  = ws + 2 * SZ_XD;                // 3*SZ_XD floats
    float* MLPH = QKV;
    float* PT   = QKV;
    float* PH   = QKV + (size_t)Bc * Nc * Dc;
    f16* wsplit = (f16*)(ws + 5 * SZ_XD);        // 6,422,528 f16 = 12.85 MB

    auto qkvT = [&](int l) { return wsplit + (size_t)l * 393216; };
    auto projT = [&](int l) { return wsplit + 2359296 + (size_t)l * 131072; };
    auto fc1T = [&](int l) { return wsplit + 3145728 + (size_t)l * 262144; };
    auto fc2T = [&](int l) { return wsplit + 4718592 + (size_t)l * 262144; };
    f16* polT = wsplit + 6291456;

    split_w_kernel<<<12544, 256, 0, stream>>>(
        qkv_w, proj_w, fc1_w, fc2_w, pol_w1, wsplit);

    embed_kernel<<<dim3(Tc, Bc), 256, 0, stream>>>(
        obs, input_w, input_b, cls_tok, glob_tok, row_emb, col_emb, X);

    for (int l = 0; l < DEPTHc; ++l) {
        ln4_kernel<<<(BT + 3) / 4, 256, 0, stream>>>(
            X, ln1_g + l * Dc, ln1_b + l * Dc, Hb, BT);
        mgemm_kernel<0, false><<<dim3(12, 73), 256, 0, stream>>>(
            Hb, qkvT(l), qkv_b + l * 3 * Dc, nullptr, QKV, BT, 3 * Dc, Dc);
        mattn_kernel<<<dim3(Bc * NHc, 10), 256, 0, stream>>>(
            QKV, rel_bias + l * NHc * BINSc, rel_idx, Hb);
        mgemm_kernel<0, true><<<dim3(4, 73), 256, 0, stream>>>(
            Hb, projT(l), proj_b + l * Dc, X, X, BT, Dc, Dc);
        ln4_kernel<<<(BT + 3) / 4, 256, 0, stream>>>(
            X, ln2_g + l * Dc, ln2_b + l * Dc, Hb, BT);
        mgemm_kernel<1, false><<<dim3(8, 73), 256, 0, stream>>>(
            Hb, fc1T(l), fc1_b + l * MLPc, nullptr, MLPH, BT, MLPc, Dc);
        mgemm_kernel<0, true><<<dim3(4, 73), 256, 0, stream>>>(
            MLPH, fc2T(l), fc2_b + l * Dc, X, X, BT, Dc, MLPc);
    }

    ln4_kernel<<<(BT + 3) / 4, 256, 0, stream>>>(X, norm_g, norm_b, Hb, BT);
    lnsel4_kernel<<<Bc * Nc / 4, 256, 0, stream>>>(Hb, pol_ln_g, pol_ln_b, PT);
    mgemm_kernel<1, false><<<dim3(4, 72), 256, 0, stream>>>(
        PT, polT, pol_b1, nullptr, PH, Bc * Nc, Dc, Dc);
    logits_kernel<<<Bc * Nc, 256, 0, stream>>>(PH, pol_w2, pol_b2, out);
    value_kernel<<<Bc, 256, 0, stream>>>(
        Hb, val_ln_g, val_ln_b, val_w1, val_b1, val_w2, val_b2, out);
}

// Round 5
// 1612.977 us; speedup vs baseline: 4.1922x; 1.0124x over previous
//
#include <hip/hip_runtime.h>
#include <math.h>

// ---- problem constants ----
constexpr int Hc = 24, Wc = 24, Nc = 576, BINSc = 82, Gc = 2;
constexpr int Tc = Nc + 1 + Gc;          // 579
constexpr int Dc = 256, NHc = 8, HDc = 32, DEPTHc = 6, MLPc = 512;
constexpr int Bc = 16, CINc = 10;
constexpr int BT = Bc * Tc;              // 9264
constexpr float SCALE = 0.17677669529663687f;  // 1/sqrt(32)

typedef _Float16 f16;
typedef _Float16 f16x8 __attribute__((ext_vector_type(8)));
typedef float f32x4 __attribute__((ext_vector_type(4)));

// ---- split-QKV region layout (f16 elements, base = R) ----
constexpr size_t QK_ST   = (size_t)BT * 256;           // 2,371,584
constexpr int    VT_PAD  = 640;                        // key-dim pad (>=579+61)
constexpr size_t VT_ST   = (size_t)Bc * NHc * 32 * VT_PAD;  // 2,621,440
constexpr size_t OFF_KH  = 2 * QK_ST;
constexpr size_t OFF_VTH = 4 * QK_ST;
constexpr size_t OFF_BIAS = 4 * QK_ST + 2 * VT_ST;
constexpr size_t R_F16   = OFF_BIAS + (size_t)NHc * Tc * Tc;  // 17,411,144
constexpr size_t R_FLOATS = 8705576;                   // ceil(R_F16/2), +align

__device__ __forceinline__ float gelu_f(float x) {
    return 0.5f * x * (1.0f + erff(x * 0.70710678118654752f));
}

__device__ __forceinline__ float block_sum256(float v, float* s4) {
    #pragma unroll
    for (int off = 32; off > 0; off >>= 1) v += __shfl_down(v, off, 64);
    __syncthreads();
    if ((threadIdx.x & 63) == 0) s4[threadIdx.x >> 6] = v;
    __syncthreads();
    return s4[0] + s4[1] + s4[2] + s4[3];
}

// ---- embed ----
__global__ __launch_bounds__(256) void embed_kernel(
        const float* __restrict__ obs, const float* __restrict__ iw,
        const float* __restrict__ ib, const float* __restrict__ cls,
        const float* __restrict__ glob, const float* __restrict__ rowe,
        const float* __restrict__ cole, float* __restrict__ x) {
    int t = blockIdx.x, b = blockIdx.y, d = threadIdx.x;
    float v;
    if (t == 0) {
        v = cls[d];
    } else if (t <= Gc) {
        v = glob[(t - 1) * Dc + d];
    } else {
        int n = t - 1 - Gc;
        float acc = ib[d];
        #pragma unroll
        for (int c = 0; c < CINc; ++c)
            acc = fmaf(obs[(b * CINc + c) * Nc + n], iw[c * Dc + d], acc);
        v = acc + rowe[(n / Wc) * Dc + d] + cole[(n % Wc) * Dc + d];
    }
    x[((size_t)b * Tc + t) * Dc + d] = v;
}

// ---- layernorm: one wave per row ----
__global__ __launch_bounds__(256) void ln4_kernel(
        const float* __restrict__ x, const float* __restrict__ g,
        const float* __restrict__ b, float* __restrict__ out, int nrows) {
    const int w = threadIdx.x >> 6, l = threadIdx.x & 63;
    const int row = blockIdx.x * 4 + w;
    if (row >= nrows) return;
    const float4 v = *reinterpret_cast<const float4*>(x + (size_t)row * Dc + l * 4);
    float s = v.x + v.y + v.z + v.w;
    #pragma unroll
    for (int mk = 1; mk < 64; mk <<= 1) s += __shfl_xor(s, mk, 64);
    const float m = s * (1.0f / 256.0f);
    const float4 d = make_float4(v.x - m, v.y - m, v.z - m, v.w - m);
    float vs = d.x * d.x + d.y * d.y + d.z * d.z + d.w * d.w;
    #pragma unroll
    for (int mk = 1; mk < 64; mk <<= 1) vs += __shfl_xor(vs, mk, 64);
    const float rs = rsqrtf(vs * (1.0f / 256.0f) + 1e-5f);
    const float4 gg = *reinterpret_cast<const float4*>(g + l * 4);
    const float4 bb = *reinterpret_cast<const float4*>(b + l * 4);
    *reinterpret_cast<float4*>(out + (size_t)row * Dc + l * 4) =
        make_float4(d.x * rs * gg.x + bb.x, d.y * rs * gg.y + bb.y,
                    d.z * rs * gg.z + bb.z, d.w * rs * gg.w + bb.w);
}

// ---- LN + gather policy tokens ----
__global__ __launch_bounds__(256) void lnsel4_kernel(
        const float* __restrict__ xn, const float* __restrict__ g,
        const float* __restrict__ b, float* __restrict__ out) {
    const int w = threadIdx.x >> 6, l = threadIdx.x & 63;
    const int rr = blockIdx.x * 4 + w;
    const int bb = rr / Nc, n = rr % Nc;
    const float* xr = xn + ((size_t)bb * Tc + 1 + n) * Dc;
    const float4 v = *reinterpret_cast<const float4*>(xr + l * 4);
    float s = v.x + v.y + v.z + v.w;
    #pragma unroll
    for (int mk = 1; mk < 64; mk <<= 1) s += __shfl_xor(s, mk, 64);
    const float m = s * (1.0f / 256.0f);
    const float4 d = make_float4(v.x - m, v.y - m, v.z - m, v.w - m);
    float vs = d.x * d.x + d.y * d.y + d.z * d.z + d.w * d.w;
    #pragma unroll
    for (int mk = 1; mk < 64; mk <<= 1) vs += __shfl_xor(vs, mk, 64);
    const float rs = rsqrtf(vs * (1.0f / 256.0f) + 1e-5f);
    const float4 gg = *reinterpret_cast<const float4*>(g + l * 4);
    const float4 bb4 = *reinterpret_cast<const float4*>(b + l * 4);
    *reinterpret_cast<float4*>(out + ((size_t)bb * Nc + n) * Dc + l * 4) =
        make_float4(d.x * rs * gg.x + bb4.x, d.y * rs * gg.y + bb4.y,
                    d.z * rs * gg.z + bb4.z, d.w * rs * gg.w + bb4.w);
}

// ---- weight split+transpose (unchanged) ----
__global__ __launch_bounds__(256) void split_w_kernel(
        const float* __restrict__ qkv_w, const float* __restrict__ proj_w,
        const float* __restrict__ fc1_w, const float* __restrict__ fc2_w,
        const float* __restrict__ pol_w1, f16* __restrict__ out) {
    int r = blockIdx.x * 256 + threadIdx.x;
    float v; f16* dst; int NK;
    if (r < 1179648) {
        int layer = r / 196608, e = r % 196608;
        int n = e >> 8, k = e & 255;
        v = qkv_w[(size_t)layer * 196608 + k * 768 + n];
        dst = out + (size_t)layer * 393216 + n * 256 + k; NK = 196608;
    } else if (r < 1572864) {
        int rr = r - 1179648; int layer = rr / 65536, e = rr % 65536;
        int n = e >> 8, k = e & 255;
        v = proj_w[(size_t)layer * 65536 + k * 256 + n];
        dst = out + 2359296 + (size_t)layer * 131072 + n * 256 + k; NK = 65536;
    } else if (r < 2359296) {
        int rr = r - 1572864; int layer = rr / 131072, e = rr % 131072;
        int n = e >> 8, k = e & 255;
        v = fc1_w[(size_t)layer * 131072 + k * 512 + n];
        dst = out + 3145728 + (size_t)layer * 262144 + n * 256 + k; NK = 131072;
    } else if (r < 3145728) {
        int rr = r - 2359296; int layer = rr / 131072, e = rr % 131072;
        int n = e >> 9, k = e & 511;
        v = fc2_w[(size_t)layer * 131072 + k * 256 + n];
        dst = out + 4718592 + (size_t)layer * 262144 + n * 512 + k; NK = 131072;
    } else if (r < 3211264) {
        int rr = r - 3145728; int n = rr >> 8, k = rr & 255;
        v = pol_w1[k * 256 + n];
        dst = out + 6291456 + n * 256 + k; NK = 65536;
    } else return;
    f16 h = (f16)v;
    dst[0] = h;
    dst[NK] = (f16)(v - (float)h);
}

// ---- dense rel-bias table for one layer: bias[h][q][k] fp16 ----
__global__ __launch_bounds__(128) void biasgen_kernel(
        const float* __restrict__ relb, const int* __restrict__ relidx,
        f16* __restrict__ bias) {
    const int q = blockIdx.x, h = blockIdx.y;
    for (int k = threadIdx.x; k < Tc; k += 128)
        bias[((size_t)h * Tc + q) * Tc + k] =
            (f16)relb[h * BINSc + relidx[q * Tc + k]];
}

// ---- fp16x3 MFMA GEMM. ACT: 0=none, 1=gelu, 2=QKV-split-out ----
__device__ __forceinline__ int swz(int r, int g) {
    return r * 40 + ((g ^ ((r >> 3) & 3)) << 3);
}
template <int ACT, bool RES>
__global__ __launch_bounds__(256) void mgemm_kernel(
        const float* __restrict__ A, const f16* __restrict__ WT,
        const float* __restrict__ bias, const float* __restrict__ res,
        float* __restrict__ C, int M, int N, int K) {
    constexpr int BM = 128, BN = 64, BK = 32;
    __shared__ f16 Ah[BM * 40], Al[BM * 40];
    __shared__ f16 Bh[BN * 40], Bl[BN * 40];
    const int tid = threadIdx.x;
    const int m0 = blockIdx.y * BM, n0 = blockIdx.x * BN;
    const int w = tid >> 6, l = tid & 63;
    const int wm = (w >> 1) * 64, wn = (w & 1) * 32;
    const int lg = l >> 4, lr = l & 15;
    f32x4 acc[4][2] = {};
    const int sa_row = tid >> 1, sa_kc = (tid & 1) * 16;
    const int sb_part = tid >> 7;
    const int sb_n = (tid & 127) >> 1, sb_kc = (tid & 1) * 16;

    for (int k0 = 0; k0 < K; k0 += BK) {
        {
            int gr = m0 + sa_row; if (gr >= M) gr = M - 1;
            const float4* src = reinterpret_cast<const float4*>(
                A + (size_t)gr * K + k0 + sa_kc);
            f16x8 hv0, hv1, lv0, lv1;
            #pragma unroll
            for (int c = 0; c < 4; ++c) {
                float4 v = src[c];
                f16 h0 = (f16)v.x, h1 = (f16)v.y, h2 = (f16)v.z, h3 = (f16)v.w;
                f16 l0 = (f16)(v.x - (float)h0), l1 = (f16)(v.y - (float)h1);
                f16 l2 = (f16)(v.z - (float)h2), l3 = (f16)(v.w - (float)h3);
                if (c < 2) {
                    hv0[c * 4 + 0] = h0; hv0[c * 4 + 1] = h1;
                    hv0[c * 4 + 2] = h2; hv0[c * 4 + 3] = h3;
                    lv0[c * 4 + 0] = l0; lv0[c * 4 + 1] = l1;
                    lv0[c * 4 + 2] = l2; lv0[c * 4 + 3] = l3;
                } else {
                    hv1[(c - 2) * 4 + 0] = h0; hv1[(c - 2) * 4 + 1] = h1;
                    hv1[(c - 2) * 4 + 2] = h2; hv1[(c - 2) * 4 + 3] = h3;
                    lv1[(c - 2) * 4 + 0] = l0; lv1[(c - 2) * 4 + 1] = l1;
                    lv1[(c - 2) * 4 + 2] = l2; lv1[(c - 2) * 4 + 3] = l3;
                }
            }
            const int g0 = sa_kc >> 3;
            *reinterpret_cast<f16x8*>(&Ah[swz(sa_row, g0)])     = hv0;
            *reinterpret_cast<f16x8*>(&Ah[swz(sa_row, g0 + 1)]) = hv1;
            *reinterpret_cast<f16x8*>(&Al[swz(sa_row, g0)])     = lv0;
            *reinterpret_cast<f16x8*>(&Al[swz(sa_row, g0 + 1)]) = lv1;
        }
        {
            const f16x8* src = reinterpret_cast<const f16x8*>(
                WT + (size_t)sb_part * N * K + (size_t)(n0 + sb_n) * K + k0 + sb_kc);
            f16* dbase = sb_part ? Bl : Bh;
            const int g0 = sb_kc >> 3;
            *reinterpret_cast<f16x8*>(&dbase[swz(sb_n, g0)])     = src[0];
            *reinterpret_cast<f16x8*>(&dbase[swz(sb_n, g0 + 1)]) = src[1];
        }
        __syncthreads();
        f16x8 afh[4], afl[4], bfh[2], bfl[2];
        #pragma unroll
        for (int mi = 0; mi < 4; ++mi) {
            int row = wm + mi * 16 + lr;
            afh[mi] = *reinterpret_cast<const f16x8*>(&Ah[swz(row, lg)]);
            afl[mi] = *reinterpret_cast<const f16x8*>(&Al[swz(row, lg)]);
        }
        #pragma unroll
        for (int ni = 0; ni < 2; ++ni) {
            int col = wn + ni * 16 + lr;
            bfh[ni] = *reinterpret_cast<const f16x8*>(&Bh[swz(col, lg)]);
            bfl[ni] = *reinterpret_cast<const f16x8*>(&Bl[swz(col, lg)]);
        }
        #pragma unroll
        for (int mi = 0; mi < 4; ++mi)
            #pragma unroll
            for (int ni = 0; ni < 2; ++ni) {
                acc[mi][ni] = __builtin_amdgcn_mfma_f32_16x16x32_f16(
                    afh[mi], bfh[ni], acc[mi][ni], 0, 0, 0);
                acc[mi][ni] = __builtin_amdgcn_mfma_f32_16x16x32_f16(
                    afh[mi], bfl[ni], acc[mi][ni], 0, 0, 0);
                acc[mi][ni] = __builtin_amdgcn_mfma_f32_16x16x32_f16(
                    afl[mi], bfh[ni], acc[mi][ni], 0, 0, 0);
            }
        __syncthreads();
    }
    float bv[2];
    #pragma unroll
    for (int ni = 0; ni < 2; ++ni) bv[ni] = bias[n0 + wn + ni * 16 + lr];
    #pragma unroll
    for (int mi = 0; mi < 4; ++mi) {
        #pragma unroll
        for (int r = 0; r < 4; ++r) {
            int grow = m0 + wm + mi * 16 + lg * 4 + r;
            if (grow >= M) continue;
            if constexpr (ACT == 2) {
                // QKV split-fp16 epilogue. base = (f16*)C.
                f16* base = (f16*)C;
                const int bb = grow / Tc;
                const int tt = grow - bb * Tc;
                #pragma unroll
                for (int ni = 0; ni < 2; ++ni) {
                    const int gcol = n0 + wn + ni * 16 + lr;
                    float v = acc[mi][ni][r] + bv[ni];
                    if (gcol < 256) {                       // Q (scaled)
                        v *= SCALE;
                        f16 hh = (f16)v;
                        base[(size_t)grow * 256 + gcol] = hh;
                        base[QK_ST + (size_t)grow * 256 + gcol] = (f16)(v - (float)hh);
                    } else if (gcol < 512) {                // K
                        f16 hh = (f16)v;
                        base[OFF_KH + (size_t)grow * 256 + (gcol - 256)] = hh;
                        base[OFF_KH + QK_ST + (size_t)grow * 256 + (gcol - 256)] =
                            (f16)(v - (float)hh);
                    } else {                                // V transposed
                        const int e = gcol - 512;
                        const int hh_ = e >> 5, dd = e & 31;
                        const size_t o =
                            ((size_t)((bb * NHc + hh_) * 32 + dd)) * VT_PAD + tt;
                        f16 hh = (f16)v;
                        base[OFF_VTH + o] = hh;
                        base[OFF_VTH + VT_ST + o] = (f16)(v - (float)hh);
                    }
                }
            } else {
                #pragma unroll
                for (int ni = 0; ni < 2; ++ni) {
                    int gcol = n0 + wn + ni * 16 + lr;
                    float v = acc[mi][ni][r] + bv[ni];
                    if (ACT == 1) v = gelu_f(v);
                    if (RES) v += res[(size_t)grow * N + gcol];
                    C[(size_t)grow * N + gcol] = v;
                }
            }
        }
    }
}

// ---- MFMA flash attention v2: pre-split fp16 inputs, dense bias,
//      register prefetch, split-P LDS ----
__global__ __launch_bounds__(256) void mattn2_kernel(
        const f16* __restrict__ qsp, float* __restrict__ o) {
    __shared__ __align__(16) f16 Kh_s[64][40], Kl_s[64][40];   // 10240 B
    __shared__ __align__(16) f16 VTh_s[32][72], VTl_s[32][72]; // 9216 B
    __shared__ __align__(16) f16 Ph_s[4][16][72], Pl_s[4][16][72]; // 18432 B
    const f16* __restrict__ Qh_g  = qsp;
    const f16* __restrict__ Kh_g  = qsp + OFF_KH;
    const f16* __restrict__ VTh_g = qsp + OFF_VTH;
    const f16* __restrict__ bias_g = qsp + OFF_BIAS;

    const int tid = threadIdx.x;
    const int b = blockIdx.x >> 3, h = blockIdx.x & 7;
    const int q0 = blockIdx.y * 64;
    const int w = tid >> 6, l = tid & 63;
    const int lr = l & 15, lg = l >> 4;

    // Q A-fragment (pre-split, pre-scaled)
    int qrow = q0 + w * 16 + lr; if (qrow >= Tc) qrow = Tc - 1;
    const f16* qp = Qh_g + ((size_t)(b * Tc + qrow)) * 256 + h * 32 + lg * 8;
    const f16x8 Qh = *reinterpret_cast<const f16x8*>(qp);
    const f16x8 Ql = *reinterpret_cast<const f16x8*>(qp + QK_ST);
    const int myq = q0 + w * 16 + lg * 4;

    // staging roles
    const int skrow = tid >> 2, skc = (tid & 3) * 8;   // K: 64 rows x 4 chunks
    const int svd = tid >> 3, svc = (tid & 7) * 8;     // VT: 32 d x 8 chunks

    // prefetch registers
    f16x8 pkh, pkl, pvh, pvl;
    const f16* vrow = VTh_g + ((size_t)((b * NHc + h) * 32 + svd)) * VT_PAD;
    auto load_tile = [&](int k0) {
        int gk = k0 + skrow; if (gk >= Tc) gk = Tc - 1;
        const f16* kp = Kh_g + ((size_t)(b * Tc + gk)) * 256 + h * 32 + skc;
        pkh = *reinterpret_cast<const f16x8*>(kp);
        pkl = *reinterpret_cast<const f16x8*>(kp + QK_ST);
        const f16* vp = vrow + k0 + svc;
        pvh = *reinterpret_cast<const f16x8*>(vp);
        pvl = *reinterpret_cast<const f16x8*>(vp + VT_ST);
    };
    load_tile(0);

    float m_run[4], l_run[4];
    f32x4 Oacc[2] = {};
    #pragma unroll
    for (int r = 0; r < 4; ++r) { m_run[r] = -1e30f; l_run[r] = 0.f; }

    for (int t = 0; t < 10; ++t) {
        const int k0 = t * 64;
        __syncthreads();  // LDS free (prev tile reads done)
        *reinterpret_cast<f16x8*>(&Kh_s[skrow][skc]) = pkh;
        *reinterpret_cast<f16x8*>(&Kl_s[skrow][skc]) = pkl;
        *reinterpret_cast<f16x8*>(&VTh_s[svd][svc]) = pvh;
        *reinterpret_cast<f16x8*>(&VTl_s[svd][svc]) = pvl;
        if (t < 9) load_tile(k0 + 64);
        __syncthreads();  // LDS ready
        // ---- scores: 4 key-subtiles x 3 MFMA ----
        f32x4 sc[4];
        #pragma unroll
        for (int j = 0; j < 4; ++j) {
            const f16x8 kh = *reinterpret_cast<const f16x8*>(&Kh_s[j * 16 + lr][lg * 8]);
            const f16x8 kl = *reinterpret_cast<const f16x8*>(&Kl_s[j * 16 + lr][lg * 8]);
            f32x4 s = {};
            s = __builtin_amdgcn_mfma_f32_16x16x32_f16(Qh, kh, s, 0, 0, 0);
            s = __builtin_amdgcn_mfma_f32_16x16x32_f16(Qh, kl, s, 0, 0, 0);
            s = __builtin_amdgcn_mfma_f32_16x16x32_f16(Ql, kh, s, 0, 0, 0);
            sc[j] = s;
        }
        // ---- dense bias + tail mask ----
        #pragma unroll
        for (int r = 0; r < 4; ++r) {
            const int qq = myq + r < Tc ? myq + r : Tc - 1;
            const f16* brow = bias_g + ((size_t)h * Tc + qq) * Tc;
            #pragma unroll
            for (int j = 0; j < 4; ++j) {
                const int kk = k0 + j * 16 + lr;
                const int kks = kk < Tc ? kk : Tc - 1;
                float v = sc[j][r] + (float)brow[kks];
                sc[j][r] = (kk < Tc) ? v : -1e30f;
            }
        }
        // ---- online softmax per row; write split P ----
        #pragma unroll
        for (int r = 0; r < 4; ++r) {
            float tm = fmaxf(fmaxf(sc[0][r], sc[1][r]), fmaxf(sc[2][r], sc[3][r]));
            #pragma unroll
            for (int mk = 1; mk < 16; mk <<= 1) tm = fmaxf(tm, __shfl_xor(tm, mk, 64));
            const float mn = fmaxf(m_run[r], tm);
            const float resc = __expf(m_run[r] - mn);
            m_run[r] = mn;
            float ls = 0.f;
            #pragma unroll
            for (int j = 0; j < 4; ++j) {
                sc[j][r] = __expf(sc[j][r] - mn);
                ls += sc[j][r];
            }
            #pragma unroll
            for (int mk = 1; mk < 16; mk <<= 1) ls += __shfl_xor(ls, mk, 64);
            l_run[r] = l_run[r] * resc + ls;
            Oacc[0][r] *= resc; Oacc[1][r] *= resc;
            const int prow = lg * 4 + r;
            #pragma unroll
            for (int j = 0; j < 4; ++j) {
                const float p = sc[j][r];
                const f16 ph = (f16)p;
                Ph_s[w][prow][j * 16 + lr] = ph;
                Pl_s[w][prow][j * 16 + lr] = (f16)(p - (float)ph);
            }
        }
        // ---- PV: split-P A-frag x split-VT B-frag ----
        #pragma unroll
        for (int kc = 0; kc < 2; ++kc) {
            const f16x8 Pa = *reinterpret_cast<const f16x8*>(&Ph_s[w][lr][kc * 32 + lg * 8]);
            const f16x8 Pb = *reinterpret_cast<const f16x8*>(&Pl_s[w][lr][kc * 32 + lg * 8]);
            #pragma unroll
            for (int dt = 0; dt < 2; ++dt) {
                const f16x8 vh = *reinterpret_cast<const f16x8*>(&VTh_s[dt * 16 + lr][kc * 32 + lg * 8]);
                const f16x8 vl = *reinterpret_cast<const f16x8*>(&VTl_s[dt * 16 + lr][kc * 32 + lg * 8]);
                Oacc[dt] = __builtin_amdgcn_mfma_f32_16x16x32_f16(Pa, vh, Oacc[dt], 0, 0, 0);
                Oacc[dt] = __builtin_amdgcn_mfma_f32_16x16x32_f16(Pa, vl, Oacc[dt], 0, 0, 0);
                Oacc[dt] = __builtin_amdgcn_mfma_f32_16x16x32_f16(Pb, vh, Oacc[dt], 0, 0, 0);
            }
        }
    }
    // ---- store ----
    #pragma unroll
    for (int r = 0; r < 4; ++r) {
        const int qq = myq + r;
        if (qq < Tc) {
            const float inv = 1.0f / l_run[r];
            float* op = o + ((size_t)b * Tc + qq) * Dc + h * HDc;
            op[lr]      = Oacc[0][r] * inv;
            op[16 + lr] = Oacc[1][r] * inv;
        }
    }
}

// ---- logits ----
__global__ __launch_bounds__(256) void logits_kernel(
        const float* __restrict__ ph, const float* __restrict__ w2,
        const float* __restrict__ b2, float* __restrict__ out) {
    __shared__ float s4[4];
    size_t r = blockIdx.x;
    int bb = (int)(r / Nc), n = (int)(r % Nc);
    float v = ph[r * Dc + threadIdx.x] * w2[threadIdx.x];
    float s = block_sum256(v, s4);
    if (threadIdx.x == 0) out[bb * (Nc + 1) + n] = s + b2[0];
}

// ---- value head ----
__global__ __launch_bounds__(256) void value_kernel(
        const float* __restrict__ xn, const float* __restrict__ g,
        const float* __restrict__ b, const float* __restrict__ w1,
        const float* __restrict__ b1, const float* __restrict__ w2,
        const float* __restrict__ b2, float* __restrict__ out) {
    __shared__ float s4[4];
    __shared__ float ts[Dc];
    const int bb = blockIdx.x, tid = threadIdx.x;
    float v = xn[(size_t)bb * Tc * Dc + tid];
    float m = block_sum256(v, s4) * (1.0f / 256.0f);
    float d = v - m;
    float var = block_sum256(d * d, s4) * (1.0f / 256.0f);
    ts[tid] = d * rsqrtf(var + 1e-5f) * g[tid] + b[tid];
    __syncthreads();
    float acc = b1[tid];
    #pragma unroll 8
    for (int i = 0; i < Dc; ++i) acc = fmaf(ts[i], w1[i * Dc + tid], acc);
    float hv = gelu_f(acc) * w2[tid];
    float s = block_sum256(hv, s4);
    if (tid == 0) out[bb * (Nc + 1) + Nc] = s + b2[0];
}

extern "C" void kernel_launch(void* const* d_in, const int* in_sizes, int n_in,
                              void* d_out, int out_size, void* d_ws, size_t ws_size,
                              hipStream_t stream) {
    const float* obs      = (const float*)d_in[0];
    const float* input_w  = (const float*)d_in[1];
    const float* input_b  = (const float*)d_in[2];
    const float* cls_tok  = (const float*)d_in[3];
    const float* glob_tok = (const float*)d_in[4];
    const float* row_emb  = (const float*)d_in[5];
    const float* col_emb  = (const float*)d_in[6];
    const float* ln1_g    = (const float*)d_in[7];
    const float* ln1_b    = (const float*)d_in[8];
    const float* qkv_w    = (const float*)d_in[9];
    const float* qkv_b    = (const float*)d_in[10];
    const float* proj_w   = (const float*)d_in[11];
    const float* proj_b   = (const float*)d_in[12];
    const float* rel_bias = (const float*)d_in[13];
    const float* ln2_g    = (const float*)d_in[14];
    const float* ln2_b    = (const float*)d_in[15];
    const float* fc1_w    = (const float*)d_in[16];
    const float* fc1_b    = (const float*)d_in[17];
    const float* fc2_w    = (const float*)d_in[18];
    const float* fc2_b    = (const float*)d_in[19];
    const float* norm_g   = (const float*)d_in[20];
    const float* norm_b   = (const float*)d_in[21];
    const float* pol_ln_g = (const float*)d_in[22];
    const float* pol_ln_b = (const float*)d_in[23];
    const float* pol_w1   = (const float*)d_in[24];
    const float* pol_b1   = (const float*)d_in[25];
    const float* pol_w2   = (const float*)d_in[26];
    const float* pol_b2   = (const float*)d_in[27];
    const float* val_ln_g = (const float*)d_in[28];
    const float* val_ln_b = (const float*)d_in[29];
    const float* val_w1   = (const float*)d_in[30];
    const float* val_b1   = (const float*)d_in[31];
    const float* val_w2   = (const float*)d_in[32];
    const float* val_b2   = (const float*)d_in[33];
    const int*   rel_idx  = (const int*)d_in[34];
    float* out = (float*)d_out;

    float* ws = (float*)d_ws;
    const size_t SZ_XD = (size_t)BT * Dc;        // 2,371,584 floats
    float* X  = ws;
    float* Hb = ws + SZ_XD;
    float* R  = ws + 2 * SZ_XD;                  // aliased region (R_FLOATS)
    f16* qsp = (f16*)R;                          // Qh|Ql|Kh|Kl|VTh|VTl|bias
    f16* bias_g = qsp + OFF_BIAS;
    float* MLPH = R;                             // alias (MLP phase)
    float* PT = R;                               // alias (head phase)
    float* PH = R + (size_t)Bc * Nc * Dc;
    f16* wsplit = (f16*)(R + R_FLOATS);          // 12.85 MB

    auto qkvT = [&](int l) { return wsplit + (size_t)l * 393216; };
    auto projT = [&](int l) { return wsplit + 2359296 + (size_t)l * 131072; };
    auto fc1T = [&](int l) { return wsplit + 3145728 + (size_t)l * 262144; };
    auto fc2T = [&](int l) { return wsplit + 4718592 + (size_t)l * 262144; };
    f16* polT = wsplit + 6291456;

    split_w_kernel<<<12544, 256, 0, stream>>>(
        qkv_w, proj_w, fc1_w, fc2_w, pol_w1, wsplit);

    embed_kernel<<<dim3(Tc, Bc), 256, 0, stream>>>(
        obs, input_w, input_b, cls_tok, glob_tok, row_emb, col_emb, X);

    for (int l = 0; l < DEPTHc; ++l) {
        ln4_kernel<<<(BT + 3) / 4, 256, 0, stream>>>(
            X, ln1_g + l * Dc, ln1_b + l * Dc, Hb, BT);
        mgemm_kernel<2, false><<<dim3(12, 73), 256, 0, stream>>>(
            Hb, qkvT(l), qkv_b + l * 3 * Dc, nullptr, (float*)qsp, BT, 3 * Dc, Dc);
        biasgen_kernel<<<dim3(Tc, NHc), 128, 0, stream>>>(
            rel_bias + l * NHc * BINSc, rel_idx, bias_g);
        mattn2_kernel<<<dim3(Bc * NHc, 10), 256, 0, stream>>>(qsp, Hb);
        mgemm_kernel<0, true><<<dim3(4, 73), 256, 0, stream>>>(
            Hb, projT(l), proj_b + l * Dc, X, X, BT, Dc, Dc);
        ln4_kernel<<<(BT + 3) / 4, 256, 0, stream>>>(
            X, ln2_g + l * Dc, ln2_b + l * Dc, Hb, BT);
        mgemm_kernel<1, false><<<dim3(8, 73), 256, 0, stream>>>(
            Hb, fc1T(l), fc1_b + l * MLPc, nullptr, MLPH, BT, MLPc, Dc);
        mgemm_kernel<0, true><<<dim3(4, 73), 256, 0, stream>>>(
            MLPH, fc2T(l), fc2_b + l * Dc, X, X, BT, Dc, MLPc);
    }

    ln4_kernel<<<(BT + 3) / 4, 256, 0, stream>>>(X, norm_g, norm_b, Hb, BT);
    lnsel4_kernel<<<Bc * Nc / 4, 256, 0, stream>>>(Hb, pol_ln_g, pol_ln_b, PT);
    mgemm_kernel<1, false><<<dim3(4, 72), 256, 0, stream>>>(
        PT, polT, pol_b1, nullptr, PH, Bc * Nc, Dc, Dc);
    logits_kernel<<<Bc * Nc, 256, 0, stream>>>(PH, pol_w2, pol_b2, out);
    value_kernel<<<Bc, 256, 0, stream>>>(
        Hb, val_ln_g, val_ln_b, val_w1, val_b1, val_w2, val_b2, out);
}

// Round 6
// 1313.924 us; speedup vs baseline: 5.1464x; 1.2276x over previous
//
#include <hip/hip_runtime.h>
#include <math.h>

// ---- problem constants ----
constexpr int Hc = 24, Wc = 24, Nc = 576, BINSc = 82, Gc = 2;
constexpr int Tc = Nc + 1 + Gc;          // 579
constexpr int Dc = 256, NHc = 8, HDc = 32, DEPTHc = 6, MLPc = 512;
constexpr int Bc = 16, CINc = 10;
constexpr int BT = Bc * Tc;              // 9264
constexpr float SCALE = 0.17677669529663687f;  // 1/sqrt(32)

typedef _Float16 f16;
typedef _Float16 f16x8 __attribute__((ext_vector_type(8)));
typedef _Float16 f16x16 __attribute__((ext_vector_type(16)));
typedef float f32x4 __attribute__((ext_vector_type(4)));

// ---- split-QKV region layout (f16 elements, base = R) ----
constexpr size_t QK_ST   = (size_t)BT * 256;           // 2,371,584
constexpr int    VT_PAD  = 640;
constexpr size_t VT_ST   = (size_t)Bc * NHc * 32 * VT_PAD;  // 2,621,440
constexpr size_t OFF_KH  = 2 * QK_ST;
constexpr size_t OFF_VTH = 4 * QK_ST;
constexpr size_t OFF_BIAS = 4 * QK_ST + 2 * VT_ST;     // 14,729,216
constexpr int    BPAD    = 580;                        // bias row stride (even)
constexpr size_t R_F16   = OFF_BIAS + (size_t)NHc * Tc * BPAD;  // 17,415,776
constexpr size_t R_FLOATS = 8707904;                   // ceil(R_F16/2) + align

// bijective XCD chunk swizzle: contiguous v-chunks per XCD (T1, m204 variant)
__device__ __forceinline__ int xcd_swz(int d, int nwg) {
    const int q = nwg >> 3, r = nwg & 7;
    const int x = d & 7, s = d >> 3;
    return x * q + (x < r ? x : r) + s;
}

__device__ __forceinline__ float gelu_f(float x) {
    return 0.5f * x * (1.0f + erff(x * 0.70710678118654752f));
}

__device__ __forceinline__ float block_sum256(float v, float* s4) {
    #pragma unroll
    for (int off = 32; off > 0; off >>= 1) v += __shfl_down(v, off, 64);
    __syncthreads();
    if ((threadIdx.x & 63) == 0) s4[threadIdx.x >> 6] = v;
    __syncthreads();
    return s4[0] + s4[1] + s4[2] + s4[3];
}

// ---- embed ----
__global__ __launch_bounds__(256) void embed_kernel(
        const float* __restrict__ obs, const float* __restrict__ iw,
        const float* __restrict__ ib, const float* __restrict__ cls,
        const float* __restrict__ glob, const float* __restrict__ rowe,
        const float* __restrict__ cole, float* __restrict__ x) {
    int t = blockIdx.x, b = blockIdx.y, d = threadIdx.x;
    float v;
    if (t == 0) {
        v = cls[d];
    } else if (t <= Gc) {
        v = glob[(t - 1) * Dc + d];
    } else {
        int n = t - 1 - Gc;
        float acc = ib[d];
        #pragma unroll
        for (int c = 0; c < CINc; ++c)
            acc = fmaf(obs[(b * CINc + c) * Nc + n], iw[c * Dc + d], acc);
        v = acc + rowe[(n / Wc) * Dc + d] + cole[(n % Wc) * Dc + d];
    }
    x[((size_t)b * Tc + t) * Dc + d] = v;
}

// ---- layernorm: one wave per row ----
__global__ __launch_bounds__(256) void ln4_kernel(
        const float* __restrict__ x, const float* __restrict__ g,
        const float* __restrict__ b, float* __restrict__ out, int nrows) {
    const int w = threadIdx.x >> 6, l = threadIdx.x & 63;
    const int row = blockIdx.x * 4 + w;
    if (row >= nrows) return;
    const float4 v = *reinterpret_cast<const float4*>(x + (size_t)row * Dc + l * 4);
    float s = v.x + v.y + v.z + v.w;
    #pragma unroll
    for (int mk = 1; mk < 64; mk <<= 1) s += __shfl_xor(s, mk, 64);
    const float m = s * (1.0f / 256.0f);
    const float4 d = make_float4(v.x - m, v.y - m, v.z - m, v.w - m);
    float vs = d.x * d.x + d.y * d.y + d.z * d.z + d.w * d.w;
    #pragma unroll
    for (int mk = 1; mk < 64; mk <<= 1) vs += __shfl_xor(vs, mk, 64);
    const float rs = rsqrtf(vs * (1.0f / 256.0f) + 1e-5f);
    const float4 gg = *reinterpret_cast<const float4*>(g + l * 4);
    const float4 bb = *reinterpret_cast<const float4*>(b + l * 4);
    *reinterpret_cast<float4*>(out + (size_t)row * Dc + l * 4) =
        make_float4(d.x * rs * gg.x + bb.x, d.y * rs * gg.y + bb.y,
                    d.z * rs * gg.z + bb.z, d.w * rs * gg.w + bb.w);
}

// ---- LN + gather policy tokens ----
__global__ __launch_bounds__(256) void lnsel4_kernel(
        const float* __restrict__ xn, const float* __restrict__ g,
        const float* __restrict__ b, float* __restrict__ out) {
    const int w = threadIdx.x >> 6, l = threadIdx.x & 63;
    const int rr = blockIdx.x * 4 + w;
    const int bb = rr / Nc, n = rr % Nc;
    const float* xr = xn + ((size_t)bb * Tc + 1 + n) * Dc;
    const float4 v = *reinterpret_cast<const float4*>(xr + l * 4);
    float s = v.x + v.y + v.z + v.w;
    #pragma unroll
    for (int mk = 1; mk < 64; mk <<= 1) s += __shfl_xor(s, mk, 64);
    const float m = s * (1.0f / 256.0f);
    const float4 d = make_float4(v.x - m, v.y - m, v.z - m, v.w - m);
    float vs = d.x * d.x + d.y * d.y + d.z * d.z + d.w * d.w;
    #pragma unroll
    for (int mk = 1; mk < 64; mk <<= 1) vs += __shfl_xor(vs, mk, 64);
    const float rs = rsqrtf(vs * (1.0f / 256.0f) + 1e-5f);
    const float4 gg = *reinterpret_cast<const float4*>(g + l * 4);
    const float4 bb4 = *reinterpret_cast<const float4*>(b + l * 4);
    *reinterpret_cast<float4*>(out + ((size_t)bb * Nc + n) * Dc + l * 4) =
        make_float4(d.x * rs * gg.x + bb4.x, d.y * rs * gg.y + bb4.y,
                    d.z * rs * gg.z + bb4.z, d.w * rs * gg.w + bb4.w);
}

// ---- weight split+transpose ----
__global__ __launch_bounds__(256) void split_w_kernel(
        const float* __restrict__ qkv_w, const float* __restrict__ proj_w,
        const float* __restrict__ fc1_w, const float* __restrict__ fc2_w,
        const float* __restrict__ pol_w1, f16* __restrict__ out) {
    int r = blockIdx.x * 256 + threadIdx.x;
    float v; f16* dst; int NK;
    if (r < 1179648) {
        int layer = r / 196608, e = r % 196608;
        int n = e >> 8, k = e & 255;
        v = qkv_w[(size_t)layer * 196608 + k * 768 + n];
        dst = out + (size_t)layer * 393216 + n * 256 + k; NK = 196608;
    } else if (r < 1572864) {
        int rr = r - 1179648; int layer = rr / 65536, e = rr % 65536;
        int n = e >> 8, k = e & 255;
        v = proj_w[(size_t)layer * 65536 + k * 256 + n];
        dst = out + 2359296 + (size_t)layer * 131072 + n * 256 + k; NK = 65536;
    } else if (r < 2359296) {
        int rr = r - 1572864; int layer = rr / 131072, e = rr % 131072;
        int n = e >> 8, k = e & 255;
        v = fc1_w[(size_t)layer * 131072 + k * 512 + n];
        dst = out + 3145728 + (size_t)layer * 262144 + n * 256 + k; NK = 131072;
    } else if (r < 3145728) {
        int rr = r - 2359296; int layer = rr / 131072, e = rr % 131072;
        int n = e >> 9, k = e & 511;
        v = fc2_w[(size_t)layer * 131072 + k * 256 + n];
        dst = out + 4718592 + (size_t)layer * 262144 + n * 512 + k; NK = 131072;
    } else if (r < 3211264) {
        int rr = r - 3145728; int n = rr >> 8, k = rr & 255;
        v = pol_w1[k * 256 + n];
        dst = out + 6291456 + n * 256 + k; NK = 65536;
    } else return;
    f16 h = (f16)v;
    dst[0] = h;
    dst[NK] = (f16)(v - (float)h);
}

// ---- dense rel-bias table (row stride BPAD, u32-paired stores) ----
__global__ __launch_bounds__(256) void biasgen_kernel(
        const float* __restrict__ relb, const int* __restrict__ relidx,
        f16* __restrict__ bias) {
    const int q = blockIdx.x, h = blockIdx.y;
    const size_t rowo = ((size_t)h * Tc + q) * BPAD;
    const int* ridx = relidx + q * Tc;
    const float* rb = relb + h * BINSc;
    for (int kp = threadIdx.x; kp * 2 + 1 < Tc; kp += 256) {
        f16 b0 = (f16)rb[ridx[kp * 2]];
        f16 b1 = (f16)rb[ridx[kp * 2 + 1]];
        unsigned pk = (unsigned)__builtin_bit_cast(unsigned short, b0) |
                      ((unsigned)__builtin_bit_cast(unsigned short, b1) << 16);
        *reinterpret_cast<unsigned*>(&bias[rowo + kp * 2]) = pk;
    }
    if (threadIdx.x == 0)
        bias[rowo + Tc - 1] = (f16)rb[ridx[Tc - 1]];
}

// ---- fp16x3 MFMA GEMM. ACT: 0=none, 1=gelu, 2=QKV-split-out ----
__device__ __forceinline__ int swz(int r, int g) {
    return r * 40 + ((g ^ ((r >> 3) & 3)) << 3);
}
template <int ACT, bool RES>
__global__ __launch_bounds__(256) void mgemm_kernel(
        const float* __restrict__ A, const f16* __restrict__ WT,
        const float* __restrict__ bias, const float* __restrict__ res,
        float* __restrict__ C, int M, int N, int K, int nbx) {
    constexpr int BM = 128, BN = 64, BK = 32;
    __shared__ f16 Ah[BM * 40], Al[BM * 40];
    __shared__ f16 Bh[BN * 40], Bl[BN * 40];
    const int tid = threadIdx.x;
    const int v = xcd_swz(blockIdx.x, gridDim.x);
    const int m0 = (v / nbx) * BM, n0 = (v % nbx) * BN;
    const int w = tid >> 6, l = tid & 63;
    const int wm = (w >> 1) * 64, wn = (w & 1) * 32;
    const int lg = l >> 4, lr = l & 15;
    f32x4 acc[4][2] = {};
    const int sa_row = tid >> 1, sa_kc = (tid & 1) * 16;
    const int sb_part = tid >> 7;
    const int sb_n = (tid & 127) >> 1, sb_kc = (tid & 1) * 16;

    for (int k0 = 0; k0 < K; k0 += BK) {
        {
            int gr = m0 + sa_row; if (gr >= M) gr = M - 1;
            const float4* src = reinterpret_cast<const float4*>(
                A + (size_t)gr * K + k0 + sa_kc);
            f16x8 hv0, hv1, lv0, lv1;
            #pragma unroll
            for (int c = 0; c < 4; ++c) {
                float4 v4 = src[c];
                f16 h0 = (f16)v4.x, h1 = (f16)v4.y, h2 = (f16)v4.z, h3 = (f16)v4.w;
                f16 l0 = (f16)(v4.x - (float)h0), l1 = (f16)(v4.y - (float)h1);
                f16 l2 = (f16)(v4.z - (float)h2), l3 = (f16)(v4.w - (float)h3);
                if (c < 2) {
                    hv0[c * 4 + 0] = h0; hv0[c * 4 + 1] = h1;
                    hv0[c * 4 + 2] = h2; hv0[c * 4 + 3] = h3;
                    lv0[c * 4 + 0] = l0; lv0[c * 4 + 1] = l1;
                    lv0[c * 4 + 2] = l2; lv0[c * 4 + 3] = l3;
                } else {
                    hv1[(c - 2) * 4 + 0] = h0; hv1[(c - 2) * 4 + 1] = h1;
                    hv1[(c - 2) * 4 + 2] = h2; hv1[(c - 2) * 4 + 3] = h3;
                    lv1[(c - 2) * 4 + 0] = l0; lv1[(c - 2) * 4 + 1] = l1;
                    lv1[(c - 2) * 4 + 2] = l2; lv1[(c - 2) * 4 + 3] = l3;
                }
            }
            const int g0 = sa_kc >> 3;
            *reinterpret_cast<f16x8*>(&Ah[swz(sa_row, g0)])     = hv0;
            *reinterpret_cast<f16x8*>(&Ah[swz(sa_row, g0 + 1)]) = hv1;
            *reinterpret_cast<f16x8*>(&Al[swz(sa_row, g0)])     = lv0;
            *reinterpret_cast<f16x8*>(&Al[swz(sa_row, g0 + 1)]) = lv1;
        }
        {
            const f16x8* src = reinterpret_cast<const f16x8*>(
                WT + (size_t)sb_part * N * K + (size_t)(n0 + sb_n) * K + k0 + sb_kc);
            f16* dbase = sb_part ? Bl : Bh;
            const int g0 = sb_kc >> 3;
            *reinterpret_cast<f16x8*>(&dbase[swz(sb_n, g0)])     = src[0];
            *reinterpret_cast<f16x8*>(&dbase[swz(sb_n, g0 + 1)]) = src[1];
        }
        __syncthreads();
        f16x8 afh[4], afl[4], bfh[2], bfl[2];
        #pragma unroll
        for (int mi = 0; mi < 4; ++mi) {
            int row = wm + mi * 16 + lr;
            afh[mi] = *reinterpret_cast<const f16x8*>(&Ah[swz(row, lg)]);
            afl[mi] = *reinterpret_cast<const f16x8*>(&Al[swz(row, lg)]);
        }
        #pragma unroll
        for (int ni = 0; ni < 2; ++ni) {
            int col = wn + ni * 16 + lr;
            bfh[ni] = *reinterpret_cast<const f16x8*>(&Bh[swz(col, lg)]);
            bfl[ni] = *reinterpret_cast<const f16x8*>(&Bl[swz(col, lg)]);
        }
        #pragma unroll
        for (int mi = 0; mi < 4; ++mi)
            #pragma unroll
            for (int ni = 0; ni < 2; ++ni) {
                acc[mi][ni] = __builtin_amdgcn_mfma_f32_16x16x32_f16(
                    afh[mi], bfh[ni], acc[mi][ni], 0, 0, 0);
                acc[mi][ni] = __builtin_amdgcn_mfma_f32_16x16x32_f16(
                    afh[mi], bfl[ni], acc[mi][ni], 0, 0, 0);
                acc[mi][ni] = __builtin_amdgcn_mfma_f32_16x16x32_f16(
                    afl[mi], bfh[ni], acc[mi][ni], 0, 0, 0);
            }
        __syncthreads();
    }
    float bv[2];
    #pragma unroll
    for (int ni = 0; ni < 2; ++ni) bv[ni] = bias[n0 + wn + ni * 16 + lr];
    #pragma unroll
    for (int mi = 0; mi < 4; ++mi) {
        #pragma unroll
        for (int r = 0; r < 4; ++r) {
            int grow = m0 + wm + mi * 16 + lg * 4 + r;
            if (grow >= M) continue;
            if constexpr (ACT == 2) {
                f16* base = (f16*)C;
                const int bb = grow / Tc;
                const int tt = grow - bb * Tc;
                #pragma unroll
                for (int ni = 0; ni < 2; ++ni) {
                    const int gcol = n0 + wn + ni * 16 + lr;
                    float vv = acc[mi][ni][r] + bv[ni];
                    if (gcol < 256) {                       // Q (scaled)
                        vv *= SCALE;
                        f16 hh = (f16)vv;
                        base[(size_t)grow * 256 + gcol] = hh;
                        base[QK_ST + (size_t)grow * 256 + gcol] = (f16)(vv - (float)hh);
                    } else if (gcol < 512) {                // K
                        f16 hh = (f16)vv;
                        base[OFF_KH + (size_t)grow * 256 + (gcol - 256)] = hh;
                        base[OFF_KH + QK_ST + (size_t)grow * 256 + (gcol - 256)] =
                            (f16)(vv - (float)hh);
                    } else {                                // V transposed
                        const int e = gcol - 512;
                        const int hh_ = e >> 5, dd = e & 31;
                        const size_t o =
                            ((size_t)((bb * NHc + hh_) * 32 + dd)) * VT_PAD + tt;
                        f16 hh = (f16)vv;
                        base[OFF_VTH + o] = hh;
                        base[OFF_VTH + VT_ST + o] = (f16)(vv - (float)hh);
                    }
                }
            } else {
                #pragma unroll
                for (int ni = 0; ni < 2; ++ni) {
                    int gcol = n0 + wn + ni * 16 + lr;
                    float vv = acc[mi][ni][r] + bv[ni];
                    if (ACT == 1) vv = gelu_f(vv);
                    if (RES) vv += res[(size_t)grow * N + gcol];
                    C[(size_t)grow * N + gcol] = vv;
                }
            }
        }
    }
}

// ---- MFMA flash attention v3: XCD swizzle + 2-deep K/V prefetch +
//      1-deep bias prefetch ----
__global__ __launch_bounds__(256, 4) void mattn2_kernel(
        const f16* __restrict__ qsp, float* __restrict__ o) {
    __shared__ __align__(16) f16 Kh_s[64][40], Kl_s[64][40];   // 10240 B
    __shared__ __align__(16) f16 VTh_s[32][72], VTl_s[32][72]; // 9216 B
    __shared__ __align__(16) f16 Ph_s[4][16][72], Pl_s[4][16][72]; // 18432 B
    const f16* __restrict__ Kh_g  = qsp + OFF_KH;
    const f16* __restrict__ VTh_g = qsp + OFF_VTH;
    const f16* __restrict__ bias_g = qsp + OFF_BIAS;

    const int tid = threadIdx.x;
    const int v = xcd_swz(blockIdx.x, 1280);   // 10 q-tiles per (b,h) on 1 XCD
    const int bh = v / 10, qt = v - bh * 10;
    const int b = bh >> 3, h = bh & 7;
    const int q0 = qt * 64;
    const int w = tid >> 6, l = tid & 63;
    const int lr = l & 15, lg = l >> 4;

    // Q A-fragment (pre-split, pre-scaled)
    int qrow = q0 + w * 16 + lr; if (qrow >= Tc) qrow = Tc - 1;
    const f16* qp = qsp + ((size_t)(b * Tc + qrow)) * 256 + h * 32 + lg * 8;
    const f16x8 Qh = *reinterpret_cast<const f16x8*>(qp);
    const f16x8 Ql = *reinterpret_cast<const f16x8*>(qp + QK_ST);
    const int myq = q0 + w * 16 + lg * 4;

    // bias row offsets for my 4 q-rows (stride BPAD)
    int boff[4];
    #pragma unroll
    for (int r = 0; r < 4; ++r) {
        int qq = myq + r; if (qq >= Tc) qq = Tc - 1;
        boff[r] = (h * Tc + qq) * BPAD;
    }

    // staging roles
    const int skrow = tid >> 2, skc = (tid & 3) * 8;   // K: 64 rows x 4 chunks
    const int svd = tid >> 3, svc = (tid & 7) * 8;     // VT: 32 d x 8 chunks
    const f16* vrow = VTh_g + ((size_t)((b * NHc + h) * 32 + svd)) * VT_PAD;

    struct KV { f16x8 kh, kl, vh, vl; };
    auto load_kv = [&](int k0) {
        KV r;
        int gk = k0 + skrow; if (gk >= Tc) gk = Tc - 1;
        const f16* kp = Kh_g + ((size_t)(b * Tc + gk)) * 256 + h * 32 + skc;
        r.kh = *reinterpret_cast<const f16x8*>(kp);
        r.kl = *reinterpret_cast<const f16x8*>(kp + QK_ST);
        const f16* vp = vrow + k0 + svc;
        r.vh = *reinterpret_cast<const f16x8*>(vp);
        r.vl = *reinterpret_cast<const f16x8*>(vp + VT_ST);
        return r;
    };
    auto load_bias = [&](int k0) {
        f16x16 bv;
        #pragma unroll
        for (int r = 0; r < 4; ++r)
            #pragma unroll
            for (int j = 0; j < 4; ++j) {
                int kk = k0 + j * 16 + lr; if (kk >= Tc) kk = Tc - 1;
                bv[r * 4 + j] = bias_g[boff[r] + kk];
            }
        return bv;
    };

    KV pA = load_kv(0);
    KV pB = load_kv(64);
    f16x16 bias_c = load_bias(0), bias_n;

    float m_run[4], l_run[4];
    f32x4 Oacc[2] = {};
    #pragma unroll
    for (int r = 0; r < 4; ++r) { m_run[r] = -1e30f; l_run[r] = 0.f; }

    for (int t = 0; t < 10; ++t) {
        const int k0 = t * 64;
        __syncthreads();  // prev tile's LDS reads done
        *reinterpret_cast<f16x8*>(&Kh_s[skrow][skc]) = pA.kh;
        *reinterpret_cast<f16x8*>(&Kl_s[skrow][skc]) = pA.kl;
        *reinterpret_cast<f16x8*>(&VTh_s[svd][svc]) = pA.vh;
        *reinterpret_cast<f16x8*>(&VTl_s[svd][svc]) = pA.vl;
        pA = pB;
        if (t + 2 < 10) pB = load_kv(k0 + 128);
        __syncthreads();  // LDS ready
        if (t + 1 < 10) bias_n = load_bias(k0 + 64);  // hide under compute
        // ---- scores: 4 key-subtiles x 3 MFMA ----
        f32x4 sc[4];
        #pragma unroll
        for (int j = 0; j < 4; ++j) {
            const f16x8 kh = *reinterpret_cast<const f16x8*>(&Kh_s[j * 16 + lr][lg * 8]);
            const f16x8 kl = *reinterpret_cast<const f16x8*>(&Kl_s[j * 16 + lr][lg * 8]);
            f32x4 s = {};
            s = __builtin_amdgcn_mfma_f32_16x16x32_f16(Qh, kh, s, 0, 0, 0);
            s = __builtin_amdgcn_mfma_f32_16x16x32_f16(Qh, kl, s, 0, 0, 0);
            s = __builtin_amdgcn_mfma_f32_16x16x32_f16(Ql, kh, s, 0, 0, 0);
            sc[j] = s;
        }
        // ---- prefetched bias + tail mask ----
        #pragma unroll
        for (int r = 0; r < 4; ++r)
            #pragma unroll
            for (int j = 0; j < 4; ++j) {
                const int kk = k0 + j * 16 + lr;
                float vv = sc[j][r] + (float)bias_c[r * 4 + j];
                sc[j][r] = (kk < Tc) ? vv : -1e30f;
            }
        // ---- online softmax per row; write split P ----
        #pragma unroll
        for (int r = 0; r < 4; ++r) {
            float tm = fmaxf(fmaxf(sc[0][r], sc[1][r]), fmaxf(sc[2][r], sc[3][r]));
            #pragma unroll
            for (int mk = 1; mk < 16; mk <<= 1) tm = fmaxf(tm, __shfl_xor(tm, mk, 64));
            const float mn = fmaxf(m_run[r], tm);
            const float resc = __expf(m_run[r] - mn);
            m_run[r] = mn;
            float ls = 0.f;
            #pragma unroll
            for (int j = 0; j < 4; ++j) {
                sc[j][r] = __expf(sc[j][r] - mn);
                ls += sc[j][r];
            }
            #pragma unroll
            for (int mk = 1; mk < 16; mk <<= 1) ls += __shfl_xor(ls, mk, 64);
            l_run[r] = l_run[r] * resc + ls;
            Oacc[0][r] *= resc; Oacc[1][r] *= resc;
            const int prow = lg * 4 + r;
            #pragma unroll
            for (int j = 0; j < 4; ++j) {
                const float p = sc[j][r];
                const f16 ph = (f16)p;
                Ph_s[w][prow][j * 16 + lr] = ph;
                Pl_s[w][prow][j * 16 + lr] = (f16)(p - (float)ph);
            }
        }
        // ---- PV: split-P A-frag x split-VT B-frag ----
        #pragma unroll
        for (int kc = 0; kc < 2; ++kc) {
            const f16x8 Pa = *reinterpret_cast<const f16x8*>(&Ph_s[w][lr][kc * 32 + lg * 8]);
            const f16x8 Pb = *reinterpret_cast<const f16x8*>(&Pl_s[w][lr][kc * 32 + lg * 8]);
            #pragma unroll
            for (int dt = 0; dt < 2; ++dt) {
                const f16x8 vh = *reinterpret_cast<const f16x8*>(&VTh_s[dt * 16 + lr][kc * 32 + lg * 8]);
                const f16x8 vl = *reinterpret_cast<const f16x8*>(&VTl_s[dt * 16 + lr][kc * 32 + lg * 8]);
                Oacc[dt] = __builtin_amdgcn_mfma_f32_16x16x32_f16(Pa, vh, Oacc[dt], 0, 0, 0);
                Oacc[dt] = __builtin_amdgcn_mfma_f32_16x16x32_f16(Pa, vl, Oacc[dt], 0, 0, 0);
                Oacc[dt] = __builtin_amdgcn_mfma_f32_16x16x32_f16(Pb, vh, Oacc[dt], 0, 0, 0);
            }
        }
        if (t + 1 < 10) bias_c = bias_n;
    }
    // ---- store ----
    #pragma unroll
    for (int r = 0; r < 4; ++r) {
        const int qq = myq + r;
        if (qq < Tc) {
            const float inv = 1.0f / l_run[r];
            float* op = o + ((size_t)b * Tc + qq) * Dc + h * HDc;
            op[lr]      = Oacc[0][r] * inv;
            op[16 + lr] = Oacc[1][r] * inv;
        }
    }
}

// ---- logits ----
__global__ __launch_bounds__(256) void logits_kernel(
        const float* __restrict__ ph, const float* __restrict__ w2,
        const float* __restrict__ b2, float* __restrict__ out) {
    __shared__ float s4[4];
    size_t r = blockIdx.x;
    int bb = (int)(r / Nc), n = (int)(r % Nc);
    float v = ph[r * Dc + threadIdx.x] * w2[threadIdx.x];
    float s = block_sum256(v, s4);
    if (threadIdx.x == 0) out[bb * (Nc + 1) + n] = s + b2[0];
}

// ---- value head ----
__global__ __launch_bounds__(256) void value_kernel(
        const float* __restrict__ xn, const float* __restrict__ g,
        const float* __restrict__ b, const float* __restrict__ w1,
        const float* __restrict__ b1, const float* __restrict__ w2,
        const float* __restrict__ b2, float* __restrict__ out) {
    __shared__ float s4[4];
    __shared__ float ts[Dc];
    const int bb = blockIdx.x, tid = threadIdx.x;
    float v = xn[(size_t)bb * Tc * Dc + tid];
    float m = block_sum256(v, s4) * (1.0f / 256.0f);
    float d = v - m;
    float var = block_sum256(d * d, s4) * (1.0f / 256.0f);
    ts[tid] = d * rsqrtf(var + 1e-5f) * g[tid] + b[tid];
    __syncthreads();
    float acc = b1[tid];
    #pragma unroll 8
    for (int i = 0; i < Dc; ++i) acc = fmaf(ts[i], w1[i * Dc + tid], acc);
    float hv = gelu_f(acc) * w2[tid];
    float s = block_sum256(hv, s4);
    if (tid == 0) out[bb * (Nc + 1) + Nc] = s + b2[0];
}

extern "C" void kernel_launch(void* const* d_in, const int* in_sizes, int n_in,
                              void* d_out, int out_size, void* d_ws, size_t ws_size,
                              hipStream_t stream) {
    const float* obs      = (const float*)d_in[0];
    const float* input_w  = (const float*)d_in[1];
    const float* input_b  = (const float*)d_in[2];
    const float* cls_tok  = (const float*)d_in[3];
    const float* glob_tok = (const float*)d_in[4];
    const float* row_emb  = (const float*)d_in[5];
    const float* col_emb  = (const float*)d_in[6];
    const float* ln1_g    = (const float*)d_in[7];
    const float* ln1_b    = (const float*)d_in[8];
    const float* qkv_w    = (const float*)d_in[9];
    const float* qkv_b    = (const float*)d_in[10];
    const float* proj_w   = (const float*)d_in[11];
    const float* proj_b   = (const float*)d_in[12];
    const float* rel_bias = (const float*)d_in[13];
    const float* ln2_g    = (const float*)d_in[14];
    const float* ln2_b    = (const float*)d_in[15];
    const float* fc1_w    = (const float*)d_in[16];
    const float* fc1_b    = (const float*)d_in[17];
    const float* fc2_w    = (const float*)d_in[18];
    const float* fc2_b    = (const float*)d_in[19];
    const float* norm_g   = (const float*)d_in[20];
    const float* norm_b   = (const float*)d_in[21];
    const float* pol_ln_g = (const float*)d_in[22];
    const float* pol_ln_b = (const float*)d_in[23];
    const float* pol_w1   = (const float*)d_in[24];
    const float* pol_b1   = (const float*)d_in[25];
    const float* pol_w2   = (const float*)d_in[26];
    const float* pol_b2   = (const float*)d_in[27];
    const float* val_ln_g = (const float*)d_in[28];
    const float* val_ln_b = (const float*)d_in[29];
    const float* val_w1   = (const float*)d_in[30];
    const float* val_b1   = (const float*)d_in[31];
    const float* val_w2   = (const float*)d_in[32];
    const float* val_b2   = (const float*)d_in[33];
    const int*   rel_idx  = (const int*)d_in[34];
    float* out = (float*)d_out;

    float* ws = (float*)d_ws;
    const size_t SZ_XD = (size_t)BT * Dc;        // 2,371,584 floats
    float* X  = ws;
    float* Hb = ws + SZ_XD;
    float* R  = ws + 2 * SZ_XD;                  // aliased region (R_FLOATS)
    f16* qsp = (f16*)R;                          // Qh|Ql|Kh|Kl|VTh|VTl|bias
    f16* bias_g = qsp + OFF_BIAS;
    float* MLPH = R;                             // alias (MLP phase)
    float* PT = R;                               // alias (head phase)
    float* PH = R + (size_t)Bc * Nc * Dc;
    f16* wsplit = (f16*)(R + R_FLOATS);          // 12.85 MB

    auto qkvT = [&](int l) { return wsplit + (size_t)l * 393216; };
    auto projT = [&](int l) { return wsplit + 2359296 + (size_t)l * 131072; };
    auto fc1T = [&](int l) { return wsplit + 3145728 + (size_t)l * 262144; };
    auto fc2T = [&](int l) { return wsplit + 4718592 + (size_t)l * 262144; };
    f16* polT = wsplit + 6291456;

    split_w_kernel<<<12544, 256, 0, stream>>>(
        qkv_w, proj_w, fc1_w, fc2_w, pol_w1, wsplit);

    embed_kernel<<<dim3(Tc, Bc), 256, 0, stream>>>(
        obs, input_w, input_b, cls_tok, glob_tok, row_emb, col_emb, X);

    for (int l = 0; l < DEPTHc; ++l) {
        ln4_kernel<<<(BT + 3) / 4, 256, 0, stream>>>(
            X, ln1_g + l * Dc, ln1_b + l * Dc, Hb, BT);
        mgemm_kernel<2, false><<<876, 256, 0, stream>>>(
            Hb, qkvT(l), qkv_b + l * 3 * Dc, nullptr, (float*)qsp, BT, 3 * Dc, Dc, 12);
        biasgen_kernel<<<dim3(Tc, NHc), 256, 0, stream>>>(
            rel_bias + l * NHc * BINSc, rel_idx, bias_g);
        mattn2_kernel<<<1280, 256, 0, stream>>>(qsp, Hb);
        mgemm_kernel<0, true><<<292, 256, 0, stream>>>(
            Hb, projT(l), proj_b + l * Dc, X, X, BT, Dc, Dc, 4);
        ln4_kernel<<<(BT + 3) / 4, 256, 0, stream>>>(
            X, ln2_g + l * Dc, ln2_b + l * Dc, Hb, BT);
        mgemm_kernel<1, false><<<584, 256, 0, stream>>>(
            Hb, fc1T(l), fc1_b + l * MLPc, nullptr, MLPH, BT, MLPc, Dc, 8);
        mgemm_kernel<0, true><<<292, 256, 0, stream>>>(
            MLPH, fc2T(l), fc2_b + l * Dc, X, X, BT, Dc, MLPc, 4);
    }

    ln4_kernel<<<(BT + 3) / 4, 256, 0, stream>>>(X, norm_g, norm_b, Hb, BT);
    lnsel4_kernel<<<Bc * Nc / 4, 256, 0, stream>>>(Hb, pol_ln_g, pol_ln_b, PT);
    mgemm_kernel<1, false><<<288, 256, 0, stream>>>(
        PT, polT, pol_b1, nullptr, PH, Bc * Nc, Dc, Dc, 4);
    logits_kernel<<<Bc * Nc, 256, 0, stream>>>(PH, pol_w2, pol_b2, out);
    value_kernel<<<Bc, 256, 0, stream>>>(
        Hb, val_ln_g, val_ln_b, val_w1, val_b1, val_w2, val_b2, out);
}

// Round 7
// 1299.818 us; speedup vs baseline: 5.2023x; 1.0109x over previous
//
#include <hip/hip_runtime.h>
#include <math.h>

// ---- problem constants ----
constexpr int Hc = 24, Wc = 24, Nc = 576, BINSc = 82, Gc = 2;
constexpr int Tc = Nc + 1 + Gc;          // 579
constexpr int Dc = 256, NHc = 8, HDc = 32, DEPTHc = 6, MLPc = 512;
constexpr int Bc = 16, CINc = 10;
constexpr int BT = Bc * Tc;              // 9264
constexpr float SCALE = 0.17677669529663687f;  // 1/sqrt(32)

typedef _Float16 f16;
typedef _Float16 f16x8 __attribute__((ext_vector_type(8)));
typedef _Float16 f16x16 __attribute__((ext_vector_type(16)));
typedef float f32x4 __attribute__((ext_vector_type(4)));

// ---- split-QKV region layout (f16 elements, base = R) ----
constexpr size_t QK_ST   = (size_t)BT * 256;           // 2,371,584
constexpr int    VT_PAD  = 640;
constexpr size_t VT_ST   = (size_t)Bc * NHc * 32 * VT_PAD;  // 2,621,440
constexpr size_t OFF_KH  = 2 * QK_ST;
constexpr size_t OFF_VTH = 4 * QK_ST;
constexpr size_t OFF_BIAS = 4 * QK_ST + 2 * VT_ST;     // 14,729,216
constexpr int    BPAD    = 580;                        // bias row stride (even)
constexpr size_t R_F16   = OFF_BIAS + (size_t)NHc * Tc * BPAD;  // 17,415,776
constexpr size_t R_FLOATS = 8707904;                   // ceil(R_F16/2) + align

// bijective XCD chunk swizzle (T1, m204 variant)
__device__ __forceinline__ int xcd_swz(int d, int nwg) {
    const int q = nwg >> 3, r = nwg & 7;
    const int x = d & 7, s = d >> 3;
    return x * q + (x < r ? x : r) + s;
}

__device__ __forceinline__ float gelu_f(float x) {
    return 0.5f * x * (1.0f + erff(x * 0.70710678118654752f));
}

__device__ __forceinline__ float block_sum256(float v, float* s4) {
    #pragma unroll
    for (int off = 32; off > 0; off >>= 1) v += __shfl_down(v, off, 64);
    __syncthreads();
    if ((threadIdx.x & 63) == 0) s4[threadIdx.x >> 6] = v;
    __syncthreads();
    return s4[0] + s4[1] + s4[2] + s4[3];
}

// ---- embed ----
__global__ __launch_bounds__(256) void embed_kernel(
        const float* __restrict__ obs, const float* __restrict__ iw,
        const float* __restrict__ ib, const float* __restrict__ cls,
        const float* __restrict__ glob, const float* __restrict__ rowe,
        const float* __restrict__ cole, float* __restrict__ x) {
    int t = blockIdx.x, b = blockIdx.y, d = threadIdx.x;
    float v;
    if (t == 0) {
        v = cls[d];
    } else if (t <= Gc) {
        v = glob[(t - 1) * Dc + d];
    } else {
        int n = t - 1 - Gc;
        float acc = ib[d];
        #pragma unroll
        for (int c = 0; c < CINc; ++c)
            acc = fmaf(obs[(b * CINc + c) * Nc + n], iw[c * Dc + d], acc);
        v = acc + rowe[(n / Wc) * Dc + d] + cole[(n % Wc) * Dc + d];
    }
    x[((size_t)b * Tc + t) * Dc + d] = v;
}

// ---- LN stats: per-row (mean, rstd), wave per row ----
__global__ __launch_bounds__(256) void lnstats_kernel(
        const float* __restrict__ x, float2* __restrict__ st, int nrows) {
    const int w = threadIdx.x >> 6, l = threadIdx.x & 63;
    const int row = blockIdx.x * 4 + w;
    if (row >= nrows) return;
    const float4 v = *reinterpret_cast<const float4*>(x + (size_t)row * Dc + l * 4);
    float s = v.x + v.y + v.z + v.w;
    #pragma unroll
    for (int mk = 1; mk < 64; mk <<= 1) s += __shfl_xor(s, mk, 64);
    const float m = s * (1.0f / 256.0f);
    float vs = (v.x - m) * (v.x - m) + (v.y - m) * (v.y - m) +
               (v.z - m) * (v.z - m) + (v.w - m) * (v.w - m);
    #pragma unroll
    for (int mk = 1; mk < 64; mk <<= 1) vs += __shfl_xor(vs, mk, 64);
    if (l == 0)
        st[row] = make_float2(m, rsqrtf(vs * (1.0f / 256.0f) + 1e-5f));
}

// ---- full LN (used for the final norm only) ----
__global__ __launch_bounds__(256) void ln4_kernel(
        const float* __restrict__ x, const float* __restrict__ g,
        const float* __restrict__ b, float* __restrict__ out, int nrows) {
    const int w = threadIdx.x >> 6, l = threadIdx.x & 63;
    const int row = blockIdx.x * 4 + w;
    if (row >= nrows) return;
    const float4 v = *reinterpret_cast<const float4*>(x + (size_t)row * Dc + l * 4);
    float s = v.x + v.y + v.z + v.w;
    #pragma unroll
    for (int mk = 1; mk < 64; mk <<= 1) s += __shfl_xor(s, mk, 64);
    const float m = s * (1.0f / 256.0f);
    const float4 d = make_float4(v.x - m, v.y - m, v.z - m, v.w - m);
    float vs = d.x * d.x + d.y * d.y + d.z * d.z + d.w * d.w;
    #pragma unroll
    for (int mk = 1; mk < 64; mk <<= 1) vs += __shfl_xor(vs, mk, 64);
    const float rs = rsqrtf(vs * (1.0f / 256.0f) + 1e-5f);
    const float4 gg = *reinterpret_cast<const float4*>(g + l * 4);
    const float4 bb = *reinterpret_cast<const float4*>(b + l * 4);
    *reinterpret_cast<float4*>(out + (size_t)row * Dc + l * 4) =
        make_float4(d.x * rs * gg.x + bb.x, d.y * rs * gg.y + bb.y,
                    d.z * rs * gg.z + bb.z, d.w * rs * gg.w + bb.w);
}

// ---- LN + gather policy tokens ----
__global__ __launch_bounds__(256) void lnsel4_kernel(
        const float* __restrict__ xn, const float* __restrict__ g,
        const float* __restrict__ b, float* __restrict__ out) {
    const int w = threadIdx.x >> 6, l = threadIdx.x & 63;
    const int rr = blockIdx.x * 4 + w;
    const int bb = rr / Nc, n = rr % Nc;
    const float* xr = xn + ((size_t)bb * Tc + 1 + n) * Dc;
    const float4 v = *reinterpret_cast<const float4*>(xr + l * 4);
    float s = v.x + v.y + v.z + v.w;
    #pragma unroll
    for (int mk = 1; mk < 64; mk <<= 1) s += __shfl_xor(s, mk, 64);
    const float m = s * (1.0f / 256.0f);
    const float4 d = make_float4(v.x - m, v.y - m, v.z - m, v.w - m);
    float vs = d.x * d.x + d.y * d.y + d.z * d.z + d.w * d.w;
    #pragma unroll
    for (int mk = 1; mk < 64; mk <<= 1) vs += __shfl_xor(vs, mk, 64);
    const float rs = rsqrtf(vs * (1.0f / 256.0f) + 1e-5f);
    const float4 gg = *reinterpret_cast<const float4*>(g + l * 4);
    const float4 bb4 = *reinterpret_cast<const float4*>(b + l * 4);
    *reinterpret_cast<float4*>(out + ((size_t)bb * Nc + n) * Dc + l * 4) =
        make_float4(d.x * rs * gg.x + bb4.x, d.y * rs * gg.y + bb4.y,
                    d.z * rs * gg.z + bb4.z, d.w * rs * gg.w + bb4.w);
}

// ---- weight split+transpose ----
__global__ __launch_bounds__(256) void split_w_kernel(
        const float* __restrict__ qkv_w, const float* __restrict__ proj_w,
        const float* __restrict__ fc1_w, const float* __restrict__ fc2_w,
        const float* __restrict__ pol_w1, f16* __restrict__ out) {
    int r = blockIdx.x * 256 + threadIdx.x;
    float v; f16* dst; int NK;
    if (r < 1179648) {
        int layer = r / 196608, e = r % 196608;
        int n = e >> 8, k = e & 255;
        v = qkv_w[(size_t)layer * 196608 + k * 768 + n];
        dst = out + (size_t)layer * 393216 + n * 256 + k; NK = 196608;
    } else if (r < 1572864) {
        int rr = r - 1179648; int layer = rr / 65536, e = rr % 65536;
        int n = e >> 8, k = e & 255;
        v = proj_w[(size_t)layer * 65536 + k * 256 + n];
        dst = out + 2359296 + (size_t)layer * 131072 + n * 256 + k; NK = 65536;
    } else if (r < 2359296) {
        int rr = r - 1572864; int layer = rr / 131072, e = rr % 131072;
        int n = e >> 8, k = e & 255;
        v = fc1_w[(size_t)layer * 131072 + k * 512 + n];
        dst = out + 3145728 + (size_t)layer * 262144 + n * 256 + k; NK = 131072;
    } else if (r < 3145728) {
        int rr = r - 2359296; int layer = rr / 131072, e = rr % 131072;
        int n = e >> 9, k = e & 511;
        v = fc2_w[(size_t)layer * 131072 + k * 256 + n];
        dst = out + 4718592 + (size_t)layer * 262144 + n * 512 + k; NK = 131072;
    } else if (r < 3211264) {
        int rr = r - 3145728; int n = rr >> 8, k = rr & 255;
        v = pol_w1[k * 256 + n];
        dst = out + 6291456 + n * 256 + k; NK = 65536;
    } else return;
    f16 h = (f16)v;
    dst[0] = h;
    dst[NK] = (f16)(v - (float)h);
}

// ---- dense rel-bias table (row stride BPAD) ----
__global__ __launch_bounds__(256) void biasgen_kernel(
        const float* __restrict__ relb, const int* __restrict__ relidx,
        f16* __restrict__ bias) {
    const int q = blockIdx.x, h = blockIdx.y;
    const size_t rowo = ((size_t)h * Tc + q) * BPAD;
    const int* ridx = relidx + q * Tc;
    const float* rb = relb + h * BINSc;
    for (int kp = threadIdx.x; kp * 2 + 1 < Tc; kp += 256) {
        f16 b0 = (f16)rb[ridx[kp * 2]];
        f16 b1 = (f16)rb[ridx[kp * 2 + 1]];
        unsigned pk = (unsigned)__builtin_bit_cast(unsigned short, b0) |
                      ((unsigned)__builtin_bit_cast(unsigned short, b1) << 16);
        *reinterpret_cast<unsigned*>(&bias[rowo + kp * 2]) = pk;
    }
    if (threadIdx.x == 0)
        bias[rowo + Tc - 1] = (f16)rb[ridx[Tc - 1]];
}

// ---- fp16x3 MFMA GEMM. ACT: 0=none, 1=gelu, 2=QKV-split-out.
//      LNA: apply layernorm (stats + g/b) to A during staging ----
__device__ __forceinline__ int swz(int r, int g) {
    return r * 40 + ((g ^ ((r >> 3) & 3)) << 3);
}
template <int ACT, bool RES, bool LNA>
__global__ __launch_bounds__(256) void mgemm_kernel(
        const float* __restrict__ A, const f16* __restrict__ WT,
        const float* __restrict__ bias, const float* __restrict__ res,
        float* __restrict__ C, int M, int N, int K, int nbx,
        const float2* __restrict__ lnst, const float* __restrict__ lng,
        const float* __restrict__ lnb) {
    constexpr int BM = 128, BN = 64, BK = 32;
    __shared__ f16 Ah[BM * 40], Al[BM * 40];
    __shared__ f16 Bh[BN * 40], Bl[BN * 40];
    const int tid = threadIdx.x;
    const int v = xcd_swz(blockIdx.x, gridDim.x);
    const int m0 = (v / nbx) * BM, n0 = (v % nbx) * BN;
    const int w = tid >> 6, l = tid & 63;
    const int wm = (w >> 1) * 64, wn = (w & 1) * 32;
    const int lg = l >> 4, lr = l & 15;
    f32x4 acc[4][2] = {};
    const int sa_row = tid >> 1, sa_kc = (tid & 1) * 16;
    const int sb_part = tid >> 7;
    const int sb_n = (tid & 127) >> 1, sb_kc = (tid & 1) * 16;

    int gr = m0 + sa_row; if (gr >= M) gr = M - 1;
    float mu = 0.f, rsd = 1.f;
    if constexpr (LNA) { float2 s2 = lnst[gr]; mu = s2.x; rsd = s2.y; }

    for (int k0 = 0; k0 < K; k0 += BK) {
        {
            const float4* src = reinterpret_cast<const float4*>(
                A + (size_t)gr * K + k0 + sa_kc);
            f16x8 hv0, hv1, lv0, lv1;
            #pragma unroll
            for (int c = 0; c < 4; ++c) {
                float4 v4 = src[c];
                if constexpr (LNA) {
                    const float4 g4 = *reinterpret_cast<const float4*>(
                        lng + k0 + sa_kc + c * 4);
                    const float4 b4 = *reinterpret_cast<const float4*>(
                        lnb + k0 + sa_kc + c * 4);
                    v4.x = (v4.x - mu) * rsd * g4.x + b4.x;
                    v4.y = (v4.y - mu) * rsd * g4.y + b4.y;
                    v4.z = (v4.z - mu) * rsd * g4.z + b4.z;
                    v4.w = (v4.w - mu) * rsd * g4.w + b4.w;
                }
                f16 h0 = (f16)v4.x, h1 = (f16)v4.y, h2 = (f16)v4.z, h3 = (f16)v4.w;
                f16 l0 = (f16)(v4.x - (float)h0), l1 = (f16)(v4.y - (float)h1);
                f16 l2 = (f16)(v4.z - (float)h2), l3 = (f16)(v4.w - (float)h3);
                if (c < 2) {
                    hv0[c * 4 + 0] = h0; hv0[c * 4 + 1] = h1;
                    hv0[c * 4 + 2] = h2; hv0[c * 4 + 3] = h3;
                    lv0[c * 4 + 0] = l0; lv0[c * 4 + 1] = l1;
                    lv0[c * 4 + 2] = l2; lv0[c * 4 + 3] = l3;
                } else {
                    hv1[(c - 2) * 4 + 0] = h0; hv1[(c - 2) * 4 + 1] = h1;
                    hv1[(c - 2) * 4 + 2] = h2; hv1[(c - 2) * 4 + 3] = h3;
                    lv1[(c - 2) * 4 + 0] = l0; lv1[(c - 2) * 4 + 1] = l1;
                    lv1[(c - 2) * 4 + 2] = l2; lv1[(c - 2) * 4 + 3] = l3;
                }
            }
            const int g0 = sa_kc >> 3;
            *reinterpret_cast<f16x8*>(&Ah[swz(sa_row, g0)])     = hv0;
            *reinterpret_cast<f16x8*>(&Ah[swz(sa_row, g0 + 1)]) = hv1;
            *reinterpret_cast<f16x8*>(&Al[swz(sa_row, g0)])     = lv0;
            *reinterpret_cast<f16x8*>(&Al[swz(sa_row, g0 + 1)]) = lv1;
        }
        {
            const f16x8* src = reinterpret_cast<const f16x8*>(
                WT + (size_t)sb_part * N * K + (size_t)(n0 + sb_n) * K + k0 + sb_kc);
            f16* dbase = sb_part ? Bl : Bh;
            const int g0 = sb_kc >> 3;
            *reinterpret_cast<f16x8*>(&dbase[swz(sb_n, g0)])     = src[0];
            *reinterpret_cast<f16x8*>(&dbase[swz(sb_n, g0 + 1)]) = src[1];
        }
        __syncthreads();
        f16x8 afh[4], afl[4], bfh[2], bfl[2];
        #pragma unroll
        for (int mi = 0; mi < 4; ++mi) {
            int row = wm + mi * 16 + lr;
            afh[mi] = *reinterpret_cast<const f16x8*>(&Ah[swz(row, lg)]);
            afl[mi] = *reinterpret_cast<const f16x8*>(&Al[swz(row, lg)]);
        }
        #pragma unroll
        for (int ni = 0; ni < 2; ++ni) {
            int col = wn + ni * 16 + lr;
            bfh[ni] = *reinterpret_cast<const f16x8*>(&Bh[swz(col, lg)]);
            bfl[ni] = *reinterpret_cast<const f16x8*>(&Bl[swz(col, lg)]);
        }
        #pragma unroll
        for (int mi = 0; mi < 4; ++mi)
            #pragma unroll
            for (int ni = 0; ni < 2; ++ni) {
                acc[mi][ni] = __builtin_amdgcn_mfma_f32_16x16x32_f16(
                    afh[mi], bfh[ni], acc[mi][ni], 0, 0, 0);
                acc[mi][ni] = __builtin_amdgcn_mfma_f32_16x16x32_f16(
                    afh[mi], bfl[ni], acc[mi][ni], 0, 0, 0);
                acc[mi][ni] = __builtin_amdgcn_mfma_f32_16x16x32_f16(
                    afl[mi], bfh[ni], acc[mi][ni], 0, 0, 0);
            }
        __syncthreads();
    }
    float bv[2];
    #pragma unroll
    for (int ni = 0; ni < 2; ++ni) bv[ni] = bias[n0 + wn + ni * 16 + lr];
    #pragma unroll
    for (int mi = 0; mi < 4; ++mi) {
        #pragma unroll
        for (int r = 0; r < 4; ++r) {
            int grow = m0 + wm + mi * 16 + lg * 4 + r;
            if (grow >= M) continue;
            if constexpr (ACT == 2) {
                f16* base = (f16*)C;
                const int bb = grow / Tc;
                const int tt = grow - bb * Tc;
                #pragma unroll
                for (int ni = 0; ni < 2; ++ni) {
                    const int gcol = n0 + wn + ni * 16 + lr;
                    float vv = acc[mi][ni][r] + bv[ni];
                    if (gcol < 256) {                       // Q (scaled)
                        vv *= SCALE;
                        f16 hh = (f16)vv;
                        base[(size_t)grow * 256 + gcol] = hh;
                        base[QK_ST + (size_t)grow * 256 + gcol] = (f16)(vv - (float)hh);
                    } else if (gcol < 512) {                // K
                        f16 hh = (f16)vv;
                        base[OFF_KH + (size_t)grow * 256 + (gcol - 256)] = hh;
                        base[OFF_KH + QK_ST + (size_t)grow * 256 + (gcol - 256)] =
                            (f16)(vv - (float)hh);
                    } else {                                // V transposed
                        const int e = gcol - 512;
                        const int hh_ = e >> 5, dd = e & 31;
                        const size_t o =
                            ((size_t)((bb * NHc + hh_) * 32 + dd)) * VT_PAD + tt;
                        f16 hh = (f16)vv;
                        base[OFF_VTH + o] = hh;
                        base[OFF_VTH + VT_ST + o] = (f16)(vv - (float)hh);
                    }
                }
            } else {
                #pragma unroll
                for (int ni = 0; ni < 2; ++ni) {
                    int gcol = n0 + wn + ni * 16 + lr;
                    float vv = acc[mi][ni][r] + bv[ni];
                    if (ACT == 1) vv = gelu_f(vv);
                    if (RES) vv += res[(size_t)grow * N + gcol];
                    C[(size_t)grow * N + gcol] = vv;
                }
            }
        }
    }
}

// ---- MFMA flash attention v4: h-major XCD swizzle, bias-as-C-init,
//      row-sum via MFMA-ones (no sum shuffles), 2-deep K/V prefetch ----
__global__ __launch_bounds__(256, 4) void mattn2_kernel(
        const f16* __restrict__ qsp, float* __restrict__ o) {
    __shared__ __align__(16) f16 Kh_s[64][40], Kl_s[64][40];   // 10240 B
    __shared__ __align__(16) f16 VTh_s[32][72], VTl_s[32][72]; // 9216 B
    __shared__ __align__(16) f16 Ph_s[4][16][72], Pl_s[4][16][72]; // 18432 B
    const f16* __restrict__ Kh_g  = qsp + OFF_KH;
    const f16* __restrict__ VTh_g = qsp + OFF_VTH;
    const f16* __restrict__ bias_g = qsp + OFF_BIAS;

    const int tid = threadIdx.x;
    // h-major: each XCD owns ONE head for all batches; q-tiles consecutive.
    const int v = xcd_swz(blockIdx.x, 1280);
    const int h = v / 160;
    const int rem = v - h * 160;
    const int b = rem / 10, qt = rem - b * 10;
    const int q0 = qt * 64;
    const int w = tid >> 6, l = tid & 63;
    const int lr = l & 15, lg = l >> 4;

    // Q A-fragment (pre-split, pre-scaled)
    int qrow = q0 + w * 16 + lr; if (qrow >= Tc) qrow = Tc - 1;
    const f16* qp = qsp + ((size_t)(b * Tc + qrow)) * 256 + h * 32 + lg * 8;
    const f16x8 Qh = *reinterpret_cast<const f16x8*>(qp);
    const f16x8 Ql = *reinterpret_cast<const f16x8*>(qp + QK_ST);
    const int myq = q0 + w * 16 + lg * 4;

    int boff[4];
    #pragma unroll
    for (int r = 0; r < 4; ++r) {
        int qq = myq + r; if (qq >= Tc) qq = Tc - 1;
        boff[r] = (h * Tc + qq) * BPAD;
    }

    const int skrow = tid >> 2, skc = (tid & 3) * 8;   // K: 64 rows x 4 chunks
    const int svd = tid >> 3, svc = (tid & 7) * 8;     // VT: 32 d x 8 chunks
    const f16* vrow = VTh_g + ((size_t)((b * NHc + h) * 32 + svd)) * VT_PAD;

    struct KV { f16x8 kh, kl, vh, vl; };
    auto load_kv = [&](int k0) {
        KV r;
        int gk = k0 + skrow; if (gk >= Tc) gk = Tc - 1;
        const f16* kp = Kh_g + ((size_t)(b * Tc + gk)) * 256 + h * 32 + skc;
        r.kh = *reinterpret_cast<const f16x8*>(kp);
        r.kl = *reinterpret_cast<const f16x8*>(kp + QK_ST);
        const f16* vp = vrow + k0 + svc;
        r.vh = *reinterpret_cast<const f16x8*>(vp);
        r.vl = *reinterpret_cast<const f16x8*>(vp + VT_ST);
        return r;
    };
    auto load_bias = [&](int k0) {
        f16x16 bv;
        #pragma unroll
        for (int r = 0; r < 4; ++r)
            #pragma unroll
            for (int j = 0; j < 4; ++j) {
                int kk = k0 + j * 16 + lr; if (kk >= Tc) kk = Tc - 1;
                bv[r * 4 + j] = bias_g[boff[r] + kk];
            }
        return bv;
    };

    KV pA = load_kv(0);
    KV pB = load_kv(64);
    f16x16 bias_c = load_bias(0), bias_n;

    f16x8 kOnes;
    #pragma unroll
    for (int e = 0; e < 8; ++e) kOnes[e] = (f16)1.0f;

    float m_run[4];
    f32x4 Oacc[2] = {};
    f32x4 Oext = {};                 // row-sums (l) via MFMA-ones
    #pragma unroll
    for (int r = 0; r < 4; ++r) m_run[r] = -1e30f;

    for (int t = 0; t < 10; ++t) {
        const int k0 = t * 64;
        __syncthreads();
        *reinterpret_cast<f16x8*>(&Kh_s[skrow][skc]) = pA.kh;
        *reinterpret_cast<f16x8*>(&Kl_s[skrow][skc]) = pA.kl;
        *reinterpret_cast<f16x8*>(&VTh_s[svd][svc]) = pA.vh;
        *reinterpret_cast<f16x8*>(&VTl_s[svd][svc]) = pA.vl;
        pA = pB;
        if (t + 2 < 10) pB = load_kv(k0 + 128);
        __syncthreads();
        if (t + 1 < 10) bias_n = load_bias(k0 + 64);
        // ---- scores: C initialized with bias (free add) ----
        f32x4 sc[4];
        #pragma unroll
        for (int j = 0; j < 4; ++j) {
            const f16x8 kh = *reinterpret_cast<const f16x8*>(&Kh_s[j * 16 + lr][lg * 8]);
            const f16x8 kl = *reinterpret_cast<const f16x8*>(&Kl_s[j * 16 + lr][lg * 8]);
            f32x4 s = {(float)bias_c[j], (float)bias_c[4 + j],
                       (float)bias_c[8 + j], (float)bias_c[12 + j]};
            s = __builtin_amdgcn_mfma_f32_16x16x32_f16(Qh, kh, s, 0, 0, 0);
            s = __builtin_amdgcn_mfma_f32_16x16x32_f16(Qh, kl, s, 0, 0, 0);
            s = __builtin_amdgcn_mfma_f32_16x16x32_f16(Ql, kh, s, 0, 0, 0);
            sc[j] = s;
        }
        // ---- tail mask ----
        #pragma unroll
        for (int j = 0; j < 4; ++j) {
            const int kk = k0 + j * 16 + lr;
            if (kk >= Tc) { sc[j][0] = sc[j][1] = sc[j][2] = sc[j][3] = -1e30f; }
        }
        // ---- online max + exp; write split P (sum deferred to MFMA) ----
        #pragma unroll
        for (int r = 0; r < 4; ++r) {
            float tm = fmaxf(fmaxf(sc[0][r], sc[1][r]), fmaxf(sc[2][r], sc[3][r]));
            #pragma unroll
            for (int mk = 1; mk < 16; mk <<= 1) tm = fmaxf(tm, __shfl_xor(tm, mk, 64));
            const float mn = fmaxf(m_run[r], tm);
            const float resc = __expf(m_run[r] - mn);
            m_run[r] = mn;
            Oacc[0][r] *= resc; Oacc[1][r] *= resc; Oext[r] *= resc;
            const int prow = lg * 4 + r;
            #pragma unroll
            for (int j = 0; j < 4; ++j) {
                const float p = __expf(sc[j][r] - mn);
                const f16 ph = (f16)p;
                Ph_s[w][prow][j * 16 + lr] = ph;
                Pl_s[w][prow][j * 16 + lr] = (f16)(p - (float)ph);
            }
        }
        // ---- PV + row-sum accumulation (all on MFMA pipe) ----
        #pragma unroll
        for (int kc = 0; kc < 2; ++kc) {
            const f16x8 Pa = *reinterpret_cast<const f16x8*>(&Ph_s[w][lr][kc * 32 + lg * 8]);
            const f16x8 Pb = *reinterpret_cast<const f16x8*>(&Pl_s[w][lr][kc * 32 + lg * 8]);
            #pragma unroll
            for (int dt = 0; dt < 2; ++dt) {
                const f16x8 vh = *reinterpret_cast<const f16x8*>(&VTh_s[dt * 16 + lr][kc * 32 + lg * 8]);
                const f16x8 vl = *reinterpret_cast<const f16x8*>(&VTl_s[dt * 16 + lr][kc * 32 + lg * 8]);
                Oacc[dt] = __builtin_amdgcn_mfma_f32_16x16x32_f16(Pa, vh, Oacc[dt], 0, 0, 0);
                Oacc[dt] = __builtin_amdgcn_mfma_f32_16x16x32_f16(Pa, vl, Oacc[dt], 0, 0, 0);
                Oacc[dt] = __builtin_amdgcn_mfma_f32_16x16x32_f16(Pb, vh, Oacc[dt], 0, 0, 0);
            }
            Oext = __builtin_amdgcn_mfma_f32_16x16x32_f16(Pa, kOnes, Oext, 0, 0, 0);
            Oext = __builtin_amdgcn_mfma_f32_16x16x32_f16(Pb, kOnes, Oext, 0, 0, 0);
        }
        if (t + 1 < 10) bias_c = bias_n;
    }
    // ---- store ----
    #pragma unroll
    for (int r = 0; r < 4; ++r) {
        const int qq = myq + r;
        if (qq < Tc) {
            const float inv = 1.0f / Oext[r];
            float* op = o + ((size_t)b * Tc + qq) * Dc + h * HDc;
            op[lr]      = Oacc[0][r] * inv;
            op[16 + lr] = Oacc[1][r] * inv;
        }
    }
}

// ---- logits ----
__global__ __launch_bounds__(256) void logits_kernel(
        const float* __restrict__ ph, const float* __restrict__ w2,
        const float* __restrict__ b2, float* __restrict__ out) {
    __shared__ float s4[4];
    size_t r = blockIdx.x;
    int bb = (int)(r / Nc), n = (int)(r % Nc);
    float v = ph[r * Dc + threadIdx.x] * w2[threadIdx.x];
    float s = block_sum256(v, s4);
    if (threadIdx.x == 0) out[bb * (Nc + 1) + n] = s + b2[0];
}

// ---- value head ----
__global__ __launch_bounds__(256) void value_kernel(
        const float* __restrict__ xn, const float* __restrict__ g,
        const float* __restrict__ b, const float* __restrict__ w1,
        const float* __restrict__ b1, const float* __restrict__ w2,
        const float* __restrict__ b2, float* __restrict__ out) {
    __shared__ float s4[4];
    __shared__ float ts[Dc];
    const int bb = blockIdx.x, tid = threadIdx.x;
    float v = xn[(size_t)bb * Tc * Dc + tid];
    float m = block_sum256(v, s4) * (1.0f / 256.0f);
    float d = v - m;
    float var = block_sum256(d * d, s4) * (1.0f / 256.0f);
    ts[tid] = d * rsqrtf(var + 1e-5f) * g[tid] + b[tid];
    __syncthreads();
    float acc = b1[tid];
    #pragma unroll 8
    for (int i = 0; i < Dc; ++i) acc = fmaf(ts[i], w1[i * Dc + tid], acc);
    float hv = gelu_f(acc) * w2[tid];
    float s = block_sum256(hv, s4);
    if (tid == 0) out[bb * (Nc + 1) + Nc] = s + b2[0];
}

extern "C" void kernel_launch(void* const* d_in, const int* in_sizes, int n_in,
                              void* d_out, int out_size, void* d_ws, size_t ws_size,
                              hipStream_t stream) {
    const float* obs      = (const float*)d_in[0];
    const float* input_w  = (const float*)d_in[1];
    const float* input_b  = (const float*)d_in[2];
    const float* cls_tok  = (const float*)d_in[3];
    const float* glob_tok = (const float*)d_in[4];
    const float* row_emb  = (const float*)d_in[5];
    const float* col_emb  = (const float*)d_in[6];
    const float* ln1_g    = (const float*)d_in[7];
    const float* ln1_b    = (const float*)d_in[8];
    const float* qkv_w    = (const float*)d_in[9];
    const float* qkv_b    = (const float*)d_in[10];
    const float* proj_w   = (const float*)d_in[11];
    const float* proj_b   = (const float*)d_in[12];
    const float* rel_bias = (const float*)d_in[13];
    const float* ln2_g    = (const float*)d_in[14];
    const float* ln2_b    = (const float*)d_in[15];
    const float* fc1_w    = (const float*)d_in[16];
    const float* fc1_b    = (const float*)d_in[17];
    const float* fc2_w    = (const float*)d_in[18];
    const float* fc2_b    = (const float*)d_in[19];
    const float* norm_g   = (const float*)d_in[20];
    const float* norm_b   = (const float*)d_in[21];
    const float* pol_ln_g = (const float*)d_in[22];
    const float* pol_ln_b = (const float*)d_in[23];
    const float* pol_w1   = (const float*)d_in[24];
    const float* pol_b1   = (const float*)d_in[25];
    const float* pol_w2   = (const float*)d_in[26];
    const float* pol_b2   = (const float*)d_in[27];
    const float* val_ln_g = (const float*)d_in[28];
    const float* val_ln_b = (const float*)d_in[29];
    const float* val_w1   = (const float*)d_in[30];
    const float* val_b1   = (const float*)d_in[31];
    const float* val_w2   = (const float*)d_in[32];
    const float* val_b2   = (const float*)d_in[33];
    const int*   rel_idx  = (const int*)d_in[34];
    float* out = (float*)d_out;

    float* ws = (float*)d_ws;
    const size_t SZ_XD = (size_t)BT * Dc;        // 2,371,584 floats
    float* X  = ws;
    float* Hb = ws + SZ_XD;
    float* R  = ws + 2 * SZ_XD;                  // aliased region (R_FLOATS)
    f16* qsp = (f16*)R;                          // Qh|Ql|Kh|Kl|VTh|VTl|bias
    f16* bias_g = qsp + OFF_BIAS;
    float* MLPH = R;                             // alias (MLP phase)
    float* PT = R;                               // alias (head phase)
    float* PH = R + (size_t)Bc * Nc * Dc;
    f16* wsplit = (f16*)(R + R_FLOATS);          // 12.85 MB
    float2* lnst = (float2*)(wsplit + 6422528);  // BT float2 (74 KB)

    auto qkvT = [&](int l) { return wsplit + (size_t)l * 393216; };
    auto projT = [&](int l) { return wsplit + 2359296 + (size_t)l * 131072; };
    auto fc1T = [&](int l) { return wsplit + 3145728 + (size_t)l * 262144; };
    auto fc2T = [&](int l) { return wsplit + 4718592 + (size_t)l * 262144; };
    f16* polT = wsplit + 6291456;

    split_w_kernel<<<12544, 256, 0, stream>>>(
        qkv_w, proj_w, fc1_w, fc2_w, pol_w1, wsplit);

    embed_kernel<<<dim3(Tc, Bc), 256, 0, stream>>>(
        obs, input_w, input_b, cls_tok, glob_tok, row_emb, col_emb, X);

    for (int l = 0; l < DEPTHc; ++l) {
        lnstats_kernel<<<(BT + 3) / 4, 256, 0, stream>>>(X, lnst, BT);
        mgemm_kernel<2, false, true><<<876, 256, 0, stream>>>(
            X, qkvT(l), qkv_b + l * 3 * Dc, nullptr, (float*)qsp, BT, 3 * Dc, Dc, 12,
            lnst, ln1_g + l * Dc, ln1_b + l * Dc);
        biasgen_kernel<<<dim3(Tc, NHc), 256, 0, stream>>>(
            rel_bias + l * NHc * BINSc, rel_idx, bias_g);
        mattn2_kernel<<<1280, 256, 0, stream>>>(qsp, Hb);
        mgemm_kernel<0, true, false><<<292, 256, 0, stream>>>(
            Hb, projT(l), proj_b + l * Dc, X, X, BT, Dc, Dc, 4,
            nullptr, nullptr, nullptr);
        lnstats_kernel<<<(BT + 3) / 4, 256, 0, stream>>>(X, lnst, BT);
        mgemm_kernel<1, false, true><<<584, 256, 0, stream>>>(
            X, fc1T(l), fc1_b + l * MLPc, nullptr, MLPH, BT, MLPc, Dc, 8,
            lnst, ln2_g + l * Dc, ln2_b + l * Dc);
        mgemm_kernel<0, true, false><<<292, 256, 0, stream>>>(
            MLPH, fc2T(l), fc2_b + l * Dc, X, X, BT, Dc, MLPc, 4,
            nullptr, nullptr, nullptr);
    }

    ln4_kernel<<<(BT + 3) / 4, 256, 0, stream>>>(X, norm_g, norm_b, Hb, BT);
    lnsel4_kernel<<<Bc * Nc / 4, 256, 0, stream>>>(Hb, pol_ln_g, pol_ln_b, PT);
    mgemm_kernel<1, false, false><<<288, 256, 0, stream>>>(
        PT, polT, pol_b1, nullptr, PH, Bc * Nc, Dc, Dc, 4,
        nullptr, nullptr, nullptr);
    logits_kernel<<<Bc * Nc, 256, 0, stream>>>(PH, pol_w2, pol_b2, out);
    value_kernel<<<Bc, 256, 0, stream>>>(
        Hb, val_ln_g, val_ln_b, val_w1, val_b1, val_w2, val_b2, out);
}

// Round 8
// 1194.628 us; speedup vs baseline: 5.6603x; 1.0881x over previous
//
#include <hip/hip_runtime.h>
#include <math.h>

// ---- problem constants ----
constexpr int Hc = 24, Wc = 24, Nc = 576, BINSc = 82, Gc = 2;
constexpr int Tc = Nc + 1 + Gc;          // 579
constexpr int Dc = 256, NHc = 8, HDc = 32, DEPTHc = 6, MLPc = 512;
constexpr int Bc = 16, CINc = 10;
constexpr int BT = Bc * Tc;              // 9264
constexpr float SCALE = 0.17677669529663687f;  // 1/sqrt(32)

typedef _Float16 f16;
typedef _Float16 f16x4 __attribute__((ext_vector_type(4)));
typedef _Float16 f16x8 __attribute__((ext_vector_type(8)));
typedef _Float16 f16x16 __attribute__((ext_vector_type(16)));
typedef float f32x4 __attribute__((ext_vector_type(4)));

// ---- split-QKV region layout (f16 elements, base = R) ----
constexpr size_t QK_ST   = (size_t)BT * 256;           // 2,371,584
constexpr int    VT_PAD  = 640;
constexpr size_t VT_ST   = (size_t)Bc * NHc * 32 * VT_PAD;  // 2,621,440
constexpr size_t OFF_KH  = 2 * QK_ST;
constexpr size_t OFF_VTH = 4 * QK_ST;
constexpr size_t OFF_BIAS = 4 * QK_ST + 2 * VT_ST;     // 14,729,216
constexpr int    BPAD    = 580;                        // bias row stride
constexpr size_t R_F16   = OFF_BIAS + (size_t)NHc * Tc * BPAD;  // 17,415,776
constexpr size_t R_FLOATS = 8707904;

// bijective XCD chunk swizzle (T1, m204 variant)
__device__ __forceinline__ int xcd_swz(int d, int nwg) {
    const int q = nwg >> 3, r = nwg & 7;
    const int x = d & 7, s = d >> 3;
    return x * q + (x < r ? x : r) + s;
}

__device__ __forceinline__ float gelu_f(float x) {
    return 0.5f * x * (1.0f + erff(x * 0.70710678118654752f));
}

__device__ __forceinline__ float block_sum256(float v, float* s4) {
    #pragma unroll
    for (int off = 32; off > 0; off >>= 1) v += __shfl_down(v, off, 64);
    __syncthreads();
    if ((threadIdx.x & 63) == 0) s4[threadIdx.x >> 6] = v;
    __syncthreads();
    return s4[0] + s4[1] + s4[2] + s4[3];
}

// ---- embed ----
__global__ __launch_bounds__(256) void embed_kernel(
        const float* __restrict__ obs, const float* __restrict__ iw,
        const float* __restrict__ ib, const float* __restrict__ cls,
        const float* __restrict__ glob, const float* __restrict__ rowe,
        const float* __restrict__ cole, float* __restrict__ x) {
    int t = blockIdx.x, b = blockIdx.y, d = threadIdx.x;
    float v;
    if (t == 0) {
        v = cls[d];
    } else if (t <= Gc) {
        v = glob[(t - 1) * Dc + d];
    } else {
        int n = t - 1 - Gc;
        float acc = ib[d];
        #pragma unroll
        for (int c = 0; c < CINc; ++c)
            acc = fmaf(obs[(b * CINc + c) * Nc + n], iw[c * Dc + d], acc);
        v = acc + rowe[(n / Wc) * Dc + d] + cole[(n % Wc) * Dc + d];
    }
    x[((size_t)b * Tc + t) * Dc + d] = v;
}

// ---- LN + h/l split: X row -> Aq (h at [row][256], l at +QK_ST) ----
__global__ __launch_bounds__(256) void splitA_ln_kernel(
        const float* __restrict__ x, const float* __restrict__ g,
        const float* __restrict__ b, f16* __restrict__ outp) {
    const int w = threadIdx.x >> 6, l = threadIdx.x & 63;
    const int row = blockIdx.x * 4 + w;
    const float4 v = *reinterpret_cast<const float4*>(x + (size_t)row * Dc + l * 4);
    float s = v.x + v.y + v.z + v.w;
    #pragma unroll
    for (int mk = 1; mk < 64; mk <<= 1) s += __shfl_xor(s, mk, 64);
    const float m = s * (1.0f / 256.0f);
    const float4 d = make_float4(v.x - m, v.y - m, v.z - m, v.w - m);
    float vs = d.x * d.x + d.y * d.y + d.z * d.z + d.w * d.w;
    #pragma unroll
    for (int mk = 1; mk < 64; mk <<= 1) vs += __shfl_xor(vs, mk, 64);
    const float rs = rsqrtf(vs * (1.0f / 256.0f) + 1e-5f);
    const float4 gg = *reinterpret_cast<const float4*>(g + l * 4);
    const float4 bb = *reinterpret_cast<const float4*>(b + l * 4);
    const float y0 = d.x * rs * gg.x + bb.x, y1 = d.y * rs * gg.y + bb.y;
    const float y2 = d.z * rs * gg.z + bb.z, y3 = d.w * rs * gg.w + bb.w;
    const f16 h0 = (f16)y0, h1 = (f16)y1, h2 = (f16)y2, h3 = (f16)y3;
    f16x4 hv = {h0, h1, h2, h3};
    f16x4 lv = {(f16)(y0 - (float)h0), (f16)(y1 - (float)h1),
                (f16)(y2 - (float)h2), (f16)(y3 - (float)h3)};
    *reinterpret_cast<f16x4*>(outp + (size_t)row * Dc + l * 4) = hv;
    *reinterpret_cast<f16x4*>(outp + QK_ST + (size_t)row * Dc + l * 4) = lv;
}

// ---- double-LN + gather policy tokens: X -> LN(norm) -> LN(pol) -> PT ----
__global__ __launch_bounds__(256) void lnself_kernel(
        const float* __restrict__ X, const float* __restrict__ ng,
        const float* __restrict__ nb, const float* __restrict__ pg,
        const float* __restrict__ pb, float* __restrict__ out) {
    const int w = threadIdx.x >> 6, l = threadIdx.x & 63;
    const int rr = blockIdx.x * 4 + w;
    const int bb = rr / Nc, n = rr % Nc;
    const float* xr = X + ((size_t)bb * Tc + 1 + n) * Dc;
    const float4 v = *reinterpret_cast<const float4*>(xr + l * 4);
    float s = v.x + v.y + v.z + v.w;
    #pragma unroll
    for (int mk = 1; mk < 64; mk <<= 1) s += __shfl_xor(s, mk, 64);
    const float m = s * (1.0f / 256.0f);
    float4 d = make_float4(v.x - m, v.y - m, v.z - m, v.w - m);
    float vs = d.x * d.x + d.y * d.y + d.z * d.z + d.w * d.w;
    #pragma unroll
    for (int mk = 1; mk < 64; mk <<= 1) vs += __shfl_xor(vs, mk, 64);
    const float rs = rsqrtf(vs * (1.0f / 256.0f) + 1e-5f);
    const float4 gg = *reinterpret_cast<const float4*>(ng + l * 4);
    const float4 bb4 = *reinterpret_cast<const float4*>(nb + l * 4);
    float4 y = make_float4(d.x * rs * gg.x + bb4.x, d.y * rs * gg.y + bb4.y,
                           d.z * rs * gg.z + bb4.z, d.w * rs * gg.w + bb4.w);
    // second LN (pol)
    float s2 = y.x + y.y + y.z + y.w;
    #pragma unroll
    for (int mk = 1; mk < 64; mk <<= 1) s2 += __shfl_xor(s2, mk, 64);
    const float m2 = s2 * (1.0f / 256.0f);
    float4 d2 = make_float4(y.x - m2, y.y - m2, y.z - m2, y.w - m2);
    float vs2 = d2.x * d2.x + d2.y * d2.y + d2.z * d2.z + d2.w * d2.w;
    #pragma unroll
    for (int mk = 1; mk < 64; mk <<= 1) vs2 += __shfl_xor(vs2, mk, 64);
    const float rs2 = rsqrtf(vs2 * (1.0f / 256.0f) + 1e-5f);
    const float4 pg4 = *reinterpret_cast<const float4*>(pg + l * 4);
    const float4 pb4 = *reinterpret_cast<const float4*>(pb + l * 4);
    *reinterpret_cast<float4*>(out + ((size_t)bb * Nc + n) * Dc + l * 4) =
        make_float4(d2.x * rs2 * pg4.x + pb4.x, d2.y * rs2 * pg4.y + pb4.y,
                    d2.z * rs2 * pg4.z + pb4.z, d2.w * rs2 * pg4.w + pb4.w);
}

// ---- weight split+transpose ----
__global__ __launch_bounds__(256) void split_w_kernel(
        const float* __restrict__ qkv_w, const float* __restrict__ proj_w,
        const float* __restrict__ fc1_w, const float* __restrict__ fc2_w,
        const float* __restrict__ pol_w1, f16* __restrict__ out) {
    int r = blockIdx.x * 256 + threadIdx.x;
    float v; f16* dst; int NK;
    if (r < 1179648) {
        int layer = r / 196608, e = r % 196608;
        int n = e >> 8, k = e & 255;
        v = qkv_w[(size_t)layer * 196608 + k * 768 + n];
        dst = out + (size_t)layer * 393216 + n * 256 + k; NK = 196608;
    } else if (r < 1572864) {
        int rr = r - 1179648; int layer = rr / 65536, e = rr % 65536;
        int n = e >> 8, k = e & 255;
        v = proj_w[(size_t)layer * 65536 + k * 256 + n];
        dst = out + 2359296 + (size_t)layer * 131072 + n * 256 + k; NK = 65536;
    } else if (r < 2359296) {
        int rr = r - 1572864; int layer = rr / 131072, e = rr % 131072;
        int n = e >> 8, k = e & 255;
        v = fc1_w[(size_t)layer * 131072 + k * 512 + n];
        dst = out + 3145728 + (size_t)layer * 262144 + n * 256 + k; NK = 131072;
    } else if (r < 3145728) {
        int rr = r - 2359296; int layer = rr / 131072, e = rr % 131072;
        int n = e >> 9, k = e & 511;
        v = fc2_w[(size_t)layer * 131072 + k * 256 + n];
        dst = out + 4718592 + (size_t)layer * 262144 + n * 512 + k; NK = 131072;
    } else if (r < 3211264) {
        int rr = r - 3145728; int n = rr >> 8, k = rr & 255;
        v = pol_w1[k * 256 + n];
        dst = out + 6291456 + n * 256 + k; NK = 65536;
    } else return;
    f16 h = (f16)v;
    dst[0] = h;
    dst[NK] = (f16)(v - (float)h);
}

// ---- dense rel-bias table (row stride BPAD) ----
__global__ __launch_bounds__(256) void biasgen_kernel(
        const float* __restrict__ relb, const int* __restrict__ relidx,
        f16* __restrict__ bias) {
    const int q = blockIdx.x, h = blockIdx.y;
    const size_t rowo = ((size_t)h * Tc + q) * BPAD;
    const int* ridx = relidx + q * Tc;
    const float* rb = relb + h * BINSc;
    for (int kp = threadIdx.x; kp * 2 + 1 < Tc; kp += 256) {
        f16 b0 = (f16)rb[ridx[kp * 2]];
        f16 b1 = (f16)rb[ridx[kp * 2 + 1]];
        unsigned pk = (unsigned)__builtin_bit_cast(unsigned short, b0) |
                      ((unsigned)__builtin_bit_cast(unsigned short, b1) << 16);
        *reinterpret_cast<unsigned*>(&bias[rowo + kp * 2]) = pk;
    }
    if (threadIdx.x == 0)
        bias[rowo + Tc - 1] = (f16)rb[ridx[Tc - 1]];
}

// ---- fp16x3 MFMA GEMM.
// ACT: 0=none, 1=gelu, 2=QKV-split-out, 3=gelu+split-out(osplit)
// PSA: A is pre-split f16 (h at A, l at A + M*K); else fp32 (split on stage)
__device__ __forceinline__ int swz(int r, int g) {
    return r * 40 + ((g ^ ((r >> 3) & 3)) << 3);
}
template <int ACT, bool RES, bool PSA>
__global__ __launch_bounds__(256) void mgemm_kernel(
        const void* __restrict__ Ap, const f16* __restrict__ WT,
        const float* __restrict__ bias, const float* __restrict__ res,
        void* __restrict__ Cp, int M, int N, int K, int nbx, size_t osplit) {
    constexpr int BM = 128, BN = 64, BK = 32;
    __shared__ f16 Ah[BM * 40], Al[BM * 40];
    __shared__ f16 Bh[BN * 40], Bl[BN * 40];
    const int tid = threadIdx.x;
    const int v = xcd_swz(blockIdx.x, gridDim.x);
    const int m0 = (v / nbx) * BM, n0 = (v % nbx) * BN;
    const int w = tid >> 6, l = tid & 63;
    const int wm = (w >> 1) * 64, wn = (w & 1) * 32;
    const int lg = l >> 4, lr = l & 15;
    f32x4 acc[4][2] = {};
    const int sa_row = tid >> 1, sa_kc = (tid & 1) * 16;
    const int sb_part = tid >> 7;
    const int sb_n = (tid & 127) >> 1, sb_kc = (tid & 1) * 16;

    int gr = m0 + sa_row; if (gr >= M) gr = M - 1;

    for (int k0 = 0; k0 < K; k0 += BK) {
        const int g0 = sa_kc >> 3;
        if constexpr (PSA) {
            const f16* Ah_g = (const f16*)Ap;
            const f16* src = Ah_g + (size_t)gr * K + k0 + sa_kc;
            *reinterpret_cast<f16x8*>(&Ah[swz(sa_row, g0)]) =
                *reinterpret_cast<const f16x8*>(src);
            *reinterpret_cast<f16x8*>(&Ah[swz(sa_row, g0 + 1)]) =
                *reinterpret_cast<const f16x8*>(src + 8);
            const f16* srcl = src + (size_t)M * K;
            *reinterpret_cast<f16x8*>(&Al[swz(sa_row, g0)]) =
                *reinterpret_cast<const f16x8*>(srcl);
            *reinterpret_cast<f16x8*>(&Al[swz(sa_row, g0 + 1)]) =
                *reinterpret_cast<const f16x8*>(srcl + 8);
        } else {
            const float4* src = reinterpret_cast<const float4*>(
                (const float*)Ap + (size_t)gr * K + k0 + sa_kc);
            f16x8 hv0, hv1, lv0, lv1;
            #pragma unroll
            for (int c = 0; c < 4; ++c) {
                float4 v4 = src[c];
                f16 h0 = (f16)v4.x, h1 = (f16)v4.y, h2 = (f16)v4.z, h3 = (f16)v4.w;
                f16 l0 = (f16)(v4.x - (float)h0), l1 = (f16)(v4.y - (float)h1);
                f16 l2 = (f16)(v4.z - (float)h2), l3 = (f16)(v4.w - (float)h3);
                if (c < 2) {
                    hv0[c * 4 + 0] = h0; hv0[c * 4 + 1] = h1;
                    hv0[c * 4 + 2] = h2; hv0[c * 4 + 3] = h3;
                    lv0[c * 4 + 0] = l0; lv0[c * 4 + 1] = l1;
                    lv0[c * 4 + 2] = l2; lv0[c * 4 + 3] = l3;
                } else {
                    hv1[(c - 2) * 4 + 0] = h0; hv1[(c - 2) * 4 + 1] = h1;
                    hv1[(c - 2) * 4 + 2] = h2; hv1[(c - 2) * 4 + 3] = h3;
                    lv1[(c - 2) * 4 + 0] = l0; lv1[(c - 2) * 4 + 1] = l1;
                    lv1[(c - 2) * 4 + 2] = l2; lv1[(c - 2) * 4 + 3] = l3;
                }
            }
            *reinterpret_cast<f16x8*>(&Ah[swz(sa_row, g0)])     = hv0;
            *reinterpret_cast<f16x8*>(&Ah[swz(sa_row, g0 + 1)]) = hv1;
            *reinterpret_cast<f16x8*>(&Al[swz(sa_row, g0)])     = lv0;
            *reinterpret_cast<f16x8*>(&Al[swz(sa_row, g0 + 1)]) = lv1;
        }
        {
            const f16x8* src = reinterpret_cast<const f16x8*>(
                WT + (size_t)sb_part * N * K + (size_t)(n0 + sb_n) * K + k0 + sb_kc);
            f16* dbase = sb_part ? Bl : Bh;
            const int gb = sb_kc >> 3;
            *reinterpret_cast<f16x8*>(&dbase[swz(sb_n, gb)])     = src[0];
            *reinterpret_cast<f16x8*>(&dbase[swz(sb_n, gb + 1)]) = src[1];
        }
        __syncthreads();
        f16x8 afh[4], afl[4], bfh[2], bfl[2];
        #pragma unroll
        for (int mi = 0; mi < 4; ++mi) {
            int row = wm + mi * 16 + lr;
            afh[mi] = *reinterpret_cast<const f16x8*>(&Ah[swz(row, lg)]);
            afl[mi] = *reinterpret_cast<const f16x8*>(&Al[swz(row, lg)]);
        }
        #pragma unroll
        for (int ni = 0; ni < 2; ++ni) {
            int col = wn + ni * 16 + lr;
            bfh[ni] = *reinterpret_cast<const f16x8*>(&Bh[swz(col, lg)]);
            bfl[ni] = *reinterpret_cast<const f16x8*>(&Bl[swz(col, lg)]);
        }
        #pragma unroll
        for (int mi = 0; mi < 4; ++mi)
            #pragma unroll
            for (int ni = 0; ni < 2; ++ni) {
                acc[mi][ni] = __builtin_amdgcn_mfma_f32_16x16x32_f16(
                    afh[mi], bfh[ni], acc[mi][ni], 0, 0, 0);
                acc[mi][ni] = __builtin_amdgcn_mfma_f32_16x16x32_f16(
                    afh[mi], bfl[ni], acc[mi][ni], 0, 0, 0);
                acc[mi][ni] = __builtin_amdgcn_mfma_f32_16x16x32_f16(
                    afl[mi], bfh[ni], acc[mi][ni], 0, 0, 0);
            }
        __syncthreads();
    }
    float bv[2];
    #pragma unroll
    for (int ni = 0; ni < 2; ++ni) bv[ni] = bias[n0 + wn + ni * 16 + lr];
    #pragma unroll
    for (int mi = 0; mi < 4; ++mi) {
        #pragma unroll
        for (int r = 0; r < 4; ++r) {
            int grow = m0 + wm + mi * 16 + lg * 4 + r;
            if (grow >= M) continue;
            if constexpr (ACT == 2) {
                f16* base = (f16*)Cp;
                const int bb = grow / Tc;
                const int tt = grow - bb * Tc;
                #pragma unroll
                for (int ni = 0; ni < 2; ++ni) {
                    const int gcol = n0 + wn + ni * 16 + lr;
                    float vv = acc[mi][ni][r] + bv[ni];
                    if (gcol < 256) {                       // Q (scaled)
                        vv *= SCALE;
                        f16 hh = (f16)vv;
                        base[(size_t)grow * 256 + gcol] = hh;
                        base[QK_ST + (size_t)grow * 256 + gcol] = (f16)(vv - (float)hh);
                    } else if (gcol < 512) {                // K
                        f16 hh = (f16)vv;
                        base[OFF_KH + (size_t)grow * 256 + (gcol - 256)] = hh;
                        base[OFF_KH + QK_ST + (size_t)grow * 256 + (gcol - 256)] =
                            (f16)(vv - (float)hh);
                    } else {                                // V transposed
                        const int e = gcol - 512;
                        const int hh_ = e >> 5, dd = e & 31;
                        const size_t o =
                            ((size_t)((bb * NHc + hh_) * 32 + dd)) * VT_PAD + tt;
                        f16 hh = (f16)vv;
                        base[OFF_VTH + o] = hh;
                        base[OFF_VTH + VT_ST + o] = (f16)(vv - (float)hh);
                    }
                }
            } else if constexpr (ACT == 3) {
                f16* base = (f16*)Cp;
                #pragma unroll
                for (int ni = 0; ni < 2; ++ni) {
                    const int gcol = n0 + wn + ni * 16 + lr;
                    float vv = gelu_f(acc[mi][ni][r] + bv[ni]);
                    f16 hh = (f16)vv;
                    base[(size_t)grow * N + gcol] = hh;
                    base[osplit + (size_t)grow * N + gcol] = (f16)(vv - (float)hh);
                }
            } else {
                float* C = (float*)Cp;
                #pragma unroll
                for (int ni = 0; ni < 2; ++ni) {
                    int gcol = n0 + wn + ni * 16 + lr;
                    float vv = acc[mi][ni][r] + bv[ni];
                    if (ACT == 1) vv = gelu_f(vv);
                    if (RES) vv += res[(size_t)grow * N + gcol];
                    C[(size_t)grow * N + gcol] = vv;
                }
            }
        }
    }
}

// ---- MFMA flash attention v5: split f16 output (feeds proj's PSA path) ----
__global__ __launch_bounds__(256, 4) void mattn2_kernel(
        const f16* __restrict__ qsp, f16* __restrict__ ao) {
    __shared__ __align__(16) f16 Kh_s[64][40], Kl_s[64][40];   // 10240 B
    __shared__ __align__(16) f16 VTh_s[32][72], VTl_s[32][72]; // 9216 B
    __shared__ __align__(16) f16 Ph_s[4][16][72], Pl_s[4][16][72]; // 18432 B
    const f16* __restrict__ Kh_g  = qsp + OFF_KH;
    const f16* __restrict__ VTh_g = qsp + OFF_VTH;
    const f16* __restrict__ bias_g = qsp + OFF_BIAS;

    const int tid = threadIdx.x;
    const int v = xcd_swz(blockIdx.x, 1280);   // h-major: XCD owns one head
    const int h = v / 160;
    const int rem = v - h * 160;
    const int b = rem / 10, qt = rem - b * 10;
    const int q0 = qt * 64;
    const int w = tid >> 6, l = tid & 63;
    const int lr = l & 15, lg = l >> 4;

    int qrow = q0 + w * 16 + lr; if (qrow >= Tc) qrow = Tc - 1;
    const f16* qp = qsp + ((size_t)(b * Tc + qrow)) * 256 + h * 32 + lg * 8;
    const f16x8 Qh = *reinterpret_cast<const f16x8*>(qp);
    const f16x8 Ql = *reinterpret_cast<const f16x8*>(qp + QK_ST);
    const int myq = q0 + w * 16 + lg * 4;

    int boff[4];
    #pragma unroll
    for (int r = 0; r < 4; ++r) {
        int qq = myq + r; if (qq >= Tc) qq = Tc - 1;
        boff[r] = (h * Tc + qq) * BPAD;
    }

    const int skrow = tid >> 2, skc = (tid & 3) * 8;
    const int svd = tid >> 3, svc = (tid & 7) * 8;
    const f16* vrow = VTh_g + ((size_t)((b * NHc + h) * 32 + svd)) * VT_PAD;

    struct KV { f16x8 kh, kl, vh, vl; };
    auto load_kv = [&](int k0) {
        KV r;
        int gk = k0 + skrow; if (gk >= Tc) gk = Tc - 1;
        const f16* kp = Kh_g + ((size_t)(b * Tc + gk)) * 256 + h * 32 + skc;
        r.kh = *reinterpret_cast<const f16x8*>(kp);
        r.kl = *reinterpret_cast<const f16x8*>(kp + QK_ST);
        const f16* vp = vrow + k0 + svc;
        r.vh = *reinterpret_cast<const f16x8*>(vp);
        r.vl = *reinterpret_cast<const f16x8*>(vp + VT_ST);
        return r;
    };
    auto load_bias = [&](int k0) {
        f16x16 bv;
        #pragma unroll
        for (int r = 0; r < 4; ++r)
            #pragma unroll
            for (int j = 0; j < 4; ++j) {
                int kk = k0 + j * 16 + lr; if (kk >= Tc) kk = Tc - 1;
                bv[r * 4 + j] = bias_g[boff[r] + kk];
            }
        return bv;
    };

    KV pA = load_kv(0);
    KV pB = load_kv(64);
    f16x16 bias_c = load_bias(0), bias_n;

    f16x8 kOnes;
    #pragma unroll
    for (int e = 0; e < 8; ++e) kOnes[e] = (f16)1.0f;

    float m_run[4];
    f32x4 Oacc[2] = {};
    f32x4 Oext = {};
    #pragma unroll
    for (int r = 0; r < 4; ++r) m_run[r] = -1e30f;

    for (int t = 0; t < 10; ++t) {
        const int k0 = t * 64;
        __syncthreads();
        *reinterpret_cast<f16x8*>(&Kh_s[skrow][skc]) = pA.kh;
        *reinterpret_cast<f16x8*>(&Kl_s[skrow][skc]) = pA.kl;
        *reinterpret_cast<f16x8*>(&VTh_s[svd][svc]) = pA.vh;
        *reinterpret_cast<f16x8*>(&VTl_s[svd][svc]) = pA.vl;
        pA = pB;
        if (t + 2 < 10) pB = load_kv(k0 + 128);
        __syncthreads();
        if (t + 1 < 10) bias_n = load_bias(k0 + 64);
        f32x4 sc[4];
        #pragma unroll
        for (int j = 0; j < 4; ++j) {
            const f16x8 kh = *reinterpret_cast<const f16x8*>(&Kh_s[j * 16 + lr][lg * 8]);
            const f16x8 kl = *reinterpret_cast<const f16x8*>(&Kl_s[j * 16 + lr][lg * 8]);
            f32x4 s = {(float)bias_c[j], (float)bias_c[4 + j],
                       (float)bias_c[8 + j], (float)bias_c[12 + j]};
            s = __builtin_amdgcn_mfma_f32_16x16x32_f16(Qh, kh, s, 0, 0, 0);
            s = __builtin_amdgcn_mfma_f32_16x16x32_f16(Qh, kl, s, 0, 0, 0);
            s = __builtin_amdgcn_mfma_f32_16x16x32_f16(Ql, kh, s, 0, 0, 0);
            sc[j] = s;
        }
        #pragma unroll
        for (int j = 0; j < 4; ++j) {
            const int kk = k0 + j * 16 + lr;
            if (kk >= Tc) { sc[j][0] = sc[j][1] = sc[j][2] = sc[j][3] = -1e30f; }
        }
        #pragma unroll
        for (int r = 0; r < 4; ++r) {
            float tm = fmaxf(fmaxf(sc[0][r], sc[1][r]), fmaxf(sc[2][r], sc[3][r]));
            #pragma unroll
            for (int mk = 1; mk < 16; mk <<= 1) tm = fmaxf(tm, __shfl_xor(tm, mk, 64));
            const float mn = fmaxf(m_run[r], tm);
            const float resc = __expf(m_run[r] - mn);
            m_run[r] = mn;
            Oacc[0][r] *= resc; Oacc[1][r] *= resc; Oext[r] *= resc;
            const int prow = lg * 4 + r;
            #pragma unroll
            for (int j = 0; j < 4; ++j) {
                const float p = __expf(sc[j][r] - mn);
                const f16 ph = (f16)p;
                Ph_s[w][prow][j * 16 + lr] = ph;
                Pl_s[w][prow][j * 16 + lr] = (f16)(p - (float)ph);
            }
        }
        #pragma unroll
        for (int kc = 0; kc < 2; ++kc) {
            const f16x8 Pa = *reinterpret_cast<const f16x8*>(&Ph_s[w][lr][kc * 32 + lg * 8]);
            const f16x8 Pb = *reinterpret_cast<const f16x8*>(&Pl_s[w][lr][kc * 32 + lg * 8]);
            #pragma unroll
            for (int dt = 0; dt < 2; ++dt) {
                const f16x8 vh = *reinterpret_cast<const f16x8*>(&VTh_s[dt * 16 + lr][kc * 32 + lg * 8]);
                const f16x8 vl = *reinterpret_cast<const f16x8*>(&VTl_s[dt * 16 + lr][kc * 32 + lg * 8]);
                Oacc[dt] = __builtin_amdgcn_mfma_f32_16x16x32_f16(Pa, vh, Oacc[dt], 0, 0, 0);
                Oacc[dt] = __builtin_amdgcn_mfma_f32_16x16x32_f16(Pa, vl, Oacc[dt], 0, 0, 0);
                Oacc[dt] = __builtin_amdgcn_mfma_f32_16x16x32_f16(Pb, vh, Oacc[dt], 0, 0, 0);
            }
            Oext = __builtin_amdgcn_mfma_f32_16x16x32_f16(Pa, kOnes, Oext, 0, 0, 0);
            Oext = __builtin_amdgcn_mfma_f32_16x16x32_f16(Pb, kOnes, Oext, 0, 0, 0);
        }
        if (t + 1 < 10) bias_c = bias_n;
    }
    // ---- store split f16 ----
    #pragma unroll
    for (int r = 0; r < 4; ++r) {
        const int qq = myq + r;
        if (qq < Tc) {
            const float inv = 1.0f / Oext[r];
            const float v0 = Oacc[0][r] * inv, v1 = Oacc[1][r] * inv;
            const f16 h0 = (f16)v0, h1 = (f16)v1;
            f16* op = ao + ((size_t)b * Tc + qq) * 256 + h * HDc;
            op[lr] = h0;
            op[16 + lr] = h1;
            f16* ol = op + QK_ST;
            ol[lr] = (f16)(v0 - (float)h0);
            ol[16 + lr] = (f16)(v1 - (float)h1);
        }
    }
}

// ---- logits ----
__global__ __launch_bounds__(256) void logits_kernel(
        const float* __restrict__ ph, const float* __restrict__ w2,
        const float* __restrict__ b2, float* __restrict__ out) {
    __shared__ float s4[4];
    size_t r = blockIdx.x;
    int bb = (int)(r / Nc), n = (int)(r % Nc);
    float v = ph[r * Dc + threadIdx.x] * w2[threadIdx.x];
    float s = block_sum256(v, s4);
    if (threadIdx.x == 0) out[bb * (Nc + 1) + n] = s + b2[0];
}

// ---- value head: double-LN (norm then val) + D->D gelu + D->1 ----
__global__ __launch_bounds__(256) void value_kernel(
        const float* __restrict__ X, const float* __restrict__ ng,
        const float* __restrict__ nb, const float* __restrict__ g,
        const float* __restrict__ b, const float* __restrict__ w1,
        const float* __restrict__ b1, const float* __restrict__ w2,
        const float* __restrict__ b2, float* __restrict__ out) {
    __shared__ float s4[4];
    __shared__ float ts[Dc];
    const int bb = blockIdx.x, tid = threadIdx.x;
    float v = X[(size_t)bb * Tc * Dc + tid];
    float m = block_sum256(v, s4) * (1.0f / 256.0f);
    float d = v - m;
    float var = block_sum256(d * d, s4) * (1.0f / 256.0f);
    float y = d * rsqrtf(var + 1e-5f) * ng[tid] + nb[tid];
    float m2 = block_sum256(y, s4) * (1.0f / 256.0f);
    float d2 = y - m2;
    float var2 = block_sum256(d2 * d2, s4) * (1.0f / 256.0f);
    ts[tid] = d2 * rsqrtf(var2 + 1e-5f) * g[tid] + b[tid];
    __syncthreads();
    float acc = b1[tid];
    #pragma unroll 8
    for (int i = 0; i < Dc; ++i) acc = fmaf(ts[i], w1[i * Dc + tid], acc);
    float hv = gelu_f(acc) * w2[tid];
    float s = block_sum256(hv, s4);
    if (tid == 0) out[bb * (Nc + 1) + Nc] = s + b2[0];
}

extern "C" void kernel_launch(void* const* d_in, const int* in_sizes, int n_in,
                              void* d_out, int out_size, void* d_ws, size_t ws_size,
                              hipStream_t stream) {
    const float* obs      = (const float*)d_in[0];
    const float* input_w  = (const float*)d_in[1];
    const float* input_b  = (const float*)d_in[2];
    const float* cls_tok  = (const float*)d_in[3];
    const float* glob_tok = (const float*)d_in[4];
    const float* row_emb  = (const float*)d_in[5];
    const float* col_emb  = (const float*)d_in[6];
    const float* ln1_g    = (const float*)d_in[7];
    const float* ln1_b    = (const float*)d_in[8];
    const float* qkv_w    = (const float*)d_in[9];
    const float* qkv_b    = (const float*)d_in[10];
    const float* proj_w   = (const float*)d_in[11];
    const float* proj_b   = (const float*)d_in[12];
    const float* rel_bias = (const float*)d_in[13];
    const float* ln2_g    = (const float*)d_in[14];
    const float* ln2_b    = (const float*)d_in[15];
    const float* fc1_w    = (const float*)d_in[16];
    const float* fc1_b    = (const float*)d_in[17];
    const float* fc2_w    = (const float*)d_in[18];
    const float* fc2_b    = (const float*)d_in[19];
    const float* norm_g   = (const float*)d_in[20];
    const float* norm_b   = (const float*)d_in[21];
    const float* pol_ln_g = (const float*)d_in[22];
    const float* pol_ln_b = (const float*)d_in[23];
    const float* pol_w1   = (const float*)d_in[24];
    const float* pol_b1   = (const float*)d_in[25];
    const float* pol_w2   = (const float*)d_in[26];
    const float* pol_b2   = (const float*)d_in[27];
    const float* val_ln_g = (const float*)d_in[28];
    const float* val_ln_b = (const float*)d_in[29];
    const float* val_w1   = (const float*)d_in[30];
    const float* val_b1   = (const float*)d_in[31];
    const float* val_w2   = (const float*)d_in[32];
    const float* val_b2   = (const float*)d_in[33];
    const int*   rel_idx  = (const int*)d_in[34];
    float* out = (float*)d_out;

    float* ws = (float*)d_ws;
    const size_t SZ_XD = (size_t)BT * Dc;        // 2,371,584 floats
    float* X  = ws;
    float* R  = ws + SZ_XD;                      // qsp region (R_FLOATS floats)
    f16* qsp = (f16*)R;                          // Qh|Ql|Kh|Kl|VTh|VTl|bias
    f16* bias_g = qsp + OFF_BIAS;
    f16* Mh = qsp;                               // MLP hidden split (aliases Q/K/VT)
    f16* Aq = (f16*)(R + R_FLOATS);              // LN'd/attn-out split (SZ_XD floats)
    f16* wsplit = (f16*)(R + R_FLOATS + SZ_XD);  // 12.85 MB
    float* PT = R;                               // heads phase alias
    float* PH = (float*)wsplit;                  // heads phase alias (before polT)

    auto qkvT = [&](int l) { return wsplit + (size_t)l * 393216; };
    auto projT = [&](int l) { return wsplit + 2359296 + (size_t)l * 131072; };
    auto fc1T = [&](int l) { return wsplit + 3145728 + (size_t)l * 262144; };
    auto fc2T = [&](int l) { return wsplit + 4718592 + (size_t)l * 262144; };
    f16* polT = wsplit + 6291456;

    split_w_kernel<<<12544, 256, 0, stream>>>(
        qkv_w, proj_w, fc1_w, fc2_w, pol_w1, wsplit);

    embed_kernel<<<dim3(Tc, Bc), 256, 0, stream>>>(
        obs, input_w, input_b, cls_tok, glob_tok, row_emb, col_emb, X);

    for (int l = 0; l < DEPTHc; ++l) {
        splitA_ln_kernel<<<BT / 4, 256, 0, stream>>>(
            X, ln1_g + l * Dc, ln1_b + l * Dc, Aq);
        mgemm_kernel<2, false, true><<<876, 256, 0, stream>>>(
            Aq, qkvT(l), qkv_b + l * 3 * Dc, nullptr, qsp, BT, 3 * Dc, Dc, 12, 0);
        biasgen_kernel<<<dim3(Tc, NHc), 256, 0, stream>>>(
            rel_bias + l * NHc * BINSc, rel_idx, bias_g);
        mattn2_kernel<<<1280, 256, 0, stream>>>(qsp, Aq);
        mgemm_kernel<0, true, true><<<292, 256, 0, stream>>>(
            Aq, projT(l), proj_b + l * Dc, X, X, BT, Dc, Dc, 4, 0);
        splitA_ln_kernel<<<BT / 4, 256, 0, stream>>>(
            X, ln2_g + l * Dc, ln2_b + l * Dc, Aq);
        mgemm_kernel<3, false, true><<<584, 256, 0, stream>>>(
            Aq, fc1T(l), fc1_b + l * MLPc, nullptr, Mh, BT, MLPc, Dc, 8,
            (size_t)BT * MLPc);
        mgemm_kernel<0, true, true><<<292, 256, 0, stream>>>(
            Mh, fc2T(l), fc2_b + l * Dc, X, X, BT, Dc, MLPc, 4, 0);
    }

    lnself_kernel<<<Bc * Nc / 4, 256, 0, stream>>>(
        X, norm_g, norm_b, pol_ln_g, pol_ln_b, PT);
    mgemm_kernel<1, false, false><<<288, 256, 0, stream>>>(
        PT, polT, pol_b1, nullptr, PH, Bc * Nc, Dc, Dc, 4, 0);
    logits_kernel<<<Bc * Nc, 256, 0, stream>>>(PH, pol_w2, pol_b2, out);
    value_kernel<<<Bc, 256, 0, stream>>>(
        X, norm_g, norm_b, val_ln_g, val_ln_b, val_w1, val_b1, val_w2, val_b2, out);
}

// Round 9
// 1165.910 us; speedup vs baseline: 5.7998x; 1.0246x over previous
//
#include <hip/hip_runtime.h>
#include <math.h>

// ---- problem constants ----
constexpr int Hc = 24, Wc = 24, Nc = 576, BINSc = 82, Gc = 2;
constexpr int Tc = Nc + 1 + Gc;          // 579
constexpr int Dc = 256, NHc = 8, HDc = 32, DEPTHc = 6, MLPc = 512;
constexpr int Bc = 16, CINc = 10;
constexpr int BT = Bc * Tc;              // 9264
constexpr float SCALE = 0.17677669529663687f;  // 1/sqrt(32)

typedef _Float16 f16;
typedef _Float16 f16x4 __attribute__((ext_vector_type(4)));
typedef _Float16 f16x8 __attribute__((ext_vector_type(8)));
typedef _Float16 f16x16 __attribute__((ext_vector_type(16)));
typedef float f32x4 __attribute__((ext_vector_type(4)));

// ---- split-QKV region layout (f16 elements, base = R) ----
constexpr size_t QK_ST   = (size_t)BT * 256;           // 2,371,584
constexpr int    VT_PAD  = 640;
constexpr size_t VT_ST   = (size_t)Bc * NHc * 32 * VT_PAD;  // 2,621,440
constexpr size_t OFF_KH  = 2 * QK_ST;
constexpr size_t OFF_VTH = 4 * QK_ST;
constexpr size_t OFF_BIAS = 4 * QK_ST + 2 * VT_ST;     // 14,729,216
constexpr int    BPAD    = 580;                        // bias row stride
constexpr size_t R_F16   = OFF_BIAS + (size_t)NHc * Tc * BPAD;  // 17,415,776
constexpr size_t R_FLOATS = 8707904;

// bijective XCD chunk swizzle (T1, m204 variant)
__device__ __forceinline__ int xcd_swz(int d, int nwg) {
    const int q = nwg >> 3, r = nwg & 7;
    const int x = d & 7, s = d >> 3;
    return x * q + (x < r ? x : r) + s;
}

__device__ __forceinline__ float gelu_f(float x) {
    return 0.5f * x * (1.0f + erff(x * 0.70710678118654752f));
}

__device__ __forceinline__ float block_sum256(float v, float* s4) {
    #pragma unroll
    for (int off = 32; off > 0; off >>= 1) v += __shfl_down(v, off, 64);
    __syncthreads();
    if ((threadIdx.x & 63) == 0) s4[threadIdx.x >> 6] = v;
    __syncthreads();
    return s4[0] + s4[1] + s4[2] + s4[3];
}

// ---- embed ----
__global__ __launch_bounds__(256) void embed_kernel(
        const float* __restrict__ obs, const float* __restrict__ iw,
        const float* __restrict__ ib, const float* __restrict__ cls,
        const float* __restrict__ glob, const float* __restrict__ rowe,
        const float* __restrict__ cole, float* __restrict__ x) {
    int t = blockIdx.x, b = blockIdx.y, d = threadIdx.x;
    float v;
    if (t == 0) {
        v = cls[d];
    } else if (t <= Gc) {
        v = glob[(t - 1) * Dc + d];
    } else {
        int n = t - 1 - Gc;
        float acc = ib[d];
        #pragma unroll
        for (int c = 0; c < CINc; ++c)
            acc = fmaf(obs[(b * CINc + c) * Nc + n], iw[c * Dc + d], acc);
        v = acc + rowe[(n / Wc) * Dc + d] + cole[(n % Wc) * Dc + d];
    }
    x[((size_t)b * Tc + t) * Dc + d] = v;
}

// ---- LN + h/l split: X row -> Aq (h at [row][256], l at +QK_ST) ----
__global__ __launch_bounds__(256) void splitA_ln_kernel(
        const float* __restrict__ x, const float* __restrict__ g,
        const float* __restrict__ b, f16* __restrict__ outp) {
    const int w = threadIdx.x >> 6, l = threadIdx.x & 63;
    const int row = blockIdx.x * 4 + w;
    const float4 v = *reinterpret_cast<const float4*>(x + (size_t)row * Dc + l * 4);
    float s = v.x + v.y + v.z + v.w;
    #pragma unroll
    for (int mk = 1; mk < 64; mk <<= 1) s += __shfl_xor(s, mk, 64);
    const float m = s * (1.0f / 256.0f);
    const float4 d = make_float4(v.x - m, v.y - m, v.z - m, v.w - m);
    float vs = d.x * d.x + d.y * d.y + d.z * d.z + d.w * d.w;
    #pragma unroll
    for (int mk = 1; mk < 64; mk <<= 1) vs += __shfl_xor(vs, mk, 64);
    const float rs = rsqrtf(vs * (1.0f / 256.0f) + 1e-5f);
    const float4 gg = *reinterpret_cast<const float4*>(g + l * 4);
    const float4 bb = *reinterpret_cast<const float4*>(b + l * 4);
    const float y0 = d.x * rs * gg.x + bb.x, y1 = d.y * rs * gg.y + bb.y;
    const float y2 = d.z * rs * gg.z + bb.z, y3 = d.w * rs * gg.w + bb.w;
    const f16 h0 = (f16)y0, h1 = (f16)y1, h2 = (f16)y2, h3 = (f16)y3;
    f16x4 hv = {h0, h1, h2, h3};
    f16x4 lv = {(f16)(y0 - (float)h0), (f16)(y1 - (float)h1),
                (f16)(y2 - (float)h2), (f16)(y3 - (float)h3)};
    *reinterpret_cast<f16x4*>(outp + (size_t)row * Dc + l * 4) = hv;
    *reinterpret_cast<f16x4*>(outp + QK_ST + (size_t)row * Dc + l * 4) = lv;
}

// ---- double-LN + gather policy tokens: X -> LN(norm) -> LN(pol) -> PT ----
__global__ __launch_bounds__(256) void lnself_kernel(
        const float* __restrict__ X, const float* __restrict__ ng,
        const float* __restrict__ nb, const float* __restrict__ pg,
        const float* __restrict__ pb, float* __restrict__ out) {
    const int w = threadIdx.x >> 6, l = threadIdx.x & 63;
    const int rr = blockIdx.x * 4 + w;
    const int bb = rr / Nc, n = rr % Nc;
    const float* xr = X + ((size_t)bb * Tc + 1 + n) * Dc;
    const float4 v = *reinterpret_cast<const float4*>(xr + l * 4);
    float s = v.x + v.y + v.z + v.w;
    #pragma unroll
    for (int mk = 1; mk < 64; mk <<= 1) s += __shfl_xor(s, mk, 64);
    const float m = s * (1.0f / 256.0f);
    float4 d = make_float4(v.x - m, v.y - m, v.z - m, v.w - m);
    float vs = d.x * d.x + d.y * d.y + d.z * d.z + d.w * d.w;
    #pragma unroll
    for (int mk = 1; mk < 64; mk <<= 1) vs += __shfl_xor(vs, mk, 64);
    const float rs = rsqrtf(vs * (1.0f / 256.0f) + 1e-5f);
    const float4 gg = *reinterpret_cast<const float4*>(ng + l * 4);
    const float4 bb4 = *reinterpret_cast<const float4*>(nb + l * 4);
    float4 y = make_float4(d.x * rs * gg.x + bb4.x, d.y * rs * gg.y + bb4.y,
                           d.z * rs * gg.z + bb4.z, d.w * rs * gg.w + bb4.w);
    float s2 = y.x + y.y + y.z + y.w;
    #pragma unroll
    for (int mk = 1; mk < 64; mk <<= 1) s2 += __shfl_xor(s2, mk, 64);
    const float m2 = s2 * (1.0f / 256.0f);
    float4 d2 = make_float4(y.x - m2, y.y - m2, y.z - m2, y.w - m2);
    float vs2 = d2.x * d2.x + d2.y * d2.y + d2.z * d2.z + d2.w * d2.w;
    #pragma unroll
    for (int mk = 1; mk < 64; mk <<= 1) vs2 += __shfl_xor(vs2, mk, 64);
    const float rs2 = rsqrtf(vs2 * (1.0f / 256.0f) + 1e-5f);
    const float4 pg4 = *reinterpret_cast<const float4*>(pg + l * 4);
    const float4 pb4 = *reinterpret_cast<const float4*>(pb + l * 4);
    *reinterpret_cast<float4*>(out + ((size_t)bb * Nc + n) * Dc + l * 4) =
        make_float4(d2.x * rs2 * pg4.x + pb4.x, d2.y * rs2 * pg4.y + pb4.y,
                    d2.z * rs2 * pg4.z + pb4.z, d2.w * rs2 * pg4.w + pb4.w);
}

// ---- weight split+transpose ----
__global__ __launch_bounds__(256) void split_w_kernel(
        const float* __restrict__ qkv_w, const float* __restrict__ proj_w,
        const float* __restrict__ fc1_w, const float* __restrict__ fc2_w,
        const float* __restrict__ pol_w1, f16* __restrict__ out) {
    int r = blockIdx.x * 256 + threadIdx.x;
    float v; f16* dst; int NK;
    if (r < 1179648) {
        int layer = r / 196608, e = r % 196608;
        int n = e >> 8, k = e & 255;
        v = qkv_w[(size_t)layer * 196608 + k * 768 + n];
        dst = out + (size_t)layer * 393216 + n * 256 + k; NK = 196608;
    } else if (r < 1572864) {
        int rr = r - 1179648; int layer = rr / 65536, e = rr % 65536;
        int n = e >> 8, k = e & 255;
        v = proj_w[(size_t)layer * 65536 + k * 256 + n];
        dst = out + 2359296 + (size_t)layer * 131072 + n * 256 + k; NK = 65536;
    } else if (r < 2359296) {
        int rr = r - 1572864; int layer = rr / 131072, e = rr % 131072;
        int n = e >> 8, k = e & 255;
        v = fc1_w[(size_t)layer * 131072 + k * 512 + n];
        dst = out + 3145728 + (size_t)layer * 262144 + n * 256 + k; NK = 131072;
    } else if (r < 3145728) {
        int rr = r - 2359296; int layer = rr / 131072, e = rr % 131072;
        int n = e >> 9, k = e & 511;
        v = fc2_w[(size_t)layer * 131072 + k * 256 + n];
        dst = out + 4718592 + (size_t)layer * 262144 + n * 512 + k; NK = 131072;
    } else if (r < 3211264) {
        int rr = r - 3145728; int n = rr >> 8, k = rr & 255;
        v = pol_w1[k * 256 + n];
        dst = out + 6291456 + n * 256 + k; NK = 65536;
    } else return;
    f16 h = (f16)v;
    dst[0] = h;
    dst[NK] = (f16)(v - (float)h);
}

// ---- dense rel-bias table (row stride BPAD) ----
__global__ __launch_bounds__(256) void biasgen_kernel(
        const float* __restrict__ relb, const int* __restrict__ relidx,
        f16* __restrict__ bias) {
    const int q = blockIdx.x, h = blockIdx.y;
    const size_t rowo = ((size_t)h * Tc + q) * BPAD;
    const int* ridx = relidx + q * Tc;
    const float* rb = relb + h * BINSc;
    for (int kp = threadIdx.x; kp * 2 + 1 < Tc; kp += 256) {
        f16 b0 = (f16)rb[ridx[kp * 2]];
        f16 b1 = (f16)rb[ridx[kp * 2 + 1]];
        unsigned pk = (unsigned)__builtin_bit_cast(unsigned short, b0) |
                      ((unsigned)__builtin_bit_cast(unsigned short, b1) << 16);
        *reinterpret_cast<unsigned*>(&bias[rowo + kp * 2]) = pk;
    }
    if (threadIdx.x == 0)
        bias[rowo + Tc - 1] = (f16)rb[ridx[Tc - 1]];
}

// ---- fp16x3 MFMA GEMM with 1-deep register-prefetch pipeline (T14).
// ACT: 0=none, 1=gelu, 2=QKV-split-out, 3=gelu+split-out(osplit)
// PSA: A is pre-split f16 (h at A, l at A + M*K); else fp32 (split on stage)
__device__ __forceinline__ int swz(int r, int g) {
    return r * 40 + ((g ^ ((r >> 3) & 3)) << 3);
}
template <int ACT, bool RES, bool PSA>
__global__ __launch_bounds__(256) void mgemm_kernel(
        const void* __restrict__ Ap, const f16* __restrict__ WT,
        const float* __restrict__ bias, const float* __restrict__ res,
        void* __restrict__ Cp, int M, int N, int K, int nbx, size_t osplit) {
    constexpr int BM = 128, BN = 64, BK = 32;
    __shared__ f16 Ah[BM * 40], Al[BM * 40];
    __shared__ f16 Bh[BN * 40], Bl[BN * 40];
    const int tid = threadIdx.x;
    const int v = xcd_swz(blockIdx.x, gridDim.x);
    const int m0 = (v / nbx) * BM, n0 = (v % nbx) * BN;
    const int w = tid >> 6, l = tid & 63;
    const int wm = (w >> 1) * 64, wn = (w & 1) * 32;
    const int lg = l >> 4, lr = l & 15;
    f32x4 acc[4][2] = {};
    const int sa_row = tid >> 1, sa_kc = (tid & 1) * 16;
    const int sb_part = tid >> 7;
    const int sb_n = (tid & 127) >> 1, sb_kc = (tid & 1) * 16;

    int gr = m0 + sa_row; if (gr >= M) gr = M - 1;

    // ---- prefetch registers (named; no runtime-indexed arrays) ----
    f16x8 rA0, rA1, rA2, rA3;        // PSA path: h0,h1,l0,l1
    float4 rF0, rF1, rF2, rF3;       // non-PSA path: raw fp32
    f16x8 rB0, rB1;

    auto load_tile = [&](int k0) {
        if constexpr (PSA) {
            const f16* src = (const f16*)Ap + (size_t)gr * K + k0 + sa_kc;
            rA0 = *reinterpret_cast<const f16x8*>(src);
            rA1 = *reinterpret_cast<const f16x8*>(src + 8);
            const f16* srcl = src + (size_t)M * K;
            rA2 = *reinterpret_cast<const f16x8*>(srcl);
            rA3 = *reinterpret_cast<const f16x8*>(srcl + 8);
        } else {
            const float4* src = reinterpret_cast<const float4*>(
                (const float*)Ap + (size_t)gr * K + k0 + sa_kc);
            rF0 = src[0]; rF1 = src[1]; rF2 = src[2]; rF3 = src[3];
        }
        const f16x8* bsrc = reinterpret_cast<const f16x8*>(
            WT + (size_t)sb_part * N * K + (size_t)(n0 + sb_n) * K + k0 + sb_kc);
        rB0 = bsrc[0]; rB1 = bsrc[1];
    };

    auto store_stage = [&]() {
        const int g0 = sa_kc >> 3;
        if constexpr (PSA) {
            *reinterpret_cast<f16x8*>(&Ah[swz(sa_row, g0)])     = rA0;
            *reinterpret_cast<f16x8*>(&Ah[swz(sa_row, g0 + 1)]) = rA1;
            *reinterpret_cast<f16x8*>(&Al[swz(sa_row, g0)])     = rA2;
            *reinterpret_cast<f16x8*>(&Al[swz(sa_row, g0 + 1)]) = rA3;
        } else {
            f16x8 hv0, hv1, lv0, lv1;
            const float va[16] = {rF0.x, rF0.y, rF0.z, rF0.w,
                                  rF1.x, rF1.y, rF1.z, rF1.w,
                                  rF2.x, rF2.y, rF2.z, rF2.w,
                                  rF3.x, rF3.y, rF3.z, rF3.w};
            #pragma unroll
            for (int e = 0; e < 8; ++e) {
                f16 h0 = (f16)va[e];
                hv0[e] = h0; lv0[e] = (f16)(va[e] - (float)h0);
                f16 h1 = (f16)va[8 + e];
                hv1[e] = h1; lv1[e] = (f16)(va[8 + e] - (float)h1);
            }
            *reinterpret_cast<f16x8*>(&Ah[swz(sa_row, g0)])     = hv0;
            *reinterpret_cast<f16x8*>(&Ah[swz(sa_row, g0 + 1)]) = hv1;
            *reinterpret_cast<f16x8*>(&Al[swz(sa_row, g0)])     = lv0;
            *reinterpret_cast<f16x8*>(&Al[swz(sa_row, g0 + 1)]) = lv1;
        }
        f16* dbase = sb_part ? Bl : Bh;
        const int gb = sb_kc >> 3;
        *reinterpret_cast<f16x8*>(&dbase[swz(sb_n, gb)])     = rB0;
        *reinterpret_cast<f16x8*>(&dbase[swz(sb_n, gb + 1)]) = rB1;
    };

    load_tile(0);
    const int nk = K / BK;
    for (int t = 0; t < nk; ++t) {
        if (t) __syncthreads();          // prev tile's LDS reads done
        store_stage();
        if (t + 1 < nk) load_tile((t + 1) * BK);  // hide load under MFMA
        __syncthreads();                 // LDS ready
        f16x8 afh[4], afl[4], bfh[2], bfl[2];
        #pragma unroll
        for (int mi = 0; mi < 4; ++mi) {
            int row = wm + mi * 16 + lr;
            afh[mi] = *reinterpret_cast<const f16x8*>(&Ah[swz(row, lg)]);
            afl[mi] = *reinterpret_cast<const f16x8*>(&Al[swz(row, lg)]);
        }
        #pragma unroll
        for (int ni = 0; ni < 2; ++ni) {
            int col = wn + ni * 16 + lr;
            bfh[ni] = *reinterpret_cast<const f16x8*>(&Bh[swz(col, lg)]);
            bfl[ni] = *reinterpret_cast<const f16x8*>(&Bl[swz(col, lg)]);
        }
        #pragma unroll
        for (int mi = 0; mi < 4; ++mi)
            #pragma unroll
            for (int ni = 0; ni < 2; ++ni) {
                acc[mi][ni] = __builtin_amdgcn_mfma_f32_16x16x32_f16(
                    afh[mi], bfh[ni], acc[mi][ni], 0, 0, 0);
                acc[mi][ni] = __builtin_amdgcn_mfma_f32_16x16x32_f16(
                    afh[mi], bfl[ni], acc[mi][ni], 0, 0, 0);
                acc[mi][ni] = __builtin_amdgcn_mfma_f32_16x16x32_f16(
                    afl[mi], bfh[ni], acc[mi][ni], 0, 0, 0);
            }
    }
    float bv[2];
    #pragma unroll
    for (int ni = 0; ni < 2; ++ni) bv[ni] = bias[n0 + wn + ni * 16 + lr];
    #pragma unroll
    for (int mi = 0; mi < 4; ++mi) {
        #pragma unroll
        for (int r = 0; r < 4; ++r) {
            int grow = m0 + wm + mi * 16 + lg * 4 + r;
            if (grow >= M) continue;
            if constexpr (ACT == 2) {
                f16* base = (f16*)Cp;
                const int bb = grow / Tc;
                const int tt = grow - bb * Tc;
                #pragma unroll
                for (int ni = 0; ni < 2; ++ni) {
                    const int gcol = n0 + wn + ni * 16 + lr;
                    float vv = acc[mi][ni][r] + bv[ni];
                    if (gcol < 256) {                       // Q (scaled)
                        vv *= SCALE;
                        f16 hh = (f16)vv;
                        base[(size_t)grow * 256 + gcol] = hh;
                        base[QK_ST + (size_t)grow * 256 + gcol] = (f16)(vv - (float)hh);
                    } else if (gcol < 512) {                // K
                        f16 hh = (f16)vv;
                        base[OFF_KH + (size_t)grow * 256 + (gcol - 256)] = hh;
                        base[OFF_KH + QK_ST + (size_t)grow * 256 + (gcol - 256)] =
                            (f16)(vv - (float)hh);
                    } else {                                // V transposed
                        const int e = gcol - 512;
                        const int hh_ = e >> 5, dd = e & 31;
                        const size_t o =
                            ((size_t)((bb * NHc + hh_) * 32 + dd)) * VT_PAD + tt;
                        f16 hh = (f16)vv;
                        base[OFF_VTH + o] = hh;
                        base[OFF_VTH + VT_ST + o] = (f16)(vv - (float)hh);
                    }
                }
            } else if constexpr (ACT == 3) {
                f16* base = (f16*)Cp;
                #pragma unroll
                for (int ni = 0; ni < 2; ++ni) {
                    const int gcol = n0 + wn + ni * 16 + lr;
                    float vv = gelu_f(acc[mi][ni][r] + bv[ni]);
                    f16 hh = (f16)vv;
                    base[(size_t)grow * N + gcol] = hh;
                    base[osplit + (size_t)grow * N + gcol] = (f16)(vv - (float)hh);
                }
            } else {
                float* C = (float*)Cp;
                #pragma unroll
                for (int ni = 0; ni < 2; ++ni) {
                    int gcol = n0 + wn + ni * 16 + lr;
                    float vv = acc[mi][ni][r] + bv[ni];
                    if (ACT == 1) vv = gelu_f(vv);
                    if (RES) vv += res[(size_t)grow * N + gcol];
                    C[(size_t)grow * N + gcol] = vv;
                }
            }
        }
    }
}

// ---- MFMA flash attention v5 (unchanged from round 8) ----
__global__ __launch_bounds__(256, 4) void mattn2_kernel(
        const f16* __restrict__ qsp, f16* __restrict__ ao) {
    __shared__ __align__(16) f16 Kh_s[64][40], Kl_s[64][40];   // 10240 B
    __shared__ __align__(16) f16 VTh_s[32][72], VTl_s[32][72]; // 9216 B
    __shared__ __align__(16) f16 Ph_s[4][16][72], Pl_s[4][16][72]; // 18432 B
    const f16* __restrict__ Kh_g  = qsp + OFF_KH;
    const f16* __restrict__ VTh_g = qsp + OFF_VTH;
    const f16* __restrict__ bias_g = qsp + OFF_BIAS;

    const int tid = threadIdx.x;
    const int v = xcd_swz(blockIdx.x, 1280);   // h-major: XCD owns one head
    const int h = v / 160;
    const int rem = v - h * 160;
    const int b = rem / 10, qt = rem - b * 10;
    const int q0 = qt * 64;
    const int w = tid >> 6, l = tid & 63;
    const int lr = l & 15, lg = l >> 4;

    int qrow = q0 + w * 16 + lr; if (qrow >= Tc) qrow = Tc - 1;
    const f16* qp = qsp + ((size_t)(b * Tc + qrow)) * 256 + h * 32 + lg * 8;
    const f16x8 Qh = *reinterpret_cast<const f16x8*>(qp);
    const f16x8 Ql = *reinterpret_cast<const f16x8*>(qp + QK_ST);
    const int myq = q0 + w * 16 + lg * 4;

    int boff[4];
    #pragma unroll
    for (int r = 0; r < 4; ++r) {
        int qq = myq + r; if (qq >= Tc) qq = Tc - 1;
        boff[r] = (h * Tc + qq) * BPAD;
    }

    const int skrow = tid >> 2, skc = (tid & 3) * 8;
    const int svd = tid >> 3, svc = (tid & 7) * 8;
    const f16* vrow = VTh_g + ((size_t)((b * NHc + h) * 32 + svd)) * VT_PAD;

    struct KV { f16x8 kh, kl, vh, vl; };
    auto load_kv = [&](int k0) {
        KV r;
        int gk = k0 + skrow; if (gk >= Tc) gk = Tc - 1;
        const f16* kp = Kh_g + ((size_t)(b * Tc + gk)) * 256 + h * 32 + skc;
        r.kh = *reinterpret_cast<const f16x8*>(kp);
        r.kl = *reinterpret_cast<const f16x8*>(kp + QK_ST);
        const f16* vp = vrow + k0 + svc;
        r.vh = *reinterpret_cast<const f16x8*>(vp);
        r.vl = *reinterpret_cast<const f16x8*>(vp + VT_ST);
        return r;
    };
    auto load_bias = [&](int k0) {
        f16x16 bv;
        #pragma unroll
        for (int r = 0; r < 4; ++r)
            #pragma unroll
            for (int j = 0; j < 4; ++j) {
                int kk = k0 + j * 16 + lr; if (kk >= Tc) kk = Tc - 1;
                bv[r * 4 + j] = bias_g[boff[r] + kk];
            }
        return bv;
    };

    KV pA = load_kv(0);
    KV pB = load_kv(64);
    f16x16 bias_c = load_bias(0), bias_n;

    f16x8 kOnes;
    #pragma unroll
    for (int e = 0; e < 8; ++e) kOnes[e] = (f16)1.0f;

    float m_run[4];
    f32x4 Oacc[2] = {};
    f32x4 Oext = {};
    #pragma unroll
    for (int r = 0; r < 4; ++r) m_run[r] = -1e30f;

    for (int t = 0; t < 10; ++t) {
        const int k0 = t * 64;
        __syncthreads();
        *reinterpret_cast<f16x8*>(&Kh_s[skrow][skc]) = pA.kh;
        *reinterpret_cast<f16x8*>(&Kl_s[skrow][skc]) = pA.kl;
        *reinterpret_cast<f16x8*>(&VTh_s[svd][svc]) = pA.vh;
        *reinterpret_cast<f16x8*>(&VTl_s[svd][svc]) = pA.vl;
        pA = pB;
        if (t + 2 < 10) pB = load_kv(k0 + 128);
        __syncthreads();
        if (t + 1 < 10) bias_n = load_bias(k0 + 64);
        f32x4 sc[4];
        #pragma unroll
        for (int j = 0; j < 4; ++j) {
            const f16x8 kh = *reinterpret_cast<const f16x8*>(&Kh_s[j * 16 + lr][lg * 8]);
            const f16x8 kl = *reinterpret_cast<const f16x8*>(&Kl_s[j * 16 + lr][lg * 8]);
            f32x4 s = {(float)bias_c[j], (float)bias_c[4 + j],
                       (float)bias_c[8 + j], (float)bias_c[12 + j]};
            s = __builtin_amdgcn_mfma_f32_16x16x32_f16(Qh, kh, s, 0, 0, 0);
            s = __builtin_amdgcn_mfma_f32_16x16x32_f16(Qh, kl, s, 0, 0, 0);
            s = __builtin_amdgcn_mfma_f32_16x16x32_f16(Ql, kh, s, 0, 0, 0);
            sc[j] = s;
        }
        #pragma unroll
        for (int j = 0; j < 4; ++j) {
            const int kk = k0 + j * 16 + lr;
            if (kk >= Tc) { sc[j][0] = sc[j][1] = sc[j][2] = sc[j][3] = -1e30f; }
        }
        #pragma unroll
        for (int r = 0; r < 4; ++r) {
            float tm = fmaxf(fmaxf(sc[0][r], sc[1][r]), fmaxf(sc[2][r], sc[3][r]));
            #pragma unroll
            for (int mk = 1; mk < 16; mk <<= 1) tm = fmaxf(tm, __shfl_xor(tm, mk, 64));
            const float mn = fmaxf(m_run[r], tm);
            const float resc = __expf(m_run[r] - mn);
            m_run[r] = mn;
            Oacc[0][r] *= resc; Oacc[1][r] *= resc; Oext[r] *= resc;
            const int prow = lg * 4 + r;
            #pragma unroll
            for (int j = 0; j < 4; ++j) {
                const float p = __expf(sc[j][r] - mn);
                const f16 ph = (f16)p;
                Ph_s[w][prow][j * 16 + lr] = ph;
                Pl_s[w][prow][j * 16 + lr] = (f16)(p - (float)ph);
            }
        }
        #pragma unroll
        for (int kc = 0; kc < 2; ++kc) {
            const f16x8 Pa = *reinterpret_cast<const f16x8*>(&Ph_s[w][lr][kc * 32 + lg * 8]);
            const f16x8 Pb = *reinterpret_cast<const f16x8*>(&Pl_s[w][lr][kc * 32 + lg * 8]);
            #pragma unroll
            for (int dt = 0; dt < 2; ++dt) {
                const f16x8 vh = *reinterpret_cast<const f16x8*>(&VTh_s[dt * 16 + lr][kc * 32 + lg * 8]);
                const f16x8 vl = *reinterpret_cast<const f16x8*>(&VTl_s[dt * 16 + lr][kc * 32 + lg * 8]);
                Oacc[dt] = __builtin_amdgcn_mfma_f32_16x16x32_f16(Pa, vh, Oacc[dt], 0, 0, 0);
                Oacc[dt] = __builtin_amdgcn_mfma_f32_16x16x32_f16(Pa, vl, Oacc[dt], 0, 0, 0);
                Oacc[dt] = __builtin_amdgcn_mfma_f32_16x16x32_f16(Pb, vh, Oacc[dt], 0, 0, 0);
            }
            Oext = __builtin_amdgcn_mfma_f32_16x16x32_f16(Pa, kOnes, Oext, 0, 0, 0);
            Oext = __builtin_amdgcn_mfma_f32_16x16x32_f16(Pb, kOnes, Oext, 0, 0, 0);
        }
        if (t + 1 < 10) bias_c = bias_n;
    }
    #pragma unroll
    for (int r = 0; r < 4; ++r) {
        const int qq = myq + r;
        if (qq < Tc) {
            const float inv = 1.0f / Oext[r];
            const float v0 = Oacc[0][r] * inv, v1 = Oacc[1][r] * inv;
            const f16 h0 = (f16)v0, h1 = (f16)v1;
            f16* op = ao + ((size_t)b * Tc + qq) * 256 + h * HDc;
            op[lr] = h0;
            op[16 + lr] = h1;
            f16* ol = op + QK_ST;
            ol[lr] = (f16)(v0 - (float)h0);
            ol[16 + lr] = (f16)(v1 - (float)h1);
        }
    }
}

// ---- logits ----
__global__ __launch_bounds__(256) void logits_kernel(
        const float* __restrict__ ph, const float* __restrict__ w2,
        const float* __restrict__ b2, float* __restrict__ out) {
    __shared__ float s4[4];
    size_t r = blockIdx.x;
    int bb = (int)(r / Nc), n = (int)(r % Nc);
    float v = ph[r * Dc + threadIdx.x] * w2[threadIdx.x];
    float s = block_sum256(v, s4);
    if (threadIdx.x == 0) out[bb * (Nc + 1) + n] = s + b2[0];
}

// ---- value head: double-LN (norm then val) + D->D gelu + D->1 ----
__global__ __launch_bounds__(256) void value_kernel(
        const float* __restrict__ X, const float* __restrict__ ng,
        const float* __restrict__ nb, const float* __restrict__ g,
        const float* __restrict__ b, const float* __restrict__ w1,
        const float* __restrict__ b1, const float* __restrict__ w2,
        const float* __restrict__ b2, float* __restrict__ out) {
    __shared__ float s4[4];
    __shared__ float ts[Dc];
    const int bb = blockIdx.x, tid = threadIdx.x;
    float v = X[(size_t)bb * Tc * Dc + tid];
    float m = block_sum256(v, s4) * (1.0f / 256.0f);
    float d = v - m;
    float var = block_sum256(d * d, s4) * (1.0f / 256.0f);
    float y = d * rsqrtf(var + 1e-5f) * ng[tid] + nb[tid];
    float m2 = block_sum256(y, s4) * (1.0f / 256.0f);
    float d2 = y - m2;
    float var2 = block_sum256(d2 * d2, s4) * (1.0f / 256.0f);
    ts[tid] = d2 * rsqrtf(var2 + 1e-5f) * g[tid] + b[tid];
    __syncthreads();
    float acc = b1[tid];
    #pragma unroll 8
    for (int i = 0; i < Dc; ++i) acc = fmaf(ts[i], w1[i * Dc + tid], acc);
    float hv = gelu_f(acc) * w2[tid];
    float s = block_sum256(hv, s4);
    if (tid == 0) out[bb * (Nc + 1) + Nc] = s + b2[0];
}

extern "C" void kernel_launch(void* const* d_in, const int* in_sizes, int n_in,
                              void* d_out, int out_size, void* d_ws, size_t ws_size,
                              hipStream_t stream) {
    const float* obs      = (const float*)d_in[0];
    const float* input_w  = (const float*)d_in[1];
    const float* input_b  = (const float*)d_in[2];
    const float* cls_tok  = (const float*)d_in[3];
    const float* glob_tok = (const float*)d_in[4];
    const float* row_emb  = (const float*)d_in[5];
    const float* col_emb  = (const float*)d_in[6];
    const float* ln1_g    = (const float*)d_in[7];
    const float* ln1_b    = (const float*)d_in[8];
    const float* qkv_w    = (const float*)d_in[9];
    const float* qkv_b    = (const float*)d_in[10];
    const float* proj_w   = (const float*)d_in[11];
    const float* proj_b   = (const float*)d_in[12];
    const float* rel_bias = (const float*)d_in[13];
    const float* ln2_g    = (const float*)d_in[14];
    const float* ln2_b    = (const float*)d_in[15];
    const float* fc1_w    = (const float*)d_in[16];
    const float* fc1_b    = (const float*)d_in[17];
    const float* fc2_w    = (const float*)d_in[18];
    const float* fc2_b    = (const float*)d_in[19];
    const float* norm_g   = (const float*)d_in[20];
    const float* norm_b   = (const float*)d_in[21];
    const float* pol_ln_g = (const float*)d_in[22];
    const float* pol_ln_b = (const float*)d_in[23];
    const float* pol_w1   = (const float*)d_in[24];
    const float* pol_b1   = (const float*)d_in[25];
    const float* pol_w2   = (const float*)d_in[26];
    const float* pol_b2   = (const float*)d_in[27];
    const float* val_ln_g = (const float*)d_in[28];
    const float* val_ln_b = (const float*)d_in[29];
    const float* val_w1   = (const float*)d_in[30];
    const float* val_b1   = (const float*)d_in[31];
    const float* val_w2   = (const float*)d_in[32];
    const float* val_b2   = (const float*)d_in[33];
    const int*   rel_idx  = (const int*)d_in[34];
    float* out = (float*)d_out;

    float* ws = (float*)d_ws;
    const size_t SZ_XD = (size_t)BT * Dc;        // 2,371,584 floats
    float* X  = ws;
    float* R  = ws + SZ_XD;                      // qsp region (R_FLOATS floats)
    f16* qsp = (f16*)R;                          // Qh|Ql|Kh|Kl|VTh|VTl|bias
    f16* bias_g = qsp + OFF_BIAS;
    f16* Mh = qsp;                               // MLP hidden split (aliases Q/K/VT)
    f16* Aq = (f16*)(R + R_FLOATS);              // LN'd/attn-out split (SZ_XD floats)
    f16* wsplit = (f16*)(R + R_FLOATS + SZ_XD);  // 12.85 MB
    float* PT = R;                               // heads phase alias
    float* PH = (float*)wsplit;                  // heads phase alias (before polT)

    auto qkvT = [&](int l) { return wsplit + (size_t)l * 393216; };
    auto projT = [&](int l) { return wsplit + 2359296 + (size_t)l * 131072; };
    auto fc1T = [&](int l) { return wsplit + 3145728 + (size_t)l * 262144; };
    auto fc2T = [&](int l) { return wsplit + 4718592 + (size_t)l * 262144; };
    f16* polT = wsplit + 6291456;

    split_w_kernel<<<12544, 256, 0, stream>>>(
        qkv_w, proj_w, fc1_w, fc2_w, pol_w1, wsplit);

    embed_kernel<<<dim3(Tc, Bc), 256, 0, stream>>>(
        obs, input_w, input_b, cls_tok, glob_tok, row_emb, col_emb, X);

    for (int l = 0; l < DEPTHc; ++l) {
        splitA_ln_kernel<<<BT / 4, 256, 0, stream>>>(
            X, ln1_g + l * Dc, ln1_b + l * Dc, Aq);
        mgemm_kernel<2, false, true><<<876, 256, 0, stream>>>(
            Aq, qkvT(l), qkv_b + l * 3 * Dc, nullptr, qsp, BT, 3 * Dc, Dc, 12, 0);
        biasgen_kernel<<<dim3(Tc, NHc), 256, 0, stream>>>(
            rel_bias + l * NHc * BINSc, rel_idx, bias_g);
        mattn2_kernel<<<1280, 256, 0, stream>>>(qsp, Aq);
        mgemm_kernel<0, true, true><<<292, 256, 0, stream>>>(
            Aq, projT(l), proj_b + l * Dc, X, X, BT, Dc, Dc, 4, 0);
        splitA_ln_kernel<<<BT / 4, 256, 0, stream>>>(
            X, ln2_g + l * Dc, ln2_b + l * Dc, Aq);
        mgemm_kernel<3, false, true><<<584, 256, 0, stream>>>(
            Aq, fc1T(l), fc1_b + l * MLPc, nullptr, Mh, BT, MLPc, Dc, 8,
            (size_t)BT * MLPc);
        mgemm_kernel<0, true, true><<<292, 256, 0, stream>>>(
            Mh, fc2T(l), fc2_b + l * Dc, X, X, BT, Dc, MLPc, 4, 0);
    }

    lnself_kernel<<<Bc * Nc / 4, 256, 0, stream>>>(
        X, norm_g, norm_b, pol_ln_g, pol_ln_b, PT);
    mgemm_kernel<1, false, false><<<288, 256, 0, stream>>>(
        PT, polT, pol_b1, nullptr, PH, Bc * Nc, Dc, Dc, 4, 0);
    logits_kernel<<<Bc * Nc, 256, 0, stream>>>(PH, pol_w2, pol_b2, out);
    value_kernel<<<Bc, 256, 0, stream>>>(
        X, norm_g, norm_b, val_ln_g, val_ln_b, val_w1, val_b1, val_w2, val_b2, out);
}